// Round 14
// baseline (8476.833 us; speedup 1.0000x reference)
//
#include <hip/hip_runtime.h>
#include <hip/hip_bf16.h>
#include <stdint.h>

#define DEV __device__ __forceinline__
typedef unsigned short u16;
typedef unsigned int   u32;
typedef unsigned long long u64;

static constexpr int SS = 256;   // src len
static constexpr int TT = 64;    // tgt len
static constexpr int EE = 256;   // embed dim
static constexpr int HH = 512;   // hidden
static constexpr int G3 = 1536;  // 3*H
static constexpr int VV = 32000; // vocab
static constexpr int WP = 260;   // wts LDS pitch (f32): odd*4 -> conflict-free

using frag   = __attribute__((ext_vector_type(8))) short;  // 8 bf16
using f32x4v = __attribute__((ext_vector_type(4))) float;  // MFMA acc

// ---------- helpers ----------
DEV float blo(u32 u){ union{u32 i; float f;} x; x.i = u << 16;         return x.f; }
DEV float bhi(u32 u){ union{u32 i; float f;} x; x.i = u & 0xffff0000u; return x.f; }
DEV float bf2f(u16 u){ union{u32 i; float f;} x; x.i = ((u32)u) << 16; return x.f; }
DEV u16 f2bf(float f){ union{float f; u32 u;} v; v.f = f;
  u32 r = v.u + 0x7fffu + ((v.u >> 16) & 1u); return (u16)(r >> 16); }
DEV float sigf (float x){ return 1.0f / (1.0f + __expf(-x)); }
DEV float tanh_(float x){ return 1.0f - 2.0f / (1.0f + __expf(2.0f * x)); }
DEV void unp8(float* d, uint4 u){
  d[0]=blo(u.x); d[1]=bhi(u.x); d[2]=blo(u.y); d[3]=bhi(u.y);
  d[4]=blo(u.z); d[5]=bhi(u.z); d[6]=blo(u.w); d[7]=bhi(u.w);
}
DEV float4 unp4(u64 v){
  return make_float4(bf2f((u16)v), bf2f((u16)(v >> 16)),
                     bf2f((u16)(v >> 32)), bf2f((u16)(v >> 48)));
}
DEV float dot4(float acc, float4 w, float4 x){
  acc = fmaf(w.x,x.x,acc); acc = fmaf(w.y,x.y,acc);
  acc = fmaf(w.z,x.z,acc); acc = fmaf(w.w,x.w,acc);
  return acc;
}
DEV float fma44(float acc, float4 w0, float4 w1, float4 h0, float4 h1){
  return dot4(dot4(acc, w0, h0), w1, h1);
}
DEV float fma8(float acc, const float* w, float4 a, float4 b){
  acc = fmaf(w[0],a.x,acc); acc = fmaf(w[1],a.y,acc);
  acc = fmaf(w[2],a.z,acc); acc = fmaf(w[3],a.w,acc);
  acc = fmaf(w[4],b.x,acc); acc = fmaf(w[5],b.y,acc);
  acc = fmaf(w[6],b.z,acc); acc = fmaf(w[7],b.w,acc);
  return acc;
}

// ---- agent-scope atomics: producers AND same-kernel cross-block consumers
// (r9-proven rule; plain loads only across kernel boundaries).
DEV void  ast_f(float* p, float v){ __hip_atomic_store(p, v, __ATOMIC_RELAXED, __HIP_MEMORY_SCOPE_AGENT); }
DEV void  ast_u(u32* p, u32 v)    { __hip_atomic_store(p, v, __ATOMIC_RELAXED, __HIP_MEMORY_SCOPE_AGENT); }
DEV float ald_f(const float* p)   { return __hip_atomic_load((float*)p, __ATOMIC_RELAXED, __HIP_MEMORY_SCOPE_AGENT); }
DEV u64   ald_u8(const u64* p)    { return __hip_atomic_load((u64*)p,   __ATOMIC_RELAXED, __HIP_MEMORY_SCOPE_AGENT); }

DEV void grid_bar(u32* cnt, u32 target){
  __syncthreads();
  if (threadIdx.x == 0) {
    __hip_atomic_fetch_add(cnt, 1u, __ATOMIC_RELAXED, __HIP_MEMORY_SCOPE_AGENT);
    while (__hip_atomic_load(cnt, __ATOMIC_RELAXED, __HIP_MEMORY_SCOPE_AGENT) < target)
      __builtin_amdgcn_s_sleep(1);
  }
  __syncthreads();
}

// ---------- K1: gi = gather(emb, tok) @ W[:, :256]^T + bih  (bf16 out) ----
__global__ __launch_bounds__(256)
void k_embed_gemm(const int* __restrict__ tok, int Tlen,
                  const float* __restrict__ emb,
                  const float* __restrict__ W, int wstride,
                  const float* __restrict__ bias,
                  u16* __restrict__ gi)
{
  __shared__ float es[16][EE];
  const int tid = threadIdx.x;
  const int r0 = blockIdx.y * 16;
  #pragma unroll
  for (int rr = 0; rr < 16; ++rr) {
    int r = r0 + rr;
    int token = tok[(r & 31) * Tlen + (r >> 5)];
    es[rr][tid] = emb[(size_t)token * EE + tid];
  }
  __syncthreads();
  const int jl = tid & 63;
  const int rg = (tid >> 6) << 2;
  const int jbase = blockIdx.x * 256 + jl;
  float acc[4][4];
  #pragma unroll
  for (int jj = 0; jj < 4; ++jj) {
    float bv = bias[jbase + jj * 64];
    #pragma unroll
    for (int rr = 0; rr < 4; ++rr) acc[jj][rr] = bv;
  }
  const float4* w0 = (const float4*)(W + (size_t)(jbase      ) * wstride);
  const float4* w1 = (const float4*)(W + (size_t)(jbase +  64) * wstride);
  const float4* w2 = (const float4*)(W + (size_t)(jbase + 128) * wstride);
  const float4* w3 = (const float4*)(W + (size_t)(jbase + 192) * wstride);
  for (int k4 = 0; k4 < EE / 4; ++k4) {
    float4 wv0 = w0[k4], wv1 = w1[k4], wv2 = w2[k4], wv3 = w3[k4];
    #pragma unroll
    for (int rr = 0; rr < 4; ++rr) {
      float4 e = *(const float4*)&es[rg + rr][k4 * 4];
      acc[0][rr] = dot4(acc[0][rr], wv0, e);
      acc[1][rr] = dot4(acc[1][rr], wv1, e);
      acc[2][rr] = dot4(acc[2][rr], wv2, e);
      acc[3][rr] = dot4(acc[3][rr], wv3, e);
    }
  }
  #pragma unroll
  for (int rr = 0; rr < 4; ++rr)
    #pragma unroll
    for (int jj = 0; jj < 4; ++jj)
      gi[(size_t)(r0 + rg + rr) * G3 + jbase + jj * 64] = f2bf(acc[jj][rr]);
}

// ---------- K2: encoder GRU scan — persistent, 64 blocks, 1 bar/step ----
// 8 i's/block; f32 weights in LDS; hs XOR-swizzled (granule ^= b&7).
__global__ __launch_bounds__(256)
void k_enc_scan(const u16* __restrict__ gi, const float* __restrict__ Whh,
                const float* __restrict__ bhh, u16* __restrict__ hring,
                u16* __restrict__ enc_outs, u32* __restrict__ bar)
{
  __shared__ float hs[32 * 512];    // 64 KB, swizzled
  __shared__ float wsl[24 * 512];   // 48 KB f32 (rows: g*8+il8)
  __shared__ float h2t[8][32];
  const int tid = threadIdx.x;
  const int bid = blockIdx.x;
  const int i0 = bid * 8;
  #pragma unroll
  for (int j = 0; j < 12; ++j) {    // 3072 float4 stage
    int f = (j * 256 + tid) * 4;
    int row24 = f >> 9, k = f & 511;
    int g = row24 >> 3, il8 = row24 & 7;
    *(float4*)&wsl[f] = *(const float4*)(Whh + (size_t)(g * 512 + i0 + il8) * 512 + k);
  }
  const int i_l = tid >> 6, lane = tid & 63, b = lane >> 1, kh = lane & 1;
  const int ia = i0 + i_l, ib = i0 + i_l + 4;
  const float* wRa = wsl + (0 * 8 + i_l    ) * 512 + kh * 256;
  const float* wZa = wsl + (1 * 8 + i_l    ) * 512 + kh * 256;
  const float* wNa = wsl + (2 * 8 + i_l    ) * 512 + kh * 256;
  const float* wRb = wsl + (0 * 8 + i_l + 4) * 512 + kh * 256;
  const float* wZb = wsl + (1 * 8 + i_l + 4) * 512 + kh * 256;
  const float* wNb = wsl + (2 * 8 + i_l + 4) * 512 + kh * 256;
  const float bRa = bhh[ia], bZa = bhh[ia + 512], bNa = bhh[ia + 1024];
  const float bRb = bhh[ib], bZb = bhh[ib + 512], bNb = bhh[ib + 1024];
  u32 bt = 0;
  for (int t = 0; t < SS; ++t) {
    // stage h: 16 atomic u64/thread -> swizzled LDS
    const u64* hsrc = (const u64*)(hring + (size_t)t * 16384);
    #pragma unroll
    for (int j = 0; j < 16; ++j) {
      int idx = j * 256 + tid;
      u64 v = ald_u8(hsrc + idx);
      int bb = idx >> 7, gr = idx & 127;
      *(float4*)&hs[bb * 512 + ((gr ^ (bb & 7)) << 2)] = unp4(v);
    }
    __syncthreads();
    float aRa=0,aZa=0,aNa=0,aRb=0,aZb=0,aNb=0;
    for (int k8 = 0; k8 < 32; ++k8) {
      int g0 = kh * 64 + k8 * 2;
      float4 h0 = *(const float4*)&hs[b * 512 + ((g0 ^ (b & 7)) << 2)];
      float4 h1 = *(const float4*)&hs[b * 512 + (((g0 + 1) ^ (b & 7)) << 2)];
      aRa = fma44(aRa, *(const float4*)&wRa[k8*8], *(const float4*)&wRa[k8*8+4], h0, h1);
      aZa = fma44(aZa, *(const float4*)&wZa[k8*8], *(const float4*)&wZa[k8*8+4], h0, h1);
      aNa = fma44(aNa, *(const float4*)&wNa[k8*8], *(const float4*)&wNa[k8*8+4], h0, h1);
      aRb = fma44(aRb, *(const float4*)&wRb[k8*8], *(const float4*)&wRb[k8*8+4], h0, h1);
      aZb = fma44(aZb, *(const float4*)&wZb[k8*8], *(const float4*)&wZb[k8*8+4], h0, h1);
      aNb = fma44(aNb, *(const float4*)&wNb[k8*8], *(const float4*)&wNb[k8*8+4], h0, h1);
    }
    aRa += __shfl_xor(aRa,1); aZa += __shfl_xor(aZa,1); aNa += __shfl_xor(aNa,1);
    aRb += __shfl_xor(aRb,1); aZb += __shfl_xor(aZb,1); aNb += __shfl_xor(aNb,1);
    if (kh == 0) {
      const size_t g = ((size_t)t * 32 + b) * G3;
      float hoa = hs[b * 512 + (((ia >> 2) ^ (b & 7)) << 2) + (ia & 3)];
      float hob = hs[b * 512 + (((ib >> 2) ^ (b & 7)) << 2) + (ib & 3)];
      float r = sigf (bf2f(gi[g +        ia]) + aRa + bRa);
      float z = sigf (bf2f(gi[g +  512 + ia]) + aZa + bZa);
      float n = tanh_(bf2f(gi[g + 1024 + ia]) + r * (aNa + bNa));
      float h2a = z * hoa + (1.f - z) * n;
      r = sigf (bf2f(gi[g +        ib]) + aRb + bRb);
      z = sigf (bf2f(gi[g +  512 + ib]) + aZb + bZb);
      n = tanh_(bf2f(gi[g + 1024 + ib]) + r * (aNb + bNb));
      float h2b = z * hob + (1.f - z) * n;
      enc_outs[((size_t)b * 256 + t) * 512 + ia] = f2bf(h2a);
      enc_outs[((size_t)b * 256 + t) * 512 + ib] = f2bf(h2b);
      h2t[i_l][b] = h2a; h2t[i_l + 4][b] = h2b;
    }
    __syncthreads();
    if (tid < 128) {   // slot t+1: 128 atomic u32 stores/block
      int p = tid >> 5, bq = tid & 31;
      u32 pk = (u32)f2bf(h2t[2*p][bq]) | ((u32)f2bf(h2t[2*p+1][bq]) << 16);
      ast_u((u32*)(hring + (size_t)(t + 1) * 16384) + bq * 256 + bid * 4 + p, pk);
    }
    bt += 64; grid_bar(bar, bt);
  }
}

// ---------- K3: enc_proj = enc_outs @ attn_W2^T + b2 ----------
__global__ __launch_bounds__(256)
void k_proj(const u16* __restrict__ A, const float* __restrict__ W,
            const float* __restrict__ bias, u16* __restrict__ Out)
{
  __shared__ float es[16][HH];
  const int tid = threadIdx.x;
  const int r0 = blockIdx.y * 16;
  #pragma unroll
  for (int j = 0; j < 4; ++j) {
    int u = j * 256 + tid;
    int row = u >> 6, k = (u & 63) * 8;
    float d[8]; unp8(d, *(const uint4*)(A + (size_t)(r0 + row) * HH + k));
    *(float4*)&es[row][k]     = make_float4(d[0],d[1],d[2],d[3]);
    *(float4*)&es[row][k + 4] = make_float4(d[4],d[5],d[6],d[7]);
  }
  __syncthreads();
  const int jl = tid & 63;
  const int rg = (tid >> 6) << 2;
  const int jbase = blockIdx.x * 256 + jl;
  float acc[4][4];
  #pragma unroll
  for (int jj = 0; jj < 4; ++jj) {
    float bv = bias[jbase + jj * 64];
    #pragma unroll
    for (int rr = 0; rr < 4; ++rr) acc[jj][rr] = bv;
  }
  const float4* w0 = (const float4*)(W + (size_t)(jbase      ) * HH);
  const float4* w1 = (const float4*)(W + (size_t)(jbase +  64) * HH);
  const float4* w2 = (const float4*)(W + (size_t)(jbase + 128) * HH);
  const float4* w3 = (const float4*)(W + (size_t)(jbase + 192) * HH);
  for (int k4 = 0; k4 < HH / 4; ++k4) {
    float4 wv0 = w0[k4], wv1 = w1[k4], wv2 = w2[k4], wv3 = w3[k4];
    #pragma unroll
    for (int rr = 0; rr < 4; ++rr) {
      float4 e = *(const float4*)&es[rg + rr][k4 * 4];
      acc[0][rr] = dot4(acc[0][rr], wv0, e);
      acc[1][rr] = dot4(acc[1][rr], wv1, e);
      acc[2][rr] = dot4(acc[2][rr], wv2, e);
      acc[3][rr] = dot4(acc[3][rr], wv3, e);
    }
  }
  #pragma unroll
  for (int rr = 0; rr < 4; ++rr)
    #pragma unroll
    for (int jj = 0; jj < 4; ++jj)
      Out[(size_t)(r0 + rg + rr) * HH + jbase + jj * 64] = f2bf(acc[jj][rr]);
}

// ---------- K4: Wih[:,256:768] -> bf16 [1536][512] ----------
__global__ __launch_bounds__(256)
void k_cvt_s(const float* __restrict__ Wih, u16* __restrict__ wctx)
{
  int gidx = blockIdx.x * 256 + threadIdx.x;     // 98304 total
  int i = gidx * 8;
  int row = i >> 9, col = i & 511;
  const float* src = Wih + (size_t)row * 768 + 256 + col;
  float4 a = *(const float4*)src, b = *(const float4*)(src + 4);
  union { uint4 v; u16 s[8]; } u;
  u.s[0]=f2bf(a.x); u.s[1]=f2bf(a.y); u.s[2]=f2bf(a.z); u.s[3]=f2bf(a.w);
  u.s[4]=f2bf(b.x); u.s[5]=f2bf(b.y); u.s[6]=f2bf(b.z); u.s[7]=f2bf(b.w);
  *(uint4*)(wctx + i) = u.v;
}

// ---------- K5: WE[row][bs] = wctx[row] . enc_outs[bs]  (MFMA, bf16 out) --
__global__ __launch_bounds__(256)
void k_we(const u16* __restrict__ A, const u16* __restrict__ B,
          u16* __restrict__ WEo)
{
  __shared__ u16 Al[64 * 512];
  const int tid = threadIdx.x;
  const int r0 = blockIdx.x * 64;   // 24 blocks over 1536 rows
  const int v0 = blockIdx.y * 64;   // 128 blocks over 8192 bs
  {
    const uint4* src = (const uint4*)(A + (size_t)r0 * 512);
    uint4* dst = (uint4*)Al;
    #pragma unroll
    for (int j = 0; j < 16; ++j) {
      int idx = j * 256 + tid;
      int row = idx >> 6, g = idx & 63;
      dst[(row << 6) | (g ^ (row & 7))] = src[idx];
    }
  }
  const int w  = tid >> 6, l = tid & 63;
  const int lr = l & 15,  qk = l >> 4;
  const int v  = v0 + w * 16 + lr;
  frag bfr[16];
  {
    const u16* wrow = B + (size_t)v * 512 + qk * 8;
    #pragma unroll
    for (int ks = 0; ks < 16; ++ks)
      bfr[ks] = *(const frag*)(wrow + ks * 32);
  }
  __syncthreads();
  f32x4v acc[4];
  #pragma unroll
  for (int mt = 0; mt < 4; ++mt) acc[mt] = (f32x4v){0.f, 0.f, 0.f, 0.f};
  #pragma unroll
  for (int ks = 0; ks < 16; ++ks) {
    #pragma unroll
    for (int mt = 0; mt < 4; ++mt) {
      const int row = mt * 16 + lr;
      const int gr  = ks * 4 + qk;
      frag a = *(const frag*)&Al[(row << 9) | ((gr ^ (row & 7)) << 3)];
      acc[mt] = __builtin_amdgcn_mfma_f32_16x16x32_bf16(a, bfr[ks], acc[mt], 0, 0, 0);
    }
  }
  #pragma unroll
  for (int mt = 0; mt < 4; ++mt)
    #pragma unroll
    for (int reg = 0; reg < 4; ++reg) {
      const int r = r0 + mt * 16 + qk * 4 + reg;
      WEo[(size_t)r * 8192 + v] = f2bf(acc[mt][reg]);
    }
}

// ---------- K6: decoder scan — persistent, 64 blocks, 3 bars/step -------
// P1(i): a | P2(b,sh): scores->e,partial-S | P3(i): wts-stage + WE-dot + GRU
__global__ __launch_bounds__(256)
void k_dec_scan(const u16* __restrict__ gi, u16* __restrict__ hring,
                const float* __restrict__ W1, const float* __restrict__ b1,
                const float* __restrict__ av,
                const u16* __restrict__ enc_proj, const u16* __restrict__ WE,
                const float* __restrict__ Whh, const float* __restrict__ bhh,
                float* __restrict__ aring, float* __restrict__ wtring,
                float* __restrict__ sring2, u16* __restrict__ h2bf,
                u32* __restrict__ bar)
{
  __shared__ float hs[32 * 512];    // 64 KB, swizzled
  __shared__ float wtl[32 * WP];    // 33.3 KB (normalized wts)
  __shared__ u16  wlds[32 * 512];   // 32 KB bf16: rows 0-7 W1, 8-31 Whh
  __shared__ float as_[512], vs_[512];
  __shared__ float scpart[4], rs[32];
  __shared__ float h2t[8][32];
  const int tid = threadIdx.x;
  const int bid = blockIdx.x;
  const int i_l = tid >> 6, lane = tid & 63, b = lane >> 1, kh = lane & 1;
  const int i0 = bid * 8;
  const int ia = i0 + i_l, ib = i0 + i_l + 4;
  const int pb = bid >> 1, sh = bid & 1;
  vs_[tid] = av[tid]; vs_[tid + 256] = av[tid + 256];
  #pragma unroll
  for (int j = 0; j < 16; ++j) {    // stage 32 rows f32 -> bf16
    int idx = j * 256 + tid;
    int row = idx >> 7, k4 = idx & 127;
    const float* src;
    if (row < 8) src = W1 + (size_t)(i0 + row) * 512 + k4 * 4;
    else { int rr = row - 8; int g = rr >> 3, il8 = rr & 7;
           src = Whh + (size_t)(g * 512 + i0 + il8) * 512 + k4 * 4; }
    float4 w = *(const float4*)src;
    int f = row * 512 + k4 * 4;
    wlds[f] = f2bf(w.x); wlds[f+1] = f2bf(w.y); wlds[f+2] = f2bf(w.z); wlds[f+3] = f2bf(w.w);
  }
  const u16* w1a = wlds + (     i_l) * 512 + kh * 256;
  const u16* w1b = wlds + ( 4 + i_l) * 512 + kh * 256;
  const u16* wRa = wlds + ( 8 + i_l) * 512 + kh * 256;
  const u16* wZa = wlds + (16 + i_l) * 512 + kh * 256;
  const u16* wNa = wlds + (24 + i_l) * 512 + kh * 256;
  const u16* wRb = wlds + (12 + i_l) * 512 + kh * 256;
  const u16* wZb = wlds + (20 + i_l) * 512 + kh * 256;
  const u16* wNb = wlds + (28 + i_l) * 512 + kh * 256;
  const float bRa = bhh[ia], bZa = bhh[ia + 512], bNa = bhh[ia + 1024];
  const float bRb = bhh[ib], bZb = bhh[ib + 512], bNb = bhh[ib + 1024];
  const float b1a = b1[ia], b1b = b1[ib];
  u32 bt = 0;
  for (int t = 0; t < TT; ++t) {
    // stage h (swizzled)
    const u64* hsrc = (const u64*)(hring + (size_t)(256 + t) * 16384);
    #pragma unroll
    for (int j = 0; j < 16; ++j) {
      int idx = j * 256 + tid;
      u64 v = ald_u8(hsrc + idx);
      int bb = idx >> 7, gr = idx & 127;
      *(float4*)&hs[bb * 512 + ((gr ^ (bb & 7)) << 2)] = unp4(v);
    }
    __syncthreads();
    // ---- P1: a = b1 + h.W1 for 2 i's ----
    {
      float a0 = 0.f, a1 = 0.f;
      for (int k8 = 0; k8 < 32; ++k8) {
        int g0 = kh * 64 + k8 * 2;
        float4 h0 = *(const float4*)&hs[b * 512 + ((g0 ^ (b & 7)) << 2)];
        float4 h1 = *(const float4*)&hs[b * 512 + (((g0 + 1) ^ (b & 7)) << 2)];
        float wf[8];
        unp8(wf, *(const uint4*)(w1a + k8 * 8)); a0 = fma8(a0, wf, h0, h1);
        unp8(wf, *(const uint4*)(w1b + k8 * 8)); a1 = fma8(a1, wf, h0, h1);
      }
      a0 += __shfl_xor(a0, 1); a1 += __shfl_xor(a1, 1);
      if (kh == 0) {
        ast_f(&aring[(size_t)t * 16384 + b * 512 + ia], a0 + b1a);
        ast_f(&aring[(size_t)t * 16384 + b * 512 + ib], a1 + b1b);
      }
    }
    bt += 64; grid_bar(bar, bt);
    // ---- P2 (pb,sh): scores -> e -> wtring + partial S ----
    {
      u64 v = ald_u8((const u64*)(aring + (size_t)t * 16384 + pb * 512) + tid);
      union { u64 q; float f[2]; } cv; cv.q = v;
      as_[2 * tid] = cv.f[0]; as_[2 * tid + 1] = cv.f[1];
    }
    __syncthreads();
    {
      const int s_l = tid >> 1, kp = tid & 1;
      const u16* pr = enc_proj + ((size_t)(pb * 256 + sh * 128 + s_l)) * 512 + kp * 256;
      const float* ak = as_ + kp * 256;
      const float* vk = vs_ + kp * 256;
      float acc = 0.f;
      for (int k8 = 0; k8 < 32; ++k8) {
        float d[8]; unp8(d, *(const uint4*)(pr + k8 * 8));
        #pragma unroll
        for (int e = 0; e < 8; ++e)
          acc += vk[k8 * 8 + e] * tanh_(d[e] + ak[k8 * 8 + e]);
      }
      acc += __shfl_xor(acc, 1);
      float ev = (kp == 0) ? __expf(acc) : 0.f;     // bounded: no max-shift
      if (kp == 0)
        ast_f(&wtring[(size_t)t * 8192 + pb * 256 + sh * 128 + s_l], ev);
      float su = ev;
      #pragma unroll
      for (int d = 1; d < 64; d <<= 1) su += __shfl_xor(su, d);
      if (lane == 0) scpart[tid >> 6] = su;
    }
    __syncthreads();
    if (tid == 0)
      ast_f(&sring2[t * 64 + sh * 32 + pb],
            (scpart[0] + scpart[1]) + (scpart[2] + scpart[3]));
    bt += 64; grid_bar(bar, bt);
    // ---- P3: normalize wts into LDS, WE-dot + GRU ----
    if (tid < 32)
      rs[tid] = 1.f / (ald_f(&sring2[t * 64 + tid]) + ald_f(&sring2[t * 64 + 32 + tid]));
    __syncthreads();
    #pragma unroll
    for (int j = 0; j < 16; ++j) {      // 4096 u64 wts stage, normalized
      int idx = j * 256 + tid;
      u64 v = ald_u8((const u64*)wtring + (size_t)t * 4096 + idx);
      union { u64 q; float f[2]; } cv; cv.q = v;
      int bb = idx >> 7, sp = (idx & 127) * 2;
      float r = rs[bb];
      wtl[bb * WP + sp] = cv.f[0] * r; wtl[bb * WP + sp + 1] = cv.f[1] * r;
    }
    __syncthreads();
    {
      // h-side gemv (LDS)
      float vRa=0,vZa=0,vNa=0,vRb=0,vZb=0,vNb=0;
      for (int k8 = 0; k8 < 32; ++k8) {
        int g0 = kh * 64 + k8 * 2;
        float4 h0 = *(const float4*)&hs[b * 512 + ((g0 ^ (b & 7)) << 2)];
        float4 h1 = *(const float4*)&hs[b * 512 + (((g0 + 1) ^ (b & 7)) << 2)];
        float wf[8];
        unp8(wf, *(const uint4*)(wRa + k8 * 8)); vRa = fma8(vRa, wf, h0, h1);
        unp8(wf, *(const uint4*)(wZa + k8 * 8)); vZa = fma8(vZa, wf, h0, h1);
        unp8(wf, *(const uint4*)(wNa + k8 * 8)); vNa = fma8(vNa, wf, h0, h1);
        unp8(wf, *(const uint4*)(wRb + k8 * 8)); vRb = fma8(vRb, wf, h0, h1);
        unp8(wf, *(const uint4*)(wZb + k8 * 8)); vZb = fma8(vZb, wf, h0, h1);
        unp8(wf, *(const uint4*)(wNb + k8 * 8)); vNb = fma8(vNb, wf, h0, h1);
      }
      // WE-side: cX = sum_s wts[b,s] * WE[row][b][s] over kh-half of s
      const size_t web = (size_t)b * 256 + kh * 128;
      const u16* eRa = WE + (size_t)(       ia) * 8192 + web;
      const u16* eZa = WE + (size_t)( 512 + ia) * 8192 + web;
      const u16* eNa = WE + (size_t)(1024 + ia) * 8192 + web;
      const u16* eRb = WE + (size_t)(       ib) * 8192 + web;
      const u16* eZb = WE + (size_t)( 512 + ib) * 8192 + web;
      const u16* eNb = WE + (size_t)(1024 + ib) * 8192 + web;
      const float* wrow = wtl + b * WP + kh * 128;
      for (int c = 0; c < 16; ++c) {
        float4 t0 = *(const float4*)&wrow[c * 8];
        float4 t1 = *(const float4*)&wrow[c * 8 + 4];
        float wf[8];
        unp8(wf, *(const uint4*)(eRa + c * 8)); vRa = fma8(vRa, wf, t0, t1);
        unp8(wf, *(const uint4*)(eZa + c * 8)); vZa = fma8(vZa, wf, t0, t1);
        unp8(wf, *(const uint4*)(eNa + c * 8)); vNa = fma8(vNa, wf, t0, t1);
        unp8(wf, *(const uint4*)(eRb + c * 8)); vRb = fma8(vRb, wf, t0, t1);
        unp8(wf, *(const uint4*)(eZb + c * 8)); vZb = fma8(vZb, wf, t0, t1);
        unp8(wf, *(const uint4*)(eNb + c * 8)); vNb = fma8(vNb, wf, t0, t1);
      }
      vRa += __shfl_xor(vRa,1); vZa += __shfl_xor(vZa,1); vNa += __shfl_xor(vNa,1);
      vRb += __shfl_xor(vRb,1); vZb += __shfl_xor(vZb,1); vNb += __shfl_xor(vNb,1);
      if (kh == 0) {
        const size_t g = ((size_t)t * 32 + b) * G3;
        float hoa = hs[b * 512 + (((ia >> 2) ^ (b & 7)) << 2) + (ia & 3)];
        float hob = hs[b * 512 + (((ib >> 2) ^ (b & 7)) << 2) + (ib & 3)];
        float r = sigf (bf2f(gi[g +        ia]) + vRa + bRa);
        float z = sigf (bf2f(gi[g +  512 + ia]) + vZa + bZa);
        float n = tanh_(bf2f(gi[g + 1024 + ia]) + vNa + r * bNa + (r - 1.f) * 0.f);
        // NOTE: PyTorch form: n = tanh(gin + r*(hn_part + bhn)); vNa already
        // mixes h-side and ctx-side; recompute properly below.
        // (replaced by exact computation)
        (void)n;
        // exact: separate h-side bNa handling requires r* on (hN + bN); but
        // vNa = hN + cN combined. Use algebra: r*(hN + bN) + cN is needed.
        // We must keep hN and cN separate for the n-gate!
        r = r; z = z;
        float h2a, h2b;
        { // recompute with separated accumulators is below (see vN split)
          h2a = 0.f; h2b = 0.f;
        }
        (void)h2a; (void)h2b;
      }
      // --- correct n-gate handling: hN and cN must stay separate ---
      // (the merged-sum shortcut above is invalid for the n gate)
      if (kh == 0) { }
    }
    // The n-gate needs r*(hN+bN)+cN, so redo reduction with hN/cN separate:
    __syncthreads();
    bt += 64; grid_bar(bar, bt);
    (void)h2bf;
  }
}

// ---------- K7: fcW f32 -> bf16 (one-time) ----------
__global__ __launch_bounds__(256)
void k_cvt(const float* __restrict__ in, u16* __restrict__ out)
{
  size_t i = ((size_t)blockIdx.x * 256 + threadIdx.x) * 8;
  float4 a = *(const float4*)(in + i);
  float4 b = *(const float4*)(in + i + 4);
  union { uint4 v; u16 s[8]; } u;
  u.s[0]=f2bf(a.x); u.s[1]=f2bf(a.y); u.s[2]=f2bf(a.z); u.s[3]=f2bf(a.w);
  u.s[4]=f2bf(b.x); u.s[5]=f2bf(b.y); u.s[6]=f2bf(b.z); u.s[7]=f2bf(b.w);
  *(uint4*)(out + i) = u.v;
}

// ---------- K8: logits via bf16 MFMA (proven) ----------
__global__ __launch_bounds__(256)
void k_logits_mfma(const u16* __restrict__ A, const u16* __restrict__ Wb,
                   const float* __restrict__ bias, float* __restrict__ out)
{
  __shared__ u16 Al[64 * 512];
  const int tid = threadIdx.x;
  const int r0 = blockIdx.x * 64;
  const int v0 = blockIdx.y * 64;
  {
    const uint4* src = (const uint4*)(A + (size_t)r0 * 512);
    uint4* dst = (uint4*)Al;
    #pragma unroll
    for (int j = 0; j < 16; ++j) {
      int idx = j * 256 + tid;
      int row = idx >> 6, g = idx & 63;
      dst[(row << 6) | (g ^ (row & 7))] = src[idx];
    }
  }
  const int w  = tid >> 6, l = tid & 63;
  const int lr = l & 15,  qk = l >> 4;
  const int v  = v0 + w * 16 + lr;
  frag bfr[16];
  {
    const u16* wrow = Wb + (size_t)v * 512 + qk * 8;
    #pragma unroll
    for (int ks = 0; ks < 16; ++ks)
      bfr[ks] = *(const frag*)(wrow + ks * 32);
  }
  const float bv = bias[v];
  __syncthreads();
  f32x4v acc[4];
  #pragma unroll
  for (int mt = 0; mt < 4; ++mt) acc[mt] = (f32x4v){0.f, 0.f, 0.f, 0.f};
  #pragma unroll
  for (int ks = 0; ks < 16; ++ks) {
    #pragma unroll
    for (int mt = 0; mt < 4; ++mt) {
      const int row = mt * 16 + lr;
      const int gr  = ks * 4 + qk;
      frag a = *(const frag*)&Al[(row << 9) | ((gr ^ (row & 7)) << 3)];
      acc[mt] = __builtin_amdgcn_mfma_f32_16x16x32_bf16(a, bfr[ks], acc[mt], 0, 0, 0);
    }
  }
  #pragma unroll
  for (int mt = 0; mt < 4; ++mt)
    #pragma unroll
    for (int reg = 0; reg < 4; ++reg) {
      const int r = r0 + mt * 16 + qk * 4 + reg;
      out[(size_t)(r & 31) * 64 * VV + (size_t)(r >> 5) * VV + v] = acc[mt][reg] + bv;
    }
}

// ============================================================================
// NOTE: k_dec_scan above contains an invalid merged n-gate path; the real
// decoder used below is k_dec_scan2 with hN kept separate (r*(hN+bN)+cN).
// ============================================================================
__global__ __launch_bounds__(256)
void k_dec_scan2(const u16* __restrict__ gi, u16* __restrict__ hring,
                 const float* __restrict__ W1, const float* __restrict__ b1,
                 const float* __restrict__ av,
                 const u16* __restrict__ enc_proj, const u16* __restrict__ WE,
                 const float* __restrict__ Whh, const float* __restrict__ bhh,
                 float* __restrict__ aring, float* __restrict__ wtring,
                 float* __restrict__ sring2, u16* __restrict__ h2bf,
                 u32* __restrict__ bar)
{
  __shared__ float hs[32 * 512];
  __shared__ float wtl[32 * WP];
  __shared__ u16  wlds[32 * 512];
  __shared__ float as_[512], vs_[512];
  __shared__ float scpart[4], rs[32];
  __shared__ float h2t[8][32];
  const int tid = threadIdx.x;
  const int bid = blockIdx.x;
  const int i_l = tid >> 6, lane = tid & 63, b = lane >> 1, kh = lane & 1;
  const int i0 = bid * 8;
  const int ia = i0 + i_l, ib = i0 + i_l + 4;
  const int pb = bid >> 1, sh = bid & 1;
  vs_[tid] = av[tid]; vs_[tid + 256] = av[tid + 256];
  #pragma unroll
  for (int j = 0; j < 16; ++j) {
    int idx = j * 256 + tid;
    int row = idx >> 7, k4 = idx & 127;
    const float* src;
    if (row < 8) src = W1 + (size_t)(i0 + row) * 512 + k4 * 4;
    else { int rr = row - 8; int g = rr >> 3, il8 = rr & 7;
           src = Whh + (size_t)(g * 512 + i0 + il8) * 512 + k4 * 4; }
    float4 w = *(const float4*)src;
    int f = row * 512 + k4 * 4;
    wlds[f] = f2bf(w.x); wlds[f+1] = f2bf(w.y); wlds[f+2] = f2bf(w.z); wlds[f+3] = f2bf(w.w);
  }
  const u16* w1a = wlds + (     i_l) * 512 + kh * 256;
  const u16* w1b = wlds + ( 4 + i_l) * 512 + kh * 256;
  const u16* wRa = wlds + ( 8 + i_l) * 512 + kh * 256;
  const u16* wRb = wlds + (12 + i_l) * 512 + kh * 256;
  const u16* wZa = wlds + (16 + i_l) * 512 + kh * 256;
  const u16* wZb = wlds + (20 + i_l) * 512 + kh * 256;
  const u16* wNa = wlds + (24 + i_l) * 512 + kh * 256;
  const u16* wNb = wlds + (28 + i_l) * 512 + kh * 256;
  const float bRa = bhh[ia], bZa = bhh[ia + 512], bNa = bhh[ia + 1024];
  const float bRb = bhh[ib], bZb = bhh[ib + 512], bNb = bhh[ib + 1024];
  const float b1a = b1[ia], b1b = b1[ib];
  u32 bt = 0;
  for (int t = 0; t < TT; ++t) {
    const u64* hsrc = (const u64*)(hring + (size_t)(256 + t) * 16384);
    #pragma unroll
    for (int j = 0; j < 16; ++j) {
      int idx = j * 256 + tid;
      u64 v = ald_u8(hsrc + idx);
      int bb = idx >> 7, gr = idx & 127;
      *(float4*)&hs[bb * 512 + ((gr ^ (bb & 7)) << 2)] = unp4(v);
    }
    __syncthreads();
    // P1
    {
      float a0 = 0.f, a1 = 0.f;
      for (int k8 = 0; k8 < 32; ++k8) {
        int g0 = kh * 64 + k8 * 2;
        float4 h0 = *(const float4*)&hs[b * 512 + ((g0 ^ (b & 7)) << 2)];
        float4 h1 = *(const float4*)&hs[b * 512 + (((g0 + 1) ^ (b & 7)) << 2)];
        float wf[8];
        unp8(wf, *(const uint4*)(w1a + k8 * 8)); a0 = fma8(a0, wf, h0, h1);
        unp8(wf, *(const uint4*)(w1b + k8 * 8)); a1 = fma8(a1, wf, h0, h1);
      }
      a0 += __shfl_xor(a0, 1); a1 += __shfl_xor(a1, 1);
      if (kh == 0) {
        ast_f(&aring[(size_t)t * 16384 + b * 512 + ia], a0 + b1a);
        ast_f(&aring[(size_t)t * 16384 + b * 512 + ib], a1 + b1b);
      }
    }
    bt += 64; grid_bar(bar, bt);
    // P2
    {
      u64 v = ald_u8((const u64*)(aring + (size_t)t * 16384 + pb * 512) + tid);
      union { u64 q; float f[2]; } cv; cv.q = v;
      as_[2 * tid] = cv.f[0]; as_[2 * tid + 1] = cv.f[1];
    }
    __syncthreads();
    {
      const int s_l = tid >> 1, kp = tid & 1;
      const u16* pr = enc_proj + ((size_t)(pb * 256 + sh * 128 + s_l)) * 512 + kp * 256;
      const float* ak = as_ + kp * 256;
      const float* vk = vs_ + kp * 256;
      float acc = 0.f;
      for (int k8 = 0; k8 < 32; ++k8) {
        float d[8]; unp8(d, *(const uint4*)(pr + k8 * 8));
        #pragma unroll
        for (int e = 0; e < 8; ++e)
          acc += vk[k8 * 8 + e] * tanh_(d[e] + ak[k8 * 8 + e]);
      }
      acc += __shfl_xor(acc, 1);
      float ev = (kp == 0) ? __expf(acc) : 0.f;
      if (kp == 0)
        ast_f(&wtring[(size_t)t * 8192 + pb * 256 + sh * 128 + s_l], ev);
      float su = ev;
      #pragma unroll
      for (int d = 1; d < 64; d <<= 1) su += __shfl_xor(su, d);
      if (lane == 0) scpart[tid >> 6] = su;
    }
    __syncthreads();
    if (tid == 0)
      ast_f(&sring2[t * 64 + sh * 32 + pb],
            (scpart[0] + scpart[1]) + (scpart[2] + scpart[3]));
    bt += 64; grid_bar(bar, bt);
    // P3
    if (tid < 32)
      rs[tid] = 1.f / (ald_f(&sring2[t * 64 + tid]) + ald_f(&sring2[t * 64 + 32 + tid]));
    __syncthreads();
    #pragma unroll
    for (int j = 0; j < 16; ++j) {
      int idx = j * 256 + tid;
      u64 v = ald_u8((const u64*)wtring + (size_t)t * 4096 + idx);
      union { u64 q; float f[2]; } cv; cv.q = v;
      int bb = idx >> 7, sp = (idx & 127) * 2;
      float r = rs[bb];
      wtl[bb * WP + sp] = cv.f[0] * r; wtl[bb * WP + sp + 1] = cv.f[1] * r;
    }
    __syncthreads();
    {
      float hRa=0,hZa=0,hNa=0,hRb=0,hZb=0,hNb=0;     // h-side (Whh)
      for (int k8 = 0; k8 < 32; ++k8) {
        int g0 = kh * 64 + k8 * 2;
        float4 h0 = *(const float4*)&hs[b * 512 + ((g0 ^ (b & 7)) << 2)];
        float4 h1 = *(const float4*)&hs[b * 512 + (((g0 + 1) ^ (b & 7)) << 2)];
        float wf[8];
        unp8(wf, *(const uint4*)(wRa + k8 * 8)); hRa = fma8(hRa, wf, h0, h1);
        unp8(wf, *(const uint4*)(wZa + k8 * 8)); hZa = fma8(hZa, wf, h0, h1);
        unp8(wf, *(const uint4*)(wNa + k8 * 8)); hNa = fma8(hNa, wf, h0, h1);
        unp8(wf, *(const uint4*)(wRb + k8 * 8)); hRb = fma8(hRb, wf, h0, h1);
        unp8(wf, *(const uint4*)(wZb + k8 * 8)); hZb = fma8(hZb, wf, h0, h1);
        unp8(wf, *(const uint4*)(wNb + k8 * 8)); hNb = fma8(hNb, wf, h0, h1);
      }
      float cRa=0,cZa=0,cNa=0,cRb=0,cZb=0,cNb=0;     // ctx-side (WE)
      const size_t web = (size_t)b * 256 + kh * 128;
      const u16* eRa = WE + (size_t)(       ia) * 8192 + web;
      const u16* eZa = WE + (size_t)( 512 + ia) * 8192 + web;
      const u16* eNa = WE + (size_t)(1024 + ia) * 8192 + web;
      const u16* eRb = WE + (size_t)(       ib) * 8192 + web;
      const u16* eZb = WE + (size_t)( 512 + ib) * 8192 + web;
      const u16* eNb = WE + (size_t)(1024 + ib) * 8192 + web;
      const float* wrow = wtl + b * WP + kh * 128;
      for (int c = 0; c < 16; ++c) {
        float4 t0 = *(const float4*)&wrow[c * 8];
        float4 t1 = *(const float4*)&wrow[c * 8 + 4];
        float wf[8];
        unp8(wf, *(const uint4*)(eRa + c * 8)); cRa = fma8(cRa, wf, t0, t1);
        unp8(wf, *(const uint4*)(eZa + c * 8)); cZa = fma8(cZa, wf, t0, t1);
        unp8(wf, *(const uint4*)(eNa + c * 8)); cNa = fma8(cNa, wf, t0, t1);
        unp8(wf, *(const uint4*)(eRb + c * 8)); cRb = fma8(cRb, wf, t0, t1);
        unp8(wf, *(const uint4*)(eZb + c * 8)); cZb = fma8(cZb, wf, t0, t1);
        unp8(wf, *(const uint4*)(eNb + c * 8)); cNb = fma8(cNb, wf, t0, t1);
      }
      // pairwise reductions (keep hN and cN separate for the n-gate)
      hRa += __shfl_xor(hRa,1); hZa += __shfl_xor(hZa,1); hNa += __shfl_xor(hNa,1);
      hRb += __shfl_xor(hRb,1); hZb += __shfl_xor(hZb,1); hNb += __shfl_xor(hNb,1);
      cRa += __shfl_xor(cRa,1); cZa += __shfl_xor(cZa,1); cNa += __shfl_xor(cNa,1);
      cRb += __shfl_xor(cRb,1); cZb += __shfl_xor(cZb,1); cNb += __shfl_xor(cNb,1);
      if (kh == 0) {
        const size_t g = ((size_t)t * 32 + b) * G3;
        float hoa = hs[b * 512 + (((ia >> 2) ^ (b & 7)) << 2) + (ia & 3)];
        float hob = hs[b * 512 + (((ib >> 2) ^ (b & 7)) << 2) + (ib & 3)];
        float r = sigf (bf2f(gi[g +        ia]) + cRa + hRa + bRa);
        float z = sigf (bf2f(gi[g +  512 + ia]) + cZa + hZa + bZa);
        float n = tanh_(bf2f(gi[g + 1024 + ia]) + cNa + r * (hNa + bNa));
        float h2a = z * hoa + (1.f - z) * n;
        r = sigf (bf2f(gi[g +        ib]) + cRb + hRb + bRb);
        z = sigf (bf2f(gi[g +  512 + ib]) + cZb + hZb + bZb);
        n = tanh_(bf2f(gi[g + 1024 + ib]) + cNb + r * (hNb + bNb));
        float h2b = z * hob + (1.f - z) * n;
        h2bf[((size_t)t * 32 + b) * 512 + ia] = f2bf(h2a);
        h2bf[((size_t)t * 32 + b) * 512 + ib] = f2bf(h2b);
        h2t[i_l][b] = h2a; h2t[i_l + 4][b] = h2b;
      }
    }
    __syncthreads();
    if (tid < 128) {
      int p = tid >> 5, bq = tid & 31;
      u32 pk = (u32)f2bf(h2t[2*p][bq]) | ((u32)f2bf(h2t[2*p+1][bq]) << 16);
      ast_u((u32*)(hring + (size_t)(257 + t) * 16384) + bq * 256 + bid * 4 + p, pk);
    }
    bt += 64; grid_bar(bar, bt);
  }
}

// ---------- launch ----------
extern "C" void kernel_launch(void* const* d_in, const int* in_sizes, int n_in,
                              void* d_out, int out_size, void* d_ws, size_t ws_size,
                              hipStream_t stream) {
  (void)in_sizes; (void)n_in; (void)out_size; (void)ws_size;
  const int*   src  = (const int*)d_in[0];
  const int*   tgt  = (const int*)d_in[1];
  const float* eemb = (const float*)d_in[2];
  const float* eWih = (const float*)d_in[3];
  const float* eWhh = (const float*)d_in[4];
  const float* ebih = (const float*)d_in[5];
  const float* ebhh = (const float*)d_in[6];
  const float* demb = (const float*)d_in[7];
  const float* aW1  = (const float*)d_in[8];
  const float* ab1  = (const float*)d_in[9];
  const float* aW2  = (const float*)d_in[10];
  const float* ab2  = (const float*)d_in[11];
  const float* av   = (const float*)d_in[12];
  const float* dWih = (const float*)d_in[13];
  const float* dWhh = (const float*)d_in[14];
  const float* dbih = (const float*)d_in[15];
  const float* dbhh = (const float*)d_in[16];
  const float* fcW  = (const float*)d_in[17];
  const float* fcb  = (const float*)d_in[18];
  float* out = (float*)d_out;

  // workspace carve (~66 MiB)
  float* aring   = (float*)d_ws;                 // 64x16384 f32 (4 MiB)
  float* wtring  = aring + 1048576;              // 64x8192 f32 (2 MiB)
  float* sring2  = wtring + 524288;              // 64x64 f32
  u32*   bars    = (u32*)(sring2 + 4096);        // 8 u32
  u16*  hring    = (u16*)(bars + 8);             // 321x16384 u16 (10.5 MiB)
  u16*  h2bf     = hring + 5259264;              // 1,048,576 u16
  u16*  wctx     = h2bf + 1048576;               //   786,432 u16 (1.5 MiB)
  u16*  gi_enc   = wctx + 786432;                // 12,582,912 u16 (24 MiB)
  u16*  gi_dec   = gi_enc + 12582912;            //  3,145,728 u16
  u16*  enc_outs = gi_dec + 3145728;             //  4,194,304 u16
  u16*  enc_proj = enc_outs + 4194304;           //  4,194,304 u16
  u16*  WE       = gi_enc;   // 1536*8192 = 12,582,912 u16 — exact alias
  u16*  wbf      = gi_enc;   // fcW bf16 (16.38M u16) spans gi_enc+gi_dec+...

  hipMemsetAsync(hring, 0, 16384 * sizeof(u16), stream);   // h0 slot
  hipMemsetAsync(bars, 0, 8 * sizeof(u32), stream);        // barrier counters

  k_embed_gemm<<<dim3(6, 512), 256, 0, stream>>>(src, SS, eemb, eWih, EE,  ebih, gi_enc);
  k_embed_gemm<<<dim3(6, 128), 256, 0, stream>>>(tgt, TT, demb, dWih, 768, dbih, gi_dec);

  k_enc_scan<<<64, 256, 0, stream>>>(gi_enc, eWhh, ebhh, hring, enc_outs, bars + 0);

  k_proj<<<dim3(2, 512), 256, 0, stream>>>(enc_outs, aW2, ab2, enc_proj);

  k_cvt_s<<<384, 256, 0, stream>>>(dWih, wctx);
  k_we<<<dim3(24, 128), 256, 0, stream>>>(wctx, enc_outs, WE);  // overwrites gi_enc

  k_dec_scan2<<<64, 256, 0, stream>>>(gi_dec, hring, aW1, ab1, av,
                                      enc_proj, WE, dWhh, dbhh,
                                      aring, wtring, sring2, h2bf, bars + 1);

  k_cvt<<<8000, 256, 0, stream>>>(fcW, wbf);

  k_logits_mfma<<<dim3(32, 500), 256, 0, stream>>>(h2bf, wbf, fcb, out);
}

// Round 15
// 7251.337 us; speedup vs baseline: 1.1690x; 1.1690x over previous
//
#include <hip/hip_runtime.h>
#include <hip/hip_bf16.h>
#include <stdint.h>

#define DEV __device__ __forceinline__
typedef unsigned short u16;
typedef unsigned int   u32;
typedef unsigned long long u64;

static constexpr int SS = 256;   // src len
static constexpr int TT = 64;    // tgt len
static constexpr int EE = 256;   // embed dim
static constexpr int HH = 512;   // hidden
static constexpr int G3 = 1536;  // 3*H
static constexpr int VV = 32000; // vocab
static constexpr int HP = 516;   // padded f32 LDS row (4-way max)
static constexpr int CP = 520;   // padded u16 LDS row (4-way max)

using frag   = __attribute__((ext_vector_type(8))) short;  // 8 bf16
using f32x4v = __attribute__((ext_vector_type(4))) float;  // MFMA acc

// ---------- helpers ----------
DEV float blo(u32 u){ union{u32 i; float f;} x; x.i = u << 16;         return x.f; }
DEV float bhi(u32 u){ union{u32 i; float f;} x; x.i = u & 0xffff0000u; return x.f; }
DEV float bf2f(u16 u){ union{u32 i; float f;} x; x.i = ((u32)u) << 16; return x.f; }
DEV u16 f2bf(float f){ union{float f; u32 u;} v; v.f = f;
  u32 r = v.u + 0x7fffu + ((v.u >> 16) & 1u); return (u16)(r >> 16); }
DEV float sigf (float x){ return 1.0f / (1.0f + __expf(-x)); }
DEV float tanh_(float x){ return 1.0f - 2.0f / (1.0f + __expf(2.0f * x)); }
DEV void unp8(float* d, uint4 u){
  d[0]=blo(u.x); d[1]=bhi(u.x); d[2]=blo(u.y); d[3]=bhi(u.y);
  d[4]=blo(u.z); d[5]=bhi(u.z); d[6]=blo(u.w); d[7]=bhi(u.w);
}
DEV float4 unp4(u64 v){
  return make_float4(bf2f((u16)v), bf2f((u16)(v >> 16)),
                     bf2f((u16)(v >> 32)), bf2f((u16)(v >> 48)));
}
DEV float dot4(float acc, float4 w, float4 x){
  acc = fmaf(w.x,x.x,acc); acc = fmaf(w.y,x.y,acc);
  acc = fmaf(w.z,x.z,acc); acc = fmaf(w.w,x.w,acc);
  return acc;
}
DEV float fma44(float acc, float4 w0, float4 w1, float4 h0, float4 h1){
  return dot4(dot4(acc, w0, h0), w1, h1);
}
DEV float fma8(float acc, const float* w, float4 a, float4 b){
  acc = fmaf(w[0],a.x,acc); acc = fmaf(w[1],a.y,acc);
  acc = fmaf(w[2],a.z,acc); acc = fmaf(w[3],a.w,acc);
  acc = fmaf(w[4],b.x,acc); acc = fmaf(w[5],b.y,acc);
  acc = fmaf(w[6],b.z,acc); acc = fmaf(w[7],b.w,acc);
  return acc;
}
DEV float fma8p(float acc, const float* w, const float* x){
  #pragma unroll
  for (int e = 0; e < 8; ++e) acc = fmaf(w[e], x[e], acc);
  return acc;
}

// ---- agent-scope atomics: producers AND same-kernel cross-block consumers
// (r9/r13-proven rule; plain loads only across kernel boundaries).
DEV void  ast_f(float* p, float v){ __hip_atomic_store(p, v, __ATOMIC_RELAXED, __HIP_MEMORY_SCOPE_AGENT); }
DEV void  ast_u(u32* p, u32 v)    { __hip_atomic_store(p, v, __ATOMIC_RELAXED, __HIP_MEMORY_SCOPE_AGENT); }
DEV float ald_f(const float* p)   { return __hip_atomic_load((float*)p, __ATOMIC_RELAXED, __HIP_MEMORY_SCOPE_AGENT); }
DEV u64   ald_u8(const u64* p)    { return __hip_atomic_load((u64*)p,   __ATOMIC_RELAXED, __HIP_MEMORY_SCOPE_AGENT); }

DEV void grid_bar(u32* cnt, u32 target){
  __syncthreads();
  if (threadIdx.x == 0) {
    __hip_atomic_fetch_add(cnt, 1u, __ATOMIC_RELAXED, __HIP_MEMORY_SCOPE_AGENT);
    while (__hip_atomic_load(cnt, __ATOMIC_RELAXED, __HIP_MEMORY_SCOPE_AGENT) < target)
      __builtin_amdgcn_s_sleep(1);
  }
  __syncthreads();
}

// ---------- K1: gi = gather(emb, tok) @ W[:, :256]^T + bih  (bf16 out) ----
__global__ __launch_bounds__(256)
void k_embed_gemm(const int* __restrict__ tok, int Tlen,
                  const float* __restrict__ emb,
                  const float* __restrict__ W, int wstride,
                  const float* __restrict__ bias,
                  u16* __restrict__ gi)
{
  __shared__ float es[16][EE];
  const int tid = threadIdx.x;
  const int r0 = blockIdx.y * 16;
  #pragma unroll
  for (int rr = 0; rr < 16; ++rr) {
    int r = r0 + rr;
    int token = tok[(r & 31) * Tlen + (r >> 5)];
    es[rr][tid] = emb[(size_t)token * EE + tid];
  }
  __syncthreads();
  const int jl = tid & 63;
  const int rg = (tid >> 6) << 2;
  const int jbase = blockIdx.x * 256 + jl;
  float acc[4][4];
  #pragma unroll
  for (int jj = 0; jj < 4; ++jj) {
    float bv = bias[jbase + jj * 64];
    #pragma unroll
    for (int rr = 0; rr < 4; ++rr) acc[jj][rr] = bv;
  }
  const float4* w0 = (const float4*)(W + (size_t)(jbase      ) * wstride);
  const float4* w1 = (const float4*)(W + (size_t)(jbase +  64) * wstride);
  const float4* w2 = (const float4*)(W + (size_t)(jbase + 128) * wstride);
  const float4* w3 = (const float4*)(W + (size_t)(jbase + 192) * wstride);
  for (int k4 = 0; k4 < EE / 4; ++k4) {
    float4 wv0 = w0[k4], wv1 = w1[k4], wv2 = w2[k4], wv3 = w3[k4];
    #pragma unroll
    for (int rr = 0; rr < 4; ++rr) {
      float4 e = *(const float4*)&es[rg + rr][k4 * 4];
      acc[0][rr] = dot4(acc[0][rr], wv0, e);
      acc[1][rr] = dot4(acc[1][rr], wv1, e);
      acc[2][rr] = dot4(acc[2][rr], wv2, e);
      acc[3][rr] = dot4(acc[3][rr], wv3, e);
    }
  }
  #pragma unroll
  for (int rr = 0; rr < 4; ++rr)
    #pragma unroll
    for (int jj = 0; jj < 4; ++jj)
      gi[(size_t)(r0 + rg + rr) * G3 + jbase + jj * 64] = f2bf(acc[jj][rr]);
}

// ---------- K2: encoder GRU scan — persistent, 64 blocks (r14-proven) ----
// 8 i's/block; f32 weights in LDS; hs XOR-swizzled (granule ^= b&7).
__global__ __launch_bounds__(256)
void k_enc_scan(const u16* __restrict__ gi, const float* __restrict__ Whh,
                const float* __restrict__ bhh, u16* __restrict__ hring,
                u16* __restrict__ enc_outs, u32* __restrict__ bar)
{
  __shared__ float hs[32 * 512];    // 64 KB, swizzled
  __shared__ float wsl[24 * 512];   // 48 KB f32 (rows: g*8+il8)
  __shared__ float h2t[8][32];
  const int tid = threadIdx.x;
  const int bid = blockIdx.x;
  const int i0 = bid * 8;
  #pragma unroll
  for (int j = 0; j < 12; ++j) {    // 3072 float4 stage
    int f = (j * 256 + tid) * 4;
    int row24 = f >> 9, k = f & 511;
    int g = row24 >> 3, il8 = row24 & 7;
    *(float4*)&wsl[f] = *(const float4*)(Whh + (size_t)(g * 512 + i0 + il8) * 512 + k);
  }
  const int i_l = tid >> 6, lane = tid & 63, b = lane >> 1, kh = lane & 1;
  const int ia = i0 + i_l, ib = i0 + i_l + 4;
  const float* wRa = wsl + (0 * 8 + i_l    ) * 512 + kh * 256;
  const float* wZa = wsl + (1 * 8 + i_l    ) * 512 + kh * 256;
  const float* wNa = wsl + (2 * 8 + i_l    ) * 512 + kh * 256;
  const float* wRb = wsl + (0 * 8 + i_l + 4) * 512 + kh * 256;
  const float* wZb = wsl + (1 * 8 + i_l + 4) * 512 + kh * 256;
  const float* wNb = wsl + (2 * 8 + i_l + 4) * 512 + kh * 256;
  const float bRa = bhh[ia], bZa = bhh[ia + 512], bNa = bhh[ia + 1024];
  const float bRb = bhh[ib], bZb = bhh[ib + 512], bNb = bhh[ib + 1024];
  u32 bt = 0;
  for (int t = 0; t < SS; ++t) {
    const u64* hsrc = (const u64*)(hring + (size_t)t * 16384);
    #pragma unroll
    for (int j = 0; j < 16; ++j) {
      int idx = j * 256 + tid;
      u64 v = ald_u8(hsrc + idx);
      int bb = idx >> 7, gr = idx & 127;
      *(float4*)&hs[bb * 512 + ((gr ^ (bb & 7)) << 2)] = unp4(v);
    }
    __syncthreads();
    float aRa=0,aZa=0,aNa=0,aRb=0,aZb=0,aNb=0;
    for (int k8 = 0; k8 < 32; ++k8) {
      int g0 = kh * 64 + k8 * 2;
      float4 h0 = *(const float4*)&hs[b * 512 + ((g0 ^ (b & 7)) << 2)];
      float4 h1 = *(const float4*)&hs[b * 512 + (((g0 + 1) ^ (b & 7)) << 2)];
      aRa = fma44(aRa, *(const float4*)&wRa[k8*8], *(const float4*)&wRa[k8*8+4], h0, h1);
      aZa = fma44(aZa, *(const float4*)&wZa[k8*8], *(const float4*)&wZa[k8*8+4], h0, h1);
      aNa = fma44(aNa, *(const float4*)&wNa[k8*8], *(const float4*)&wNa[k8*8+4], h0, h1);
      aRb = fma44(aRb, *(const float4*)&wRb[k8*8], *(const float4*)&wRb[k8*8+4], h0, h1);
      aZb = fma44(aZb, *(const float4*)&wZb[k8*8], *(const float4*)&wZb[k8*8+4], h0, h1);
      aNb = fma44(aNb, *(const float4*)&wNb[k8*8], *(const float4*)&wNb[k8*8+4], h0, h1);
    }
    aRa += __shfl_xor(aRa,1); aZa += __shfl_xor(aZa,1); aNa += __shfl_xor(aNa,1);
    aRb += __shfl_xor(aRb,1); aZb += __shfl_xor(aZb,1); aNb += __shfl_xor(aNb,1);
    if (kh == 0) {
      const size_t g = ((size_t)t * 32 + b) * G3;
      float hoa = hs[b * 512 + (((ia >> 2) ^ (b & 7)) << 2) + (ia & 3)];
      float hob = hs[b * 512 + (((ib >> 2) ^ (b & 7)) << 2) + (ib & 3)];
      float r = sigf (bf2f(gi[g +        ia]) + aRa + bRa);
      float z = sigf (bf2f(gi[g +  512 + ia]) + aZa + bZa);
      float n = tanh_(bf2f(gi[g + 1024 + ia]) + r * (aNa + bNa));
      float h2a = z * hoa + (1.f - z) * n;
      r = sigf (bf2f(gi[g +        ib]) + aRb + bRb);
      z = sigf (bf2f(gi[g +  512 + ib]) + aZb + bZb);
      n = tanh_(bf2f(gi[g + 1024 + ib]) + r * (aNb + bNb));
      float h2b = z * hob + (1.f - z) * n;
      enc_outs[((size_t)b * 256 + t) * 512 + ia] = f2bf(h2a);
      enc_outs[((size_t)b * 256 + t) * 512 + ib] = f2bf(h2b);
      h2t[i_l][b] = h2a; h2t[i_l + 4][b] = h2b;
    }
    __syncthreads();
    if (tid < 128) {   // slot t+1: 128 atomic u32 stores/block
      int p = tid >> 5, bq = tid & 31;
      u32 pk = (u32)f2bf(h2t[2*p][bq]) | ((u32)f2bf(h2t[2*p+1][bq]) << 16);
      ast_u((u32*)(hring + (size_t)(t + 1) * 16384) + bq * 256 + bid * 4 + p, pk);
    }
    bt += 64; grid_bar(bar, bt);
  }
}

// ---------- K3: enc_proj = enc_outs @ attn_W2^T + b2 ----------
__global__ __launch_bounds__(256)
void k_proj(const u16* __restrict__ A, const float* __restrict__ W,
            const float* __restrict__ bias, u16* __restrict__ Out)
{
  __shared__ float es[16][HH];
  const int tid = threadIdx.x;
  const int r0 = blockIdx.y * 16;
  #pragma unroll
  for (int j = 0; j < 4; ++j) {
    int u = j * 256 + tid;
    int row = u >> 6, k = (u & 63) * 8;
    float d[8]; unp8(d, *(const uint4*)(A + (size_t)(r0 + row) * HH + k));
    *(float4*)&es[row][k]     = make_float4(d[0],d[1],d[2],d[3]);
    *(float4*)&es[row][k + 4] = make_float4(d[4],d[5],d[6],d[7]);
  }
  __syncthreads();
  const int jl = tid & 63;
  const int rg = (tid >> 6) << 2;
  const int jbase = blockIdx.x * 256 + jl;
  float acc[4][4];
  #pragma unroll
  for (int jj = 0; jj < 4; ++jj) {
    float bv = bias[jbase + jj * 64];
    #pragma unroll
    for (int rr = 0; rr < 4; ++rr) acc[jj][rr] = bv;
  }
  const float4* w0 = (const float4*)(W + (size_t)(jbase      ) * HH);
  const float4* w1 = (const float4*)(W + (size_t)(jbase +  64) * HH);
  const float4* w2 = (const float4*)(W + (size_t)(jbase + 128) * HH);
  const float4* w3 = (const float4*)(W + (size_t)(jbase + 192) * HH);
  for (int k4 = 0; k4 < HH / 4; ++k4) {
    float4 wv0 = w0[k4], wv1 = w1[k4], wv2 = w2[k4], wv3 = w3[k4];
    #pragma unroll
    for (int rr = 0; rr < 4; ++rr) {
      float4 e = *(const float4*)&es[rg + rr][k4 * 4];
      acc[0][rr] = dot4(acc[0][rr], wv0, e);
      acc[1][rr] = dot4(acc[1][rr], wv1, e);
      acc[2][rr] = dot4(acc[2][rr], wv2, e);
      acc[3][rr] = dot4(acc[3][rr], wv3, e);
    }
  }
  #pragma unroll
  for (int rr = 0; rr < 4; ++rr)
    #pragma unroll
    for (int jj = 0; jj < 4; ++jj)
      Out[(size_t)(r0 + rg + rr) * HH + jbase + jj * 64] = f2bf(acc[jj][rr]);
}

// ---------- K4: decoder scan — persistent, 128 blocks (r13-proven) -------
// Flash-partial ctx (write-once) + ATOMIC consumer loads.
__global__ __launch_bounds__(256)
void k_dec_scan(const u16* __restrict__ gi, u16* __restrict__ hring,
                const float* __restrict__ W1, const float* __restrict__ b1,
                const float* __restrict__ av,
                const u16* __restrict__ enc_proj, const u16* __restrict__ enc_outs,
                const float* __restrict__ Whh, const float* __restrict__ Wih,
                const float* __restrict__ bhh,
                float* __restrict__ aring, u16* __restrict__ ctxP,
                float* __restrict__ sringP, u16* __restrict__ h2bf,
                u32* __restrict__ bar)
{
  __shared__ float hs[32 * HP];     // 66.0 KB
  __shared__ u16  csb[32 * CP];     // 33.3 KB (bf16 ctx)
  __shared__ u16  wlds[28 * 512];   // 28.7 KB
  __shared__ float as_[512], vs_[512];
  __shared__ float scq[4][64], wts[64];
  __shared__ float rs[32];
  __shared__ float h2t[4][32];
  const int tid = threadIdx.x;
  const int bid = blockIdx.x;
  const int i_l = tid >> 6, lane = tid & 63, b = lane >> 1, kh = lane & 1;
  const int i0 = bid * 4;
  const int i = i0 + i_l;
  const int pb = bid >> 2, sq = bid & 3;
  vs_[tid] = av[tid]; vs_[tid + 256] = av[tid + 256];
  #pragma unroll
  for (int j = 0; j < 14; ++j) {
    int idx = j * 256 + tid;
    int row = idx >> 7, k4 = idx & 127;
    const float* src;
    if (row < 4)        src = W1  + (size_t)(i0 + row) * 512 + k4 * 4;
    else if (row < 16) { int rr = row - 4;
                         src = Whh + (size_t)((rr >> 2) * 512 + i0 + (rr & 3)) * 512 + k4 * 4; }
    else               { int rr = row - 16;
                         src = Wih + (size_t)((rr >> 2) * 512 + i0 + (rr & 3)) * 768 + 256 + k4 * 4; }
    float4 w = *(const float4*)src;
    int f = row * 512 + k4 * 4;
    wlds[f] = f2bf(w.x); wlds[f+1] = f2bf(w.y); wlds[f+2] = f2bf(w.z); wlds[f+3] = f2bf(w.w);
  }
  const u16* w1r = wlds + (     i_l) * 512 + kh * 256;
  const u16* whr = wlds + ( 4 + i_l) * 512 + kh * 256;
  const u16* whz = wlds + ( 8 + i_l) * 512 + kh * 256;
  const u16* whn = wlds + (12 + i_l) * 512 + kh * 256;
  const u16* wir = wlds + (16 + i_l) * 512 + kh * 256;
  const u16* wiz = wlds + (20 + i_l) * 512 + kh * 256;
  const u16* win = wlds + (24 + i_l) * 512 + kh * 256;
  const float bR = bhh[i], bZ = bhh[i + 512], bN = bhh[i + 1024];
  const float b1i = b1[i];
  u32 bt = 0;
  for (int t = 0; t < TT; ++t) {
    const u64* hsrc = (const u64*)(hring + (size_t)(256 + t) * 16384);
    #pragma unroll
    for (int j = 0; j < 16; ++j) {
      int idx = j * 256 + tid;
      u64 v = ald_u8(hsrc + idx);
      int bb = idx >> 7, m = (idx & 127) * 4;
      *(float4*)&hs[bb * HP + m] = unp4(v);
    }
    __syncthreads();
    // ---- P1 ----
    {
      const float* hb = hs + b * HP + kh * 256;
      float acc = 0.f;
      for (int k8 = 0; k8 < 32; ++k8) {
        float wf[8]; unp8(wf, *(const uint4*)(w1r + k8 * 8));
        acc = fma8(acc, wf, *(const float4*)&hb[k8*8], *(const float4*)&hb[k8*8+4]);
      }
      acc += __shfl_xor(acc, 1);
      if (kh == 0) ast_f(&aring[(size_t)t * 16384 + b * 512 + i], acc + b1i);
    }
    bt += 128; grid_bar(bar, bt);
    // ---- P2 ----
    {
      u64 v = ald_u8((const u64*)(aring + (size_t)t * 16384 + pb * 512) + tid);
      union { u64 q; float f[2]; } cv; cv.q = v;
      as_[2 * tid] = cv.f[0]; as_[2 * tid + 1] = cv.f[1];
    }
    __syncthreads();
    {
      const int kp = tid >> 6, s_l = tid & 63;
      const int s = sq * 64 + s_l;
      const u16* pr = enc_proj + ((size_t)pb * 256 + s) * 512 + kp * 128;
      const float* ak = as_ + kp * 128;
      const float* vk = vs_ + kp * 128;
      float acc = 0.f;
      for (int k8 = 0; k8 < 16; ++k8) {
        float d[8]; unp8(d, *(const uint4*)(pr + k8 * 8));
        #pragma unroll
        for (int e = 0; e < 8; ++e)
          acc += vk[k8 * 8 + e] * tanh_(d[e] + ak[k8 * 8 + e]);
      }
      scq[kp][s_l] = acc;
    }
    __syncthreads();
    if (tid < 64) {
      float sc = (scq[0][tid] + scq[1][tid]) + (scq[2][tid] + scq[3][tid]);
      float e = __expf(sc);          // bounded scores: no max-shift (proven r7)
      wts[tid] = e;
      float su = e;
      #pragma unroll
      for (int d = 1; d < 64; d <<= 1) su += __shfl_xor(su, d);
      if (tid == 0) ast_f(&sringP[t * 128 + sq * 32 + pb], su);
    }
    __syncthreads();
    {
      const int k0 = tid * 2;
      float c0 = 0.f, c1 = 0.f;
      const u16* eo = enc_outs + ((size_t)pb * 256 + sq * 64) * 512 + k0;
      for (int s = 0; s < 64; ++s) {
        float w = wts[s];
        u32 pair = *(const u32*)(eo + (size_t)s * 512);
        c0 = fmaf(w, blo(pair), c0);
        c1 = fmaf(w, bhi(pair), c1);
      }
      u32 pk = (u32)f2bf(c0) | ((u32)f2bf(c1) << 16);
      ast_u((u32*)(ctxP + (size_t)t * 65536 + (sq * 32 + pb) * 512 + k0), pk);
    }
    bt += 128; grid_bar(bar, bt);
    // ---- P3 ----
    if (tid < 32) {
      const float* sp = sringP + t * 128;
      rs[tid] = 1.f / ((ald_f(sp + tid) + ald_f(sp + 32 + tid)) +
                       (ald_f(sp + 64 + tid) + ald_f(sp + 96 + tid)));
    }
    __syncthreads();
    #pragma unroll
    for (int j = 0; j < 8; ++j) {
      int idx = j * 256 + tid;
      int bb = idx >> 6, m = (idx & 63) * 8;
      const u64* bp = (const u64*)(ctxP + (size_t)t * 65536 + bb * 512 + m);
      float c[8] = {0,0,0,0,0,0,0,0};
      #pragma unroll
      for (int q = 0; q < 4; ++q) {
        u64 v0 = ald_u8(bp + q * 4096);
        u64 v1 = ald_u8(bp + q * 4096 + 1);
        c[0] += bf2f((u16)v0); c[1] += bf2f((u16)(v0 >> 16));
        c[2] += bf2f((u16)(v0 >> 32)); c[3] += bf2f((u16)(v0 >> 48));
        c[4] += bf2f((u16)v1); c[5] += bf2f((u16)(v1 >> 16));
        c[6] += bf2f((u16)(v1 >> 32)); c[7] += bf2f((u16)(v1 >> 48));
      }
      float r = rs[bb];
      *(u32*)&csb[bb * CP + m]     = (u32)f2bf(c[0]*r) | ((u32)f2bf(c[1]*r) << 16);
      *(u32*)&csb[bb * CP + m + 2] = (u32)f2bf(c[2]*r) | ((u32)f2bf(c[3]*r) << 16);
      *(u32*)&csb[bb * CP + m + 4] = (u32)f2bf(c[4]*r) | ((u32)f2bf(c[5]*r) << 16);
      *(u32*)&csb[bb * CP + m + 6] = (u32)f2bf(c[6]*r) | ((u32)f2bf(c[7]*r) << 16);
    }
    __syncthreads();
    {
      const float* hb = hs + b * HP + kh * 256;
      const u16*   cb = csb + b * CP + kh * 256;
      float hR=0.f,hZ=0.f,hN=0.f,cR=0.f,cZ=0.f,cN=0.f;
      for (int k8 = 0; k8 < 32; ++k8) {
        float4 h0 = *(const float4*)&hb[k8*8], h1 = *(const float4*)&hb[k8*8+4];
        float cf[8]; unp8(cf, *(const uint4*)(cb + k8 * 8));
        float wf[8];
        unp8(wf, *(const uint4*)(whr + k8 * 8)); hR = fma8(hR, wf, h0, h1);
        unp8(wf, *(const uint4*)(whz + k8 * 8)); hZ = fma8(hZ, wf, h0, h1);
        unp8(wf, *(const uint4*)(whn + k8 * 8)); hN = fma8(hN, wf, h0, h1);
        unp8(wf, *(const uint4*)(wir + k8 * 8)); cR = fma8p(cR, wf, cf);
        unp8(wf, *(const uint4*)(wiz + k8 * 8)); cZ = fma8p(cZ, wf, cf);
        unp8(wf, *(const uint4*)(win + k8 * 8)); cN = fma8p(cN, wf, cf);
      }
      hR += __shfl_xor(hR, 1); hZ += __shfl_xor(hZ, 1); hN += __shfl_xor(hN, 1);
      cR += __shfl_xor(cR, 1); cZ += __shfl_xor(cZ, 1); cN += __shfl_xor(cN, 1);
      if (kh == 0) {
        const size_t g = ((size_t)t * 32 + b) * G3;
        float r = sigf (bf2f(gi[g +        i]) + cR + hR + bR);
        float z = sigf (bf2f(gi[g +  512 + i]) + cZ + hZ + bZ);
        float n = tanh_(bf2f(gi[g + 1024 + i]) + cN + r * (hN + bN));
        float h2 = z * hs[b * HP + i] + (1.f - z) * n;
        h2bf[((size_t)t * 32 + b) * 512 + i] = f2bf(h2);   // cross-kernel: plain OK
        h2t[i_l][b] = h2;
      }
    }
    __syncthreads();
    if (tid < 64) {   // carry -> ring slot 257+t
      int p = tid >> 5, bq = tid & 31;
      u32 pk = (u32)f2bf(h2t[2*p][bq]) | ((u32)f2bf(h2t[2*p+1][bq]) << 16);
      ast_u((u32*)(hring + (size_t)(257 + t) * 16384) + bq * 256 + bid * 2 + p, pk);
    }
    bt += 128; grid_bar(bar, bt);
  }
}

// ---------- K5: fcW f32 -> bf16 (one-time) ----------
__global__ __launch_bounds__(256)
void k_cvt(const float* __restrict__ in, u16* __restrict__ out)
{
  size_t i = ((size_t)blockIdx.x * 256 + threadIdx.x) * 8;
  float4 a = *(const float4*)(in + i);
  float4 b = *(const float4*)(in + i + 4);
  union { uint4 v; u16 s[8]; } u;
  u.s[0]=f2bf(a.x); u.s[1]=f2bf(a.y); u.s[2]=f2bf(a.z); u.s[3]=f2bf(a.w);
  u.s[4]=f2bf(b.x); u.s[5]=f2bf(b.y); u.s[6]=f2bf(b.z); u.s[7]=f2bf(b.w);
  *(uint4*)(out + i) = u.v;
}

// ---------- K6: logits via bf16 MFMA (proven r8/r9/r13) ----------
__global__ __launch_bounds__(256)
void k_logits_mfma(const u16* __restrict__ A, const u16* __restrict__ Wb,
                   const float* __restrict__ bias, float* __restrict__ out)
{
  __shared__ u16 Al[64 * 512];
  const int tid = threadIdx.x;
  const int r0 = blockIdx.x * 64;
  const int v0 = blockIdx.y * 64;
  {
    const uint4* src = (const uint4*)(A + (size_t)r0 * 512);
    uint4* dst = (uint4*)Al;
    #pragma unroll
    for (int j = 0; j < 16; ++j) {
      int idx = j * 256 + tid;
      int row = idx >> 6, g = idx & 63;
      dst[(row << 6) | (g ^ (row & 7))] = src[idx];
    }
  }
  const int w  = tid >> 6, l = tid & 63;
  const int lr = l & 15,  qk = l >> 4;
  const int v  = v0 + w * 16 + lr;
  frag bfr[16];
  {
    const u16* wrow = Wb + (size_t)v * 512 + qk * 8;
    #pragma unroll
    for (int ks = 0; ks < 16; ++ks)
      bfr[ks] = *(const frag*)(wrow + ks * 32);
  }
  const float bv = bias[v];
  __syncthreads();
  f32x4v acc[4];
  #pragma unroll
  for (int mt = 0; mt < 4; ++mt) acc[mt] = (f32x4v){0.f, 0.f, 0.f, 0.f};
  #pragma unroll
  for (int ks = 0; ks < 16; ++ks) {
    #pragma unroll
    for (int mt = 0; mt < 4; ++mt) {
      const int row = mt * 16 + lr;
      const int gr  = ks * 4 + qk;
      frag a = *(const frag*)&Al[(row << 9) | ((gr ^ (row & 7)) << 3)];
      acc[mt] = __builtin_amdgcn_mfma_f32_16x16x32_bf16(a, bfr[ks], acc[mt], 0, 0, 0);
    }
  }
  #pragma unroll
  for (int mt = 0; mt < 4; ++mt)
    #pragma unroll
    for (int reg = 0; reg < 4; ++reg) {
      const int r = r0 + mt * 16 + qk * 4 + reg;
      out[(size_t)(r & 31) * 64 * VV + (size_t)(r >> 5) * VV + v] = acc[mt][reg] + bv;
    }
}

// ---------- launch ----------
extern "C" void kernel_launch(void* const* d_in, const int* in_sizes, int n_in,
                              void* d_out, int out_size, void* d_ws, size_t ws_size,
                              hipStream_t stream) {
  (void)in_sizes; (void)n_in; (void)out_size; (void)ws_size;
  const int*   src  = (const int*)d_in[0];
  const int*   tgt  = (const int*)d_in[1];
  const float* eemb = (const float*)d_in[2];
  const float* eWih = (const float*)d_in[3];
  const float* eWhh = (const float*)d_in[4];
  const float* ebih = (const float*)d_in[5];
  const float* ebhh = (const float*)d_in[6];
  const float* demb = (const float*)d_in[7];
  const float* aW1  = (const float*)d_in[8];
  const float* ab1  = (const float*)d_in[9];
  const float* aW2  = (const float*)d_in[10];
  const float* ab2  = (const float*)d_in[11];
  const float* av   = (const float*)d_in[12];
  const float* dWih = (const float*)d_in[13];
  const float* dWhh = (const float*)d_in[14];
  const float* dbih = (const float*)d_in[15];
  const float* dbhh = (const float*)d_in[16];
  const float* fcW  = (const float*)d_in[17];
  const float* fcb  = (const float*)d_in[18];
  float* out = (float*)d_out;

  // workspace carve (~71 MiB, r13 layout)
  float* aring   = (float*)d_ws;                 // 64x16384 f32 (4 MiB)
  float* sringP  = aring + 1048576;              // 64x128 f32 (32 KiB)
  u32*   bars    = (u32*)(sringP + 8192);        // 8 u32
  u16*  ctxP     = (u16*)(bars + 8);             // 64x128x512 u16 (8 MiB)
  u16*  hring    = ctxP + 4194304;               // 321x16384 u16 (10.5 MiB)
  u16*  h2bf     = hring + 5259264;              // 1,048,576 u16
  u16*  gi_enc   = h2bf + 1048576;               // 12,582,912 u16
  u16*  gi_dec   = gi_enc + 12582912;            //  3,145,728 u16
  u16*  enc_outs = gi_dec + 3145728;             //  4,194,304 u16
  u16*  enc_proj = enc_outs + 4194304;           //  4,194,304 u16
  u16*  wbf      = gi_enc;  // fcW bf16 alias (dead after k_dec_scan)

  hipMemsetAsync(hring, 0, 16384 * sizeof(u16), stream);   // h0 slot (zeros)
  hipMemsetAsync(bars, 0, 8 * sizeof(u32), stream);        // barrier counters

  k_embed_gemm<<<dim3(6, 512), 256, 0, stream>>>(src, SS, eemb, eWih, EE,  ebih, gi_enc);
  k_embed_gemm<<<dim3(6, 128), 256, 0, stream>>>(tgt, TT, demb, dWih, 768, dbih, gi_dec);

  k_enc_scan<<<64, 256, 0, stream>>>(gi_enc, eWhh, ebhh, hring, enc_outs, bars + 0);

  k_proj<<<dim3(2, 512), 256, 0, stream>>>(enc_outs, aW2, ab2, enc_proj);

  k_dec_scan<<<128, 256, 0, stream>>>(gi_dec, hring, aW1, ab1, av,
                                      enc_proj, enc_outs, dWhh, dWih, dbhh,
                                      aring, ctxP, sringP, h2bf, bars + 1);

  k_cvt<<<8000, 256, 0, stream>>>(fcW, wbf);

  k_logits_mfma<<<dim3(32, 500), 256, 0, stream>>>(h2bf, wbf, fcb, out);
}

// Round 16
// 6070.268 us; speedup vs baseline: 1.3965x; 1.1946x over previous
//
#include <hip/hip_runtime.h>
#include <hip/hip_bf16.h>
#include <stdint.h>

#define DEV __device__ __forceinline__
typedef unsigned short u16;
typedef unsigned int   u32;
typedef unsigned long long u64;

static constexpr int SS = 256;   // src len
static constexpr int TT = 64;    // tgt len
static constexpr int EE = 256;   // embed dim
static constexpr int HH = 512;   // hidden
static constexpr int G3 = 1536;  // 3*H
static constexpr int VV = 32000; // vocab
static constexpr int HP  = 516;  // padded f32 LDS row (h tiles)
static constexpr int WPE = 516;  // padded f32 weight row (encoder)
static constexpr int WPD = 520;  // padded u16 weight row (decoder)
static constexpr int CP8 = 520;  // padded u16 ctx row (decoder)

using frag   = __attribute__((ext_vector_type(8))) short;  // 8 bf16
using f32x4v = __attribute__((ext_vector_type(4))) float;  // MFMA acc

// ---------- helpers ----------
DEV float blo(u32 u){ union{u32 i; float f;} x; x.i = u << 16;         return x.f; }
DEV float bhi(u32 u){ union{u32 i; float f;} x; x.i = u & 0xffff0000u; return x.f; }
DEV float bf2f(u16 u){ union{u32 i; float f;} x; x.i = ((u32)u) << 16; return x.f; }
DEV u16 f2bf(float f){ union{float f; u32 u;} v; v.f = f;
  u32 r = v.u + 0x7fffu + ((v.u >> 16) & 1u); return (u16)(r >> 16); }
DEV float sigf (float x){ return 1.0f / (1.0f + __expf(-x)); }
DEV float tanh_(float x){ return 1.0f - 2.0f / (1.0f + __expf(2.0f * x)); }
DEV void unp8(float* d, uint4 u){
  d[0]=blo(u.x); d[1]=bhi(u.x); d[2]=blo(u.y); d[3]=bhi(u.y);
  d[4]=blo(u.z); d[5]=bhi(u.z); d[6]=blo(u.w); d[7]=bhi(u.w);
}
DEV float4 unp4(u64 v){
  return make_float4(bf2f((u16)v), bf2f((u16)(v >> 16)),
                     bf2f((u16)(v >> 32)), bf2f((u16)(v >> 48)));
}
DEV float dot4(float acc, float4 w, float4 x){
  acc = fmaf(w.x,x.x,acc); acc = fmaf(w.y,x.y,acc);
  acc = fmaf(w.z,x.z,acc); acc = fmaf(w.w,x.w,acc);
  return acc;
}
DEV float fma44(float acc, float4 w0, float4 w1, float4 h0, float4 h1){
  return dot4(dot4(acc, w0, h0), w1, h1);
}
DEV float fma8(float acc, const float* w, float4 a, float4 b){
  acc = fmaf(w[0],a.x,acc); acc = fmaf(w[1],a.y,acc);
  acc = fmaf(w[2],a.z,acc); acc = fmaf(w[3],a.w,acc);
  acc = fmaf(w[4],b.x,acc); acc = fmaf(w[5],b.y,acc);
  acc = fmaf(w[6],b.z,acc); acc = fmaf(w[7],b.w,acc);
  return acc;
}
DEV float fma8p(float acc, const float* w, const float* x){
  #pragma unroll
  for (int e = 0; e < 8; ++e) acc = fmaf(w[e], x[e], acc);
  return acc;
}

// ---- agent-scope atomics (r9/r13-proven coherence rule) ----
DEV void  ast_f(float* p, float v){ __hip_atomic_store(p, v, __ATOMIC_RELAXED, __HIP_MEMORY_SCOPE_AGENT); }
DEV void  ast_u(u32* p, u32 v)    { __hip_atomic_store(p, v, __ATOMIC_RELAXED, __HIP_MEMORY_SCOPE_AGENT); }
DEV float ald_f(const float* p)   { return __hip_atomic_load((float*)p, __ATOMIC_RELAXED, __HIP_MEMORY_SCOPE_AGENT); }
DEV u64   ald_u8(const u64* p)    { return __hip_atomic_load((u64*)p,   __ATOMIC_RELAXED, __HIP_MEMORY_SCOPE_AGENT); }

DEV void grid_bar(u32* cnt, u32 target){
  __syncthreads();
  if (threadIdx.x == 0) {
    __hip_atomic_fetch_add(cnt, 1u, __ATOMIC_RELAXED, __HIP_MEMORY_SCOPE_AGENT);
    while (__hip_atomic_load(cnt, __ATOMIC_RELAXED, __HIP_MEMORY_SCOPE_AGENT) < target)
      __builtin_amdgcn_s_sleep(1);
  }
  __syncthreads();
}

// ---------- K1: gi = gather(emb, tok) @ W[:, :256]^T + bih  (bf16 out) ----
__global__ __launch_bounds__(256)
void k_embed_gemm(const int* __restrict__ tok, int Tlen,
                  const float* __restrict__ emb,
                  const float* __restrict__ W, int wstride,
                  const float* __restrict__ bias,
                  u16* __restrict__ gi)
{
  __shared__ float es[16][EE];
  const int tid = threadIdx.x;
  const int r0 = blockIdx.y * 16;
  #pragma unroll
  for (int rr = 0; rr < 16; ++rr) {
    int r = r0 + rr;
    int token = tok[(r & 31) * Tlen + (r >> 5)];
    es[rr][tid] = emb[(size_t)token * EE + tid];
  }
  __syncthreads();
  const int jl = tid & 63;
  const int rg = (tid >> 6) << 2;
  const int jbase = blockIdx.x * 256 + jl;
  float acc[4][4];
  #pragma unroll
  for (int jj = 0; jj < 4; ++jj) {
    float bv = bias[jbase + jj * 64];
    #pragma unroll
    for (int rr = 0; rr < 4; ++rr) acc[jj][rr] = bv;
  }
  const float4* w0 = (const float4*)(W + (size_t)(jbase      ) * wstride);
  const float4* w1 = (const float4*)(W + (size_t)(jbase +  64) * wstride);
  const float4* w2 = (const float4*)(W + (size_t)(jbase + 128) * wstride);
  const float4* w3 = (const float4*)(W + (size_t)(jbase + 192) * wstride);
  for (int k4 = 0; k4 < EE / 4; ++k4) {
    float4 wv0 = w0[k4], wv1 = w1[k4], wv2 = w2[k4], wv3 = w3[k4];
    #pragma unroll
    for (int rr = 0; rr < 4; ++rr) {
      float4 e = *(const float4*)&es[rg + rr][k4 * 4];
      acc[0][rr] = dot4(acc[0][rr], wv0, e);
      acc[1][rr] = dot4(acc[1][rr], wv1, e);
      acc[2][rr] = dot4(acc[2][rr], wv2, e);
      acc[3][rr] = dot4(acc[3][rr], wv3, e);
    }
  }
  #pragma unroll
  for (int rr = 0; rr < 4; ++rr)
    #pragma unroll
    for (int jj = 0; jj < 4; ++jj)
      gi[(size_t)(r0 + rg + rr) * G3 + jbase + jj * 64] = f2bf(acc[jj][rr]);
}

// ---------- K2: encoder GRU scan — r13 kernel + padded weight rows -------
__global__ __launch_bounds__(256)
void k_enc_scan(const u16* __restrict__ gi, const float* __restrict__ Whh,
                const float* __restrict__ bhh, u16* __restrict__ hring,
                u16* __restrict__ enc_outs, u32* __restrict__ bar)
{
  __shared__ float hs[32 * HP];     // 66.0 KB
  __shared__ float wsl[12 * WPE];   // 24.8 KB f32 (padded rows: bank-spread)
  __shared__ float h2t[4][32];
  const int tid = threadIdx.x;
  const int bid = blockIdx.x;
  const int i0 = bid * 4;
  #pragma unroll
  for (int j = 0; j < 6; ++j) {     // stage 12 rows x 512 f32
    int f = (j * 256 + tid) * 4;    // flat [12][512] float index
    int rowl = f >> 9, k = f & 511;
    int g = rowl >> 2, ri = rowl & 3;
    *(float4*)&wsl[rowl * WPE + k] =
      *(const float4*)(Whh + (size_t)(g * 512 + i0 + ri) * 512 + k);
  }
  const int i_l = tid >> 6, lane = tid & 63, b = lane >> 1, kh = lane & 1;
  const int i = i0 + i_l;
  const float* w0 = wsl + (0 * 4 + i_l) * WPE + kh * 256;
  const float* w1 = wsl + (1 * 4 + i_l) * WPE + kh * 256;
  const float* w2 = wsl + (2 * 4 + i_l) * WPE + kh * 256;
  const float bR = bhh[i], bZ = bhh[i + 512], bN = bhh[i + 1024];
  u32 bt = 0;
  for (int t = 0; t < SS; ++t) {
    const u64* hsrc = (const u64*)(hring + (size_t)t * 16384);
    #pragma unroll
    for (int j = 0; j < 16; ++j) {
      int idx = j * 256 + tid;
      u64 v = ald_u8(hsrc + idx);
      int bb = idx >> 7, m = (idx & 127) * 4;
      *(float4*)&hs[bb * HP + m] = unp4(v);
    }
    __syncthreads();
    float aR = 0.f, aZ = 0.f, aN = 0.f;
    const float* hb = hs + b * HP + kh * 256;
    for (int k8 = 0; k8 < 32; ++k8) {
      float4 h0 = *(const float4*)&hb[k8*8], h1 = *(const float4*)&hb[k8*8+4];
      aR = fma44(aR, *(const float4*)&w0[k8*8], *(const float4*)&w0[k8*8+4], h0, h1);
      aZ = fma44(aZ, *(const float4*)&w1[k8*8], *(const float4*)&w1[k8*8+4], h0, h1);
      aN = fma44(aN, *(const float4*)&w2[k8*8], *(const float4*)&w2[k8*8+4], h0, h1);
    }
    aR += __shfl_xor(aR, 1);
    aZ += __shfl_xor(aZ, 1);
    aN += __shfl_xor(aN, 1);
    if (kh == 0) {
      const size_t g = ((size_t)t * 32 + b) * G3;
      float r = sigf (bf2f(gi[g +        i]) + aR + bR);
      float z = sigf (bf2f(gi[g +  512 + i]) + aZ + bZ);
      float n = tanh_(bf2f(gi[g + 1024 + i]) + r * (aN + bN));
      float h2 = z * hs[b * HP + i] + (1.f - z) * n;
      enc_outs[((size_t)b * 256 + t) * 512 + i] = f2bf(h2);
      h2t[i_l][b] = h2;
    }
    __syncthreads();
    if (tid < 64) {
      int p = tid >> 5, bq = tid & 31;
      u32 pk = (u32)f2bf(h2t[2*p][bq]) | ((u32)f2bf(h2t[2*p+1][bq]) << 16);
      ast_u((u32*)(hring + (size_t)(t + 1) * 16384) + bq * 256 + bid * 2 + p, pk);
    }
    bt += 128; grid_bar(bar, bt);
  }
}

// ---------- K3: enc_proj = enc_outs @ attn_W2^T + b2 ----------
__global__ __launch_bounds__(256)
void k_proj(const u16* __restrict__ A, const float* __restrict__ W,
            const float* __restrict__ bias, u16* __restrict__ Out)
{
  __shared__ float es[16][HH];
  const int tid = threadIdx.x;
  const int r0 = blockIdx.y * 16;
  #pragma unroll
  for (int j = 0; j < 4; ++j) {
    int u = j * 256 + tid;
    int row = u >> 6, k = (u & 63) * 8;
    float d[8]; unp8(d, *(const uint4*)(A + (size_t)(r0 + row) * HH + k));
    *(float4*)&es[row][k]     = make_float4(d[0],d[1],d[2],d[3]);
    *(float4*)&es[row][k + 4] = make_float4(d[4],d[5],d[6],d[7]);
  }
  __syncthreads();
  const int jl = tid & 63;
  const int rg = (tid >> 6) << 2;
  const int jbase = blockIdx.x * 256 + jl;
  float acc[4][4];
  #pragma unroll
  for (int jj = 0; jj < 4; ++jj) {
    float bv = bias[jbase + jj * 64];
    #pragma unroll
    for (int rr = 0; rr < 4; ++rr) acc[jj][rr] = bv;
  }
  const float4* w0 = (const float4*)(W + (size_t)(jbase      ) * HH);
  const float4* w1 = (const float4*)(W + (size_t)(jbase +  64) * HH);
  const float4* w2 = (const float4*)(W + (size_t)(jbase + 128) * HH);
  const float4* w3 = (const float4*)(W + (size_t)(jbase + 192) * HH);
  for (int k4 = 0; k4 < HH / 4; ++k4) {
    float4 wv0 = w0[k4], wv1 = w1[k4], wv2 = w2[k4], wv3 = w3[k4];
    #pragma unroll
    for (int rr = 0; rr < 4; ++rr) {
      float4 e = *(const float4*)&es[rg + rr][k4 * 4];
      acc[0][rr] = dot4(acc[0][rr], wv0, e);
      acc[1][rr] = dot4(acc[1][rr], wv1, e);
      acc[2][rr] = dot4(acc[2][rr], wv2, e);
      acc[3][rr] = dot4(acc[3][rr], wv3, e);
    }
  }
  #pragma unroll
  for (int rr = 0; rr < 4; ++rr)
    #pragma unroll
    for (int jj = 0; jj < 4; ++jj)
      Out[(size_t)(r0 + rg + rr) * HH + jbase + jj * 64] = f2bf(acc[jj][rr]);
}

// ---------- K4: decoder scan — b-partitioned P1/P3, 128 blocks -----------
// P1/P3: block = (bg[4], ig[32]) owns b in [bg*8,bg*8+8), i in [ig*16,ig*16+16).
// Thread = (b_l[8], i_l[16], kh[2]); all 7 gate-rows of each i in LDS.
// P2: block = (pb[32], sq[4]) — r13-proven attention phase.
__global__ __launch_bounds__(256)
void k_dec_scan(const u16* __restrict__ gi, u16* __restrict__ hring,
                const float* __restrict__ W1, const float* __restrict__ b1,
                const float* __restrict__ av,
                const u16* __restrict__ enc_proj, const u16* __restrict__ enc_outs,
                const float* __restrict__ Whh, const float* __restrict__ Wih,
                const float* __restrict__ bhh,
                float* __restrict__ aring, u16* __restrict__ ctxP,
                float* __restrict__ sringP, u16* __restrict__ h2bf,
                u32* __restrict__ bar)
{
  __shared__ float hs8[8 * HP];      // 16.5 KB (8 b's, full h)
  __shared__ u16  csb8[8 * CP8];     //  8.3 KB (bf16 ctx for 8 b's)
  __shared__ u16  wlds[112 * WPD];   // 113.8 KB (16 i x 7 rows, padded)
  __shared__ float as_[512], vs_[512];
  __shared__ float scq[4][64], wts[64];
  __shared__ float rs[8];
  __shared__ float h2t[16][8];
  const int tid = threadIdx.x;
  const int bid = blockIdx.x;
  const int bg = bid >> 5, ig = bid & 31;
  const int b_l = tid >> 5, i_l = (tid >> 1) & 15, kh = tid & 1;
  const int i = ig * 16 + i_l;
  const int bglob = bg * 8 + b_l;
  const int pb = bid >> 2, sq = bid & 3;
  vs_[tid] = av[tid]; vs_[tid + 256] = av[tid + 256];
  // stage 112 weight rows (f32 -> bf16, padded): 14336 float4 = 56/thread
  for (int j = 0; j < 56; ++j) {
    int idx = j * 256 + tid;
    int row = idx >> 7, k4 = idx & 127;
    const float* src;
    if (row < 16)      src = W1  + (size_t)(ig * 16 + row) * 512 + k4 * 4;
    else if (row < 64) { int rr = row - 16; int g = rr >> 4, ii = rr & 15;
                         src = Whh + (size_t)(g * 512 + ig * 16 + ii) * 512 + k4 * 4; }
    else               { int rr = row - 64; int g = rr >> 4, ii = rr & 15;
                         src = Wih + (size_t)(g * 512 + ig * 16 + ii) * 768 + 256 + k4 * 4; }
    float4 w = *(const float4*)src;
    int f = row * WPD + k4 * 4;
    wlds[f] = f2bf(w.x); wlds[f+1] = f2bf(w.y); wlds[f+2] = f2bf(w.z); wlds[f+3] = f2bf(w.w);
  }
  const u16* w1r = wlds + (      i_l) * WPD + kh * 256;
  const u16* whr = wlds + (16  + i_l) * WPD + kh * 256;
  const u16* whz = wlds + (32  + i_l) * WPD + kh * 256;
  const u16* whn = wlds + (48  + i_l) * WPD + kh * 256;
  const u16* wir = wlds + (64  + i_l) * WPD + kh * 256;
  const u16* wiz = wlds + (80  + i_l) * WPD + kh * 256;
  const u16* win = wlds + (96  + i_l) * WPD + kh * 256;
  const float bR = bhh[i], bZ = bhh[i + 512], bN = bhh[i + 1024];
  const float b1i = b1[i];
  u32 bt = 0;
  for (int t = 0; t < TT; ++t) {
    // stage h for OUR 8 b's: 1024 u64 = 4/thread
    const u64* hsrc = (const u64*)(hring + (size_t)(256 + t) * 16384);
    #pragma unroll
    for (int j = 0; j < 4; ++j) {
      int idx = j * 256 + tid;
      int lb = idx >> 7, gu = idx & 127;
      u64 v = ald_u8(hsrc + (size_t)(bg * 8 + lb) * 128 + gu);
      *(float4*)&hs8[lb * HP + gu * 4] = unp4(v);
    }
    __syncthreads();
    // ---- P1: a[b][i] = b1[i] + h[b].W1[i]  ----
    {
      const float* hb = hs8 + b_l * HP + kh * 256;
      float acc = 0.f;
      for (int k8 = 0; k8 < 32; ++k8) {
        float wf[8]; unp8(wf, *(const uint4*)(w1r + k8 * 8));
        acc = fma8(acc, wf, *(const float4*)&hb[k8*8], *(const float4*)&hb[k8*8+4]);
      }
      acc += __shfl_xor(acc, 1);
      if (kh == 0) ast_f(&aring[(size_t)t * 16384 + bglob * 512 + i], acc + b1i);
    }
    bt += 128; grid_bar(bar, bt);
    // ---- P2 (pb,sq): scores -> exp -> partial ctx/S (r13-proven) ----
    {
      u64 v = ald_u8((const u64*)(aring + (size_t)t * 16384 + pb * 512) + tid);
      union { u64 q; float f[2]; } cv; cv.q = v;
      as_[2 * tid] = cv.f[0]; as_[2 * tid + 1] = cv.f[1];
    }
    __syncthreads();
    {
      const int kp = tid >> 6, s_l = tid & 63;
      const int s = sq * 64 + s_l;
      const u16* pr = enc_proj + ((size_t)pb * 256 + s) * 512 + kp * 128;
      const float* ak = as_ + kp * 128;
      const float* vk = vs_ + kp * 128;
      float acc = 0.f;
      for (int k8 = 0; k8 < 16; ++k8) {
        float d[8]; unp8(d, *(const uint4*)(pr + k8 * 8));
        #pragma unroll
        for (int e = 0; e < 8; ++e)
          acc += vk[k8 * 8 + e] * tanh_(d[e] + ak[k8 * 8 + e]);
      }
      scq[kp][s_l] = acc;
    }
    __syncthreads();
    if (tid < 64) {
      float sc = (scq[0][tid] + scq[1][tid]) + (scq[2][tid] + scq[3][tid]);
      float e = __expf(sc);          // bounded scores: no max-shift (proven r7)
      wts[tid] = e;
      float su = e;
      #pragma unroll
      for (int d = 1; d < 64; d <<= 1) su += __shfl_xor(su, d);
      if (tid == 0) ast_f(&sringP[t * 128 + sq * 32 + pb], su);
    }
    __syncthreads();
    {
      const int k0 = tid * 2;
      float c0 = 0.f, c1 = 0.f;
      const u16* eo = enc_outs + ((size_t)pb * 256 + sq * 64) * 512 + k0;
      for (int s = 0; s < 64; ++s) {
        float w = wts[s];
        u32 pair = *(const u32*)(eo + (size_t)s * 512);
        c0 = fmaf(w, blo(pair), c0);
        c1 = fmaf(w, bhi(pair), c1);
      }
      u32 pk = (u32)f2bf(c0) | ((u32)f2bf(c1) << 16);
      ast_u((u32*)(ctxP + (size_t)t * 65536 + (sq * 32 + pb) * 512 + k0), pk);
    }
    bt += 128; grid_bar(bar, bt);
    // ---- P3: combine 4 partials for OUR 8 b's -> csb8, GRU ----
    if (tid < 8) {
      const float* sp = sringP + t * 128;
      int bq = bg * 8 + tid;
      rs[tid] = 1.f / ((ald_f(sp + bq) + ald_f(sp + 32 + bq)) +
                       (ald_f(sp + 64 + bq) + ald_f(sp + 96 + bq)));
    }
    __syncthreads();
    #pragma unroll
    for (int j = 0; j < 4; ++j) {      // 1024 u64-positions x 4 partials
      int idx = j * 256 + tid;
      int lb = idx >> 7, gu = idx & 127;
      const u64* bp = (const u64*)(ctxP + (size_t)t * 65536);
      float c[4] = {0,0,0,0};
      #pragma unroll
      for (int q = 0; q < 4; ++q) {
        float4 d = unp4(ald_u8(bp + (size_t)(q * 32 + bg * 8 + lb) * 128 + gu));
        c[0] += d.x; c[1] += d.y; c[2] += d.z; c[3] += d.w;
      }
      float r = rs[lb];
      int m = gu * 4;
      *(u32*)&csb8[lb * CP8 + m]     = (u32)f2bf(c[0]*r) | ((u32)f2bf(c[1]*r) << 16);
      *(u32*)&csb8[lb * CP8 + m + 2] = (u32)f2bf(c[2]*r) | ((u32)f2bf(c[3]*r) << 16);
    }
    __syncthreads();
    {
      const float* hb = hs8 + b_l * HP + kh * 256;
      const u16*   cb = csb8 + b_l * CP8 + kh * 256;
      float hR=0.f,hZ=0.f,hN=0.f,cR=0.f,cZ=0.f,cN=0.f;
      for (int k8 = 0; k8 < 32; ++k8) {
        float4 h0 = *(const float4*)&hb[k8*8], h1 = *(const float4*)&hb[k8*8+4];
        float cf[8]; unp8(cf, *(const uint4*)(cb + k8 * 8));
        float wf[8];
        unp8(wf, *(const uint4*)(whr + k8 * 8)); hR = fma8(hR, wf, h0, h1);
        unp8(wf, *(const uint4*)(whz + k8 * 8)); hZ = fma8(hZ, wf, h0, h1);
        unp8(wf, *(const uint4*)(whn + k8 * 8)); hN = fma8(hN, wf, h0, h1);
        unp8(wf, *(const uint4*)(wir + k8 * 8)); cR = fma8p(cR, wf, cf);
        unp8(wf, *(const uint4*)(wiz + k8 * 8)); cZ = fma8p(cZ, wf, cf);
        unp8(wf, *(const uint4*)(win + k8 * 8)); cN = fma8p(cN, wf, cf);
      }
      hR += __shfl_xor(hR, 1); hZ += __shfl_xor(hZ, 1); hN += __shfl_xor(hN, 1);
      cR += __shfl_xor(cR, 1); cZ += __shfl_xor(cZ, 1); cN += __shfl_xor(cN, 1);
      if (kh == 0) {
        const size_t g = ((size_t)t * 32 + bglob) * G3;
        float r = sigf (bf2f(gi[g +        i]) + cR + hR + bR);
        float z = sigf (bf2f(gi[g +  512 + i]) + cZ + hZ + bZ);
        float n = tanh_(bf2f(gi[g + 1024 + i]) + cN + r * (hN + bN));
        float h2 = z * hs8[b_l * HP + i] + (1.f - z) * n;
        h2bf[((size_t)t * 32 + bglob) * 512 + i] = f2bf(h2);  // cross-kernel
        h2t[i_l][b_l] = h2;
      }
    }
    __syncthreads();
    if (tid < 64) {   // 64 packed u32: 8 i-pairs x 8 b
      int p = tid >> 3, bl = tid & 7;
      u32 pk = (u32)f2bf(h2t[2*p][bl]) | ((u32)f2bf(h2t[2*p+1][bl]) << 16);
      ast_u((u32*)(hring + (size_t)(257 + t) * 16384)
            + (bg * 8 + bl) * 256 + ig * 8 + p, pk);
    }
    bt += 128; grid_bar(bar, bt);
  }
}

// ---------- K5: fcW f32 -> bf16 (one-time) ----------
__global__ __launch_bounds__(256)
void k_cvt(const float* __restrict__ in, u16* __restrict__ out)
{
  size_t i = ((size_t)blockIdx.x * 256 + threadIdx.x) * 8;
  float4 a = *(const float4*)(in + i);
  float4 b = *(const float4*)(in + i + 4);
  union { uint4 v; u16 s[8]; } u;
  u.s[0]=f2bf(a.x); u.s[1]=f2bf(a.y); u.s[2]=f2bf(a.z); u.s[3]=f2bf(a.w);
  u.s[4]=f2bf(b.x); u.s[5]=f2bf(b.y); u.s[6]=f2bf(b.z); u.s[7]=f2bf(b.w);
  *(uint4*)(out + i) = u.v;
}

// ---------- K6: logits via bf16 MFMA (proven) ----------
__global__ __launch_bounds__(256)
void k_logits_mfma(const u16* __restrict__ A, const u16* __restrict__ Wb,
                   const float* __restrict__ bias, float* __restrict__ out)
{
  __shared__ u16 Al[64 * 512];
  const int tid = threadIdx.x;
  const int r0 = blockIdx.x * 64;
  const int v0 = blockIdx.y * 64;
  {
    const uint4* src = (const uint4*)(A + (size_t)r0 * 512);
    uint4* dst = (uint4*)Al;
    #pragma unroll
    for (int j = 0; j < 16; ++j) {
      int idx = j * 256 + tid;
      int row = idx >> 6, g = idx & 63;
      dst[(row << 6) | (g ^ (row & 7))] = src[idx];
    }
  }
  const int w  = tid >> 6, l = tid & 63;
  const int lr = l & 15,  qk = l >> 4;
  const int v  = v0 + w * 16 + lr;
  frag bfr[16];
  {
    const u16* wrow = Wb + (size_t)v * 512 + qk * 8;
    #pragma unroll
    for (int ks = 0; ks < 16; ++ks)
      bfr[ks] = *(const frag*)(wrow + ks * 32);
  }
  const float bv = bias[v];
  __syncthreads();
  f32x4v acc[4];
  #pragma unroll
  for (int mt = 0; mt < 4; ++mt) acc[mt] = (f32x4v){0.f, 0.f, 0.f, 0.f};
  #pragma unroll
  for (int ks = 0; ks < 16; ++ks) {
    #pragma unroll
    for (int mt = 0; mt < 4; ++mt) {
      const int row = mt * 16 + lr;
      const int gr  = ks * 4 + qk;
      frag a = *(const frag*)&Al[(row << 9) | ((gr ^ (row & 7)) << 3)];
      acc[mt] = __builtin_amdgcn_mfma_f32_16x16x32_bf16(a, bfr[ks], acc[mt], 0, 0, 0);
    }
  }
  #pragma unroll
  for (int mt = 0; mt < 4; ++mt)
    #pragma unroll
    for (int reg = 0; reg < 4; ++reg) {
      const int r = r0 + mt * 16 + qk * 4 + reg;
      out[(size_t)(r & 31) * 64 * VV + (size_t)(r >> 5) * VV + v] = acc[mt][reg] + bv;
    }
}

// ---------- launch ----------
extern "C" void kernel_launch(void* const* d_in, const int* in_sizes, int n_in,
                              void* d_out, int out_size, void* d_ws, size_t ws_size,
                              hipStream_t stream) {
  (void)in_sizes; (void)n_in; (void)out_size; (void)ws_size;
  const int*   src  = (const int*)d_in[0];
  const int*   tgt  = (const int*)d_in[1];
  const float* eemb = (const float*)d_in[2];
  const float* eWih = (const float*)d_in[3];
  const float* eWhh = (const float*)d_in[4];
  const float* ebih = (const float*)d_in[5];
  const float* ebhh = (const float*)d_in[6];
  const float* demb = (const float*)d_in[7];
  const float* aW1  = (const float*)d_in[8];
  const float* ab1  = (const float*)d_in[9];
  const float* aW2  = (const float*)d_in[10];
  const float* ab2  = (const float*)d_in[11];
  const float* av   = (const float*)d_in[12];
  const float* dWih = (const float*)d_in[13];
  const float* dWhh = (const float*)d_in[14];
  const float* dbih = (const float*)d_in[15];
  const float* dbhh = (const float*)d_in[16];
  const float* fcW  = (const float*)d_in[17];
  const float* fcb  = (const float*)d_in[18];
  float* out = (float*)d_out;

  // workspace carve (~71 MiB, r13 layout)
  float* aring   = (float*)d_ws;                 // 64x16384 f32 (4 MiB)
  float* sringP  = aring + 1048576;              // 64x128 f32 (32 KiB)
  u32*   bars    = (u32*)(sringP + 8192);        // 8 u32
  u16*  ctxP     = (u16*)(bars + 8);             // 64x128x512 u16 (8 MiB)
  u16*  hring    = ctxP + 4194304;               // 321x16384 u16 (10.5 MiB)
  u16*  h2bf     = hring + 5259264;              // 1,048,576 u16
  u16*  gi_enc   = h2bf + 1048576;               // 12,582,912 u16
  u16*  gi_dec   = gi_enc + 12582912;            //  3,145,728 u16
  u16*  enc_outs = gi_dec + 3145728;             //  4,194,304 u16
  u16*  enc_proj = enc_outs + 4194304;           //  4,194,304 u16
  u16*  wbf      = gi_enc;  // fcW bf16 alias (dead after k_dec_scan)

  hipMemsetAsync(hring, 0, 16384 * sizeof(u16), stream);   // h0 slot (zeros)
  hipMemsetAsync(bars, 0, 8 * sizeof(u32), stream);        // barrier counters

  k_embed_gemm<<<dim3(6, 512), 256, 0, stream>>>(src, SS, eemb, eWih, EE,  ebih, gi_enc);
  k_embed_gemm<<<dim3(6, 128), 256, 0, stream>>>(tgt, TT, demb, dWih, 768, dbih, gi_dec);

  k_enc_scan<<<128, 256, 0, stream>>>(gi_enc, eWhh, ebhh, hring, enc_outs, bars + 0);

  k_proj<<<dim3(2, 512), 256, 0, stream>>>(enc_outs, aW2, ab2, enc_proj);

  k_dec_scan<<<128, 256, 0, stream>>>(gi_dec, hring, aW1, ab1, av,
                                      enc_proj, enc_outs, dWhh, dWih, dbhh,
                                      aring, ctxP, sringP, h2bf, bars + 1);

  k_cvt<<<8000, 256, 0, stream>>>(fcW, wbf);

  k_logits_mfma<<<dim3(32, 500), 256, 0, stream>>>(h2bf, wbf, fcb, out);
}

// Round 17
// 5357.349 us; speedup vs baseline: 1.5823x; 1.1331x over previous
//
#include <hip/hip_runtime.h>
#include <hip/hip_bf16.h>
#include <stdint.h>

#define DEV __device__ __forceinline__
typedef unsigned short u16;
typedef unsigned int   u32;
typedef unsigned long long u64;

static constexpr int SS = 256;   // src len
static constexpr int TT = 64;    // tgt len
static constexpr int EE = 256;   // embed dim
static constexpr int HH = 512;   // hidden
static constexpr int G3 = 1536;  // 3*H
static constexpr int VV = 32000; // vocab
static constexpr int HP  = 516;  // padded f32 LDS row (h tiles)
static constexpr int WPE = 516;  // padded f32 weight row (encoder)
static constexpr int WPD = 520;  // padded u16 weight row (decoder)
static constexpr int CP8 = 520;  // padded u16 ctx row (decoder)

using frag   = __attribute__((ext_vector_type(8))) short;  // 8 bf16
using f32x4v = __attribute__((ext_vector_type(4))) float;  // MFMA acc

// ---------- helpers ----------
DEV float blo(u32 u){ union{u32 i; float f;} x; x.i = u << 16;         return x.f; }
DEV float bhi(u32 u){ union{u32 i; float f;} x; x.i = u & 0xffff0000u; return x.f; }
DEV float bf2f(u16 u){ union{u32 i; float f;} x; x.i = ((u32)u) << 16; return x.f; }
DEV u16 f2bf(float f){ union{float f; u32 u;} v; v.f = f;
  u32 r = v.u + 0x7fffu + ((v.u >> 16) & 1u); return (u16)(r >> 16); }
DEV float sigf (float x){ return 1.0f / (1.0f + __expf(-x)); }
DEV float tanh_(float x){ return 1.0f - 2.0f / (1.0f + __expf(2.0f * x)); }
DEV void unp8(float* d, uint4 u){
  d[0]=blo(u.x); d[1]=bhi(u.x); d[2]=blo(u.y); d[3]=bhi(u.y);
  d[4]=blo(u.z); d[5]=bhi(u.z); d[6]=blo(u.w); d[7]=bhi(u.w);
}
DEV float4 unp4(u64 v){
  return make_float4(bf2f((u16)v), bf2f((u16)(v >> 16)),
                     bf2f((u16)(v >> 32)), bf2f((u16)(v >> 48)));
}
DEV float dot4(float acc, float4 w, float4 x){
  acc = fmaf(w.x,x.x,acc); acc = fmaf(w.y,x.y,acc);
  acc = fmaf(w.z,x.z,acc); acc = fmaf(w.w,x.w,acc);
  return acc;
}
DEV float fma44(float acc, float4 w0, float4 w1, float4 h0, float4 h1){
  return dot4(dot4(acc, w0, h0), w1, h1);
}
DEV float fma8(float acc, const float* w, float4 a, float4 b){
  acc = fmaf(w[0],a.x,acc); acc = fmaf(w[1],a.y,acc);
  acc = fmaf(w[2],a.z,acc); acc = fmaf(w[3],a.w,acc);
  acc = fmaf(w[4],b.x,acc); acc = fmaf(w[5],b.y,acc);
  acc = fmaf(w[6],b.z,acc); acc = fmaf(w[7],b.w,acc);
  return acc;
}
DEV float fma8p(float acc, const float* w, const float* x){
  #pragma unroll
  for (int e = 0; e < 8; ++e) acc = fmaf(w[e], x[e], acc);
  return acc;
}

// ---- agent-scope atomics (r9/r13-proven coherence rule) ----
DEV void  ast_f(float* p, float v){ __hip_atomic_store(p, v, __ATOMIC_RELAXED, __HIP_MEMORY_SCOPE_AGENT); }
DEV void  ast_u(u32* p, u32 v)    { __hip_atomic_store(p, v, __ATOMIC_RELAXED, __HIP_MEMORY_SCOPE_AGENT); }
DEV float ald_f(const float* p)   { return __hip_atomic_load((float*)p, __ATOMIC_RELAXED, __HIP_MEMORY_SCOPE_AGENT); }
DEV u64   ald_u8(const u64* p)    { return __hip_atomic_load((u64*)p,   __ATOMIC_RELAXED, __HIP_MEMORY_SCOPE_AGENT); }
DEV u32   ald_u (const u32* p)    { return __hip_atomic_load((u32*)p,   __ATOMIC_RELAXED, __HIP_MEMORY_SCOPE_AGENT); }

// DISTRIBUTED grid barrier (r17): no contended RMW. Block bid publishes its
// epoch to its own 128B-spaced flag; thread j<nb polls block j's flag.
// Visibility: __syncthreads drains each wave's stores before tid0 publishes
// (same ordering argument as the r7-r16 counter barrier, proven green).
DEV void grid_bar(u32* flags, int bid, int nb, u32 epoch){
  __syncthreads();
  if (threadIdx.x == 0) ast_u(&flags[bid * 32], epoch);
  if (threadIdx.x < (u32)nb) {
    while (ald_u(&flags[threadIdx.x * 32]) < epoch)
      __builtin_amdgcn_s_sleep(1);
  }
  __syncthreads();
}

// ---------- K1: gi = gather(emb, tok) @ W[:, :256]^T + bih  (bf16 out) ----
__global__ __launch_bounds__(256)
void k_embed_gemm(const int* __restrict__ tok, int Tlen,
                  const float* __restrict__ emb,
                  const float* __restrict__ W, int wstride,
                  const float* __restrict__ bias,
                  u16* __restrict__ gi)
{
  __shared__ float es[16][EE];
  const int tid = threadIdx.x;
  const int r0 = blockIdx.y * 16;
  #pragma unroll
  for (int rr = 0; rr < 16; ++rr) {
    int r = r0 + rr;
    int token = tok[(r & 31) * Tlen + (r >> 5)];
    es[rr][tid] = emb[(size_t)token * EE + tid];
  }
  __syncthreads();
  const int jl = tid & 63;
  const int rg = (tid >> 6) << 2;
  const int jbase = blockIdx.x * 256 + jl;
  float acc[4][4];
  #pragma unroll
  for (int jj = 0; jj < 4; ++jj) {
    float bv = bias[jbase + jj * 64];
    #pragma unroll
    for (int rr = 0; rr < 4; ++rr) acc[jj][rr] = bv;
  }
  const float4* w0 = (const float4*)(W + (size_t)(jbase      ) * wstride);
  const float4* w1 = (const float4*)(W + (size_t)(jbase +  64) * wstride);
  const float4* w2 = (const float4*)(W + (size_t)(jbase + 128) * wstride);
  const float4* w3 = (const float4*)(W + (size_t)(jbase + 192) * wstride);
  for (int k4 = 0; k4 < EE / 4; ++k4) {
    float4 wv0 = w0[k4], wv1 = w1[k4], wv2 = w2[k4], wv3 = w3[k4];
    #pragma unroll
    for (int rr = 0; rr < 4; ++rr) {
      float4 e = *(const float4*)&es[rg + rr][k4 * 4];
      acc[0][rr] = dot4(acc[0][rr], wv0, e);
      acc[1][rr] = dot4(acc[1][rr], wv1, e);
      acc[2][rr] = dot4(acc[2][rr], wv2, e);
      acc[3][rr] = dot4(acc[3][rr], wv3, e);
    }
  }
  #pragma unroll
  for (int rr = 0; rr < 4; ++rr)
    #pragma unroll
    for (int jj = 0; jj < 4; ++jj)
      gi[(size_t)(r0 + rg + rr) * G3 + jbase + jj * 64] = f2bf(acc[jj][rr]);
}

// ---------- K2: encoder GRU scan — persistent, 128 blocks, 1 bar/step ----
__global__ __launch_bounds__(256)
void k_enc_scan(const u16* __restrict__ gi, const float* __restrict__ Whh,
                const float* __restrict__ bhh, u16* __restrict__ hring,
                u16* __restrict__ enc_outs, u32* __restrict__ flags)
{
  __shared__ float hs[32 * HP];     // 66.0 KB
  __shared__ float wsl[12 * WPE];   // 24.8 KB f32
  __shared__ float h2t[4][32];
  const int tid = threadIdx.x;
  const int bid = blockIdx.x;
  const int i0 = bid * 4;
  #pragma unroll
  for (int j = 0; j < 6; ++j) {     // stage 12 rows x 512 f32
    int f = (j * 256 + tid) * 4;
    int rowl = f >> 9, k = f & 511;
    int g = rowl >> 2, ri = rowl & 3;
    *(float4*)&wsl[rowl * WPE + k] =
      *(const float4*)(Whh + (size_t)(g * 512 + i0 + ri) * 512 + k);
  }
  const int i_l = tid >> 6, lane = tid & 63, b = lane >> 1, kh = lane & 1;
  const int i = i0 + i_l;
  const float* w0 = wsl + (0 * 4 + i_l) * WPE + kh * 256;
  const float* w1 = wsl + (1 * 4 + i_l) * WPE + kh * 256;
  const float* w2 = wsl + (2 * 4 + i_l) * WPE + kh * 256;
  const float bR = bhh[i], bZ = bhh[i + 512], bN = bhh[i + 1024];
  for (int t = 0; t < SS; ++t) {
    const u64* hsrc = (const u64*)(hring + (size_t)t * 16384);
    #pragma unroll
    for (int j = 0; j < 16; ++j) {
      int idx = j * 256 + tid;
      u64 v = ald_u8(hsrc + idx);
      int bb = idx >> 7, m = (idx & 127) * 4;
      *(float4*)&hs[bb * HP + m] = unp4(v);
    }
    __syncthreads();
    float aR = 0.f, aZ = 0.f, aN = 0.f;
    const float* hb = hs + b * HP + kh * 256;
    for (int k8 = 0; k8 < 32; ++k8) {
      float4 h0 = *(const float4*)&hb[k8*8], h1 = *(const float4*)&hb[k8*8+4];
      aR = fma44(aR, *(const float4*)&w0[k8*8], *(const float4*)&w0[k8*8+4], h0, h1);
      aZ = fma44(aZ, *(const float4*)&w1[k8*8], *(const float4*)&w1[k8*8+4], h0, h1);
      aN = fma44(aN, *(const float4*)&w2[k8*8], *(const float4*)&w2[k8*8+4], h0, h1);
    }
    aR += __shfl_xor(aR, 1);
    aZ += __shfl_xor(aZ, 1);
    aN += __shfl_xor(aN, 1);
    if (kh == 0) {
      const size_t g = ((size_t)t * 32 + b) * G3;
      float r = sigf (bf2f(gi[g +        i]) + aR + bR);
      float z = sigf (bf2f(gi[g +  512 + i]) + aZ + bZ);
      float n = tanh_(bf2f(gi[g + 1024 + i]) + r * (aN + bN));
      float h2 = z * hs[b * HP + i] + (1.f - z) * n;
      enc_outs[((size_t)b * 256 + t) * 512 + i] = f2bf(h2);
      h2t[i_l][b] = h2;
    }
    __syncthreads();
    if (tid < 64) {
      int p = tid >> 5, bq = tid & 31;
      u32 pk = (u32)f2bf(h2t[2*p][bq]) | ((u32)f2bf(h2t[2*p+1][bq]) << 16);
      ast_u((u32*)(hring + (size_t)(t + 1) * 16384) + bq * 256 + bid * 2 + p, pk);
    }
    grid_bar(flags, bid, 128, (u32)(t + 1));
  }
}

// ---------- K3: enc_proj = enc_outs @ attn_W2^T + b2 ----------
__global__ __launch_bounds__(256)
void k_proj(const u16* __restrict__ A, const float* __restrict__ W,
            const float* __restrict__ bias, u16* __restrict__ Out)
{
  __shared__ float es[16][HH];
  const int tid = threadIdx.x;
  const int r0 = blockIdx.y * 16;
  #pragma unroll
  for (int j = 0; j < 4; ++j) {
    int u = j * 256 + tid;
    int row = u >> 6, k = (u & 63) * 8;
    float d[8]; unp8(d, *(const uint4*)(A + (size_t)(r0 + row) * HH + k));
    *(float4*)&es[row][k]     = make_float4(d[0],d[1],d[2],d[3]);
    *(float4*)&es[row][k + 4] = make_float4(d[4],d[5],d[6],d[7]);
  }
  __syncthreads();
  const int jl = tid & 63;
  const int rg = (tid >> 6) << 2;
  const int jbase = blockIdx.x * 256 + jl;
  float acc[4][4];
  #pragma unroll
  for (int jj = 0; jj < 4; ++jj) {
    float bv = bias[jbase + jj * 64];
    #pragma unroll
    for (int rr = 0; rr < 4; ++rr) acc[jj][rr] = bv;
  }
  const float4* w0 = (const float4*)(W + (size_t)(jbase      ) * HH);
  const float4* w1 = (const float4*)(W + (size_t)(jbase +  64) * HH);
  const float4* w2 = (const float4*)(W + (size_t)(jbase + 128) * HH);
  const float4* w3 = (const float4*)(W + (size_t)(jbase + 192) * HH);
  for (int k4 = 0; k4 < HH / 4; ++k4) {
    float4 wv0 = w0[k4], wv1 = w1[k4], wv2 = w2[k4], wv3 = w3[k4];
    #pragma unroll
    for (int rr = 0; rr < 4; ++rr) {
      float4 e = *(const float4*)&es[rg + rr][k4 * 4];
      acc[0][rr] = dot4(acc[0][rr], wv0, e);
      acc[1][rr] = dot4(acc[1][rr], wv1, e);
      acc[2][rr] = dot4(acc[2][rr], wv2, e);
      acc[3][rr] = dot4(acc[3][rr], wv3, e);
    }
  }
  #pragma unroll
  for (int rr = 0; rr < 4; ++rr)
    #pragma unroll
    for (int jj = 0; jj < 4; ++jj)
      Out[(size_t)(r0 + rg + rr) * HH + jbase + jj * 64] = f2bf(acc[jj][rr]);
}

// ---------- K4: decoder scan — b-partitioned P1/P3 (r16-proven) ----------
__global__ __launch_bounds__(256)
void k_dec_scan(const u16* __restrict__ gi, u16* __restrict__ hring,
                const float* __restrict__ W1, const float* __restrict__ b1,
                const float* __restrict__ av,
                const u16* __restrict__ enc_proj, const u16* __restrict__ enc_outs,
                const float* __restrict__ Whh, const float* __restrict__ Wih,
                const float* __restrict__ bhh,
                float* __restrict__ aring, u16* __restrict__ ctxP,
                float* __restrict__ sringP, u16* __restrict__ h2bf,
                u32* __restrict__ flags)
{
  __shared__ float hs8[8 * HP];      // 16.5 KB
  __shared__ u16  csb8[8 * CP8];     //  8.3 KB
  __shared__ u16  wlds[112 * WPD];   // 113.8 KB
  __shared__ float as_[512], vs_[512];
  __shared__ float scq[4][64], wts[64];
  __shared__ float rs[8];
  __shared__ float h2t[16][8];
  const int tid = threadIdx.x;
  const int bid = blockIdx.x;
  const int bg = bid >> 5, ig = bid & 31;
  const int b_l = tid >> 5, i_l = (tid >> 1) & 15, kh = tid & 1;
  const int i = ig * 16 + i_l;
  const int bglob = bg * 8 + b_l;
  const int pb = bid >> 2, sq = bid & 3;
  vs_[tid] = av[tid]; vs_[tid + 256] = av[tid + 256];
  for (int j = 0; j < 56; ++j) {
    int idx = j * 256 + tid;
    int row = idx >> 7, k4 = idx & 127;
    const float* src;
    if (row < 16)      src = W1  + (size_t)(ig * 16 + row) * 512 + k4 * 4;
    else if (row < 64) { int rr = row - 16; int g = rr >> 4, ii = rr & 15;
                         src = Whh + (size_t)(g * 512 + ig * 16 + ii) * 512 + k4 * 4; }
    else               { int rr = row - 64; int g = rr >> 4, ii = rr & 15;
                         src = Wih + (size_t)(g * 512 + ig * 16 + ii) * 768 + 256 + k4 * 4; }
    float4 w = *(const float4*)src;
    int f = row * WPD + k4 * 4;
    wlds[f] = f2bf(w.x); wlds[f+1] = f2bf(w.y); wlds[f+2] = f2bf(w.z); wlds[f+3] = f2bf(w.w);
  }
  const u16* w1r = wlds + (      i_l) * WPD + kh * 256;
  const u16* whr = wlds + (16  + i_l) * WPD + kh * 256;
  const u16* whz = wlds + (32  + i_l) * WPD + kh * 256;
  const u16* whn = wlds + (48  + i_l) * WPD + kh * 256;
  const u16* wir = wlds + (64  + i_l) * WPD + kh * 256;
  const u16* wiz = wlds + (80  + i_l) * WPD + kh * 256;
  const u16* win = wlds + (96  + i_l) * WPD + kh * 256;
  const float bR = bhh[i], bZ = bhh[i + 512], bN = bhh[i + 1024];
  const float b1i = b1[i];
  u32 ep = 0;
  for (int t = 0; t < TT; ++t) {
    const u64* hsrc = (const u64*)(hring + (size_t)(256 + t) * 16384);
    #pragma unroll
    for (int j = 0; j < 4; ++j) {
      int idx = j * 256 + tid;
      int lb = idx >> 7, gu = idx & 127;
      u64 v = ald_u8(hsrc + (size_t)(bg * 8 + lb) * 128 + gu);
      *(float4*)&hs8[lb * HP + gu * 4] = unp4(v);
    }
    __syncthreads();
    // ---- P1 ----
    {
      const float* hb = hs8 + b_l * HP + kh * 256;
      float acc = 0.f;
      for (int k8 = 0; k8 < 32; ++k8) {
        float wf[8]; unp8(wf, *(const uint4*)(w1r + k8 * 8));
        acc = fma8(acc, wf, *(const float4*)&hb[k8*8], *(const float4*)&hb[k8*8+4]);
      }
      acc += __shfl_xor(acc, 1);
      if (kh == 0) ast_f(&aring[(size_t)t * 16384 + bglob * 512 + i], acc + b1i);
    }
    ++ep; grid_bar(flags, bid, 128, ep);
    // ---- P2 (pb,sq): scores -> exp -> partial ctx/S ----
    {
      u64 v = ald_u8((const u64*)(aring + (size_t)t * 16384 + pb * 512) + tid);
      union { u64 q; float f[2]; } cv; cv.q = v;
      as_[2 * tid] = cv.f[0]; as_[2 * tid + 1] = cv.f[1];
    }
    __syncthreads();
    {
      const int kp = tid >> 6, s_l = tid & 63;
      const int s = sq * 64 + s_l;
      const u16* pr = enc_proj + ((size_t)pb * 256 + s) * 512 + kp * 128;
      const float* ak = as_ + kp * 128;
      const float* vk = vs_ + kp * 128;
      float acc = 0.f;
      for (int k8 = 0; k8 < 16; ++k8) {
        float d[8]; unp8(d, *(const uint4*)(pr + k8 * 8));
        #pragma unroll
        for (int e = 0; e < 8; ++e)
          acc += vk[k8 * 8 + e] * tanh_(d[e] + ak[k8 * 8 + e]);
      }
      scq[kp][s_l] = acc;
    }
    __syncthreads();
    if (tid < 64) {
      float sc = (scq[0][tid] + scq[1][tid]) + (scq[2][tid] + scq[3][tid]);
      float e = __expf(sc);          // bounded scores: no max-shift (proven r7)
      wts[tid] = e;
      float su = e;
      #pragma unroll
      for (int d = 1; d < 64; d <<= 1) su += __shfl_xor(su, d);
      if (tid == 0) ast_f(&sringP[t * 128 + sq * 32 + pb], su);
    }
    __syncthreads();
    {
      const int k0 = tid * 2;
      float c0 = 0.f, c1 = 0.f;
      const u16* eo = enc_outs + ((size_t)pb * 256 + sq * 64) * 512 + k0;
      for (int s = 0; s < 64; ++s) {
        float w = wts[s];
        u32 pair = *(const u32*)(eo + (size_t)s * 512);
        c0 = fmaf(w, blo(pair), c0);
        c1 = fmaf(w, bhi(pair), c1);
      }
      u32 pk = (u32)f2bf(c0) | ((u32)f2bf(c1) << 16);
      ast_u((u32*)(ctxP + (size_t)t * 65536 + (sq * 32 + pb) * 512 + k0), pk);
    }
    ++ep; grid_bar(flags, bid, 128, ep);
    // ---- P3: combine partials for OUR 8 b's, GRU ----
    if (tid < 8) {
      const float* sp = sringP + t * 128;
      int bq = bg * 8 + tid;
      rs[tid] = 1.f / ((ald_f(sp + bq) + ald_f(sp + 32 + bq)) +
                       (ald_f(sp + 64 + bq) + ald_f(sp + 96 + bq)));
    }
    __syncthreads();
    #pragma unroll
    for (int j = 0; j < 4; ++j) {
      int idx = j * 256 + tid;
      int lb = idx >> 7, gu = idx & 127;
      const u64* bp = (const u64*)(ctxP + (size_t)t * 65536);
      float c[4] = {0,0,0,0};
      #pragma unroll
      for (int q = 0; q < 4; ++q) {
        float4 d = unp4(ald_u8(bp + (size_t)(q * 32 + bg * 8 + lb) * 128 + gu));
        c[0] += d.x; c[1] += d.y; c[2] += d.z; c[3] += d.w;
      }
      float r = rs[lb];
      int m = gu * 4;
      *(u32*)&csb8[lb * CP8 + m]     = (u32)f2bf(c[0]*r) | ((u32)f2bf(c[1]*r) << 16);
      *(u32*)&csb8[lb * CP8 + m + 2] = (u32)f2bf(c[2]*r) | ((u32)f2bf(c[3]*r) << 16);
    }
    __syncthreads();
    {
      const float* hb = hs8 + b_l * HP + kh * 256;
      const u16*   cb = csb8 + b_l * CP8 + kh * 256;
      float hR=0.f,hZ=0.f,hN=0.f,cR=0.f,cZ=0.f,cN=0.f;
      for (int k8 = 0; k8 < 32; ++k8) {
        float4 h0 = *(const float4*)&hb[k8*8], h1 = *(const float4*)&hb[k8*8+4];
        float cf[8]; unp8(cf, *(const uint4*)(cb + k8 * 8));
        float wf[8];
        unp8(wf, *(const uint4*)(whr + k8 * 8)); hR = fma8(hR, wf, h0, h1);
        unp8(wf, *(const uint4*)(whz + k8 * 8)); hZ = fma8(hZ, wf, h0, h1);
        unp8(wf, *(const uint4*)(whn + k8 * 8)); hN = fma8(hN, wf, h0, h1);
        unp8(wf, *(const uint4*)(wir + k8 * 8)); cR = fma8p(cR, wf, cf);
        unp8(wf, *(const uint4*)(wiz + k8 * 8)); cZ = fma8p(cZ, wf, cf);
        unp8(wf, *(const uint4*)(win + k8 * 8)); cN = fma8p(cN, wf, cf);
      }
      hR += __shfl_xor(hR, 1); hZ += __shfl_xor(hZ, 1); hN += __shfl_xor(hN, 1);
      cR += __shfl_xor(cR, 1); cZ += __shfl_xor(cZ, 1); cN += __shfl_xor(cN, 1);
      if (kh == 0) {
        const size_t g = ((size_t)t * 32 + bglob) * G3;
        float r = sigf (bf2f(gi[g +        i]) + cR + hR + bR);
        float z = sigf (bf2f(gi[g +  512 + i]) + cZ + hZ + bZ);
        float n = tanh_(bf2f(gi[g + 1024 + i]) + cN + r * (hN + bN));
        float h2 = z * hs8[b_l * HP + i] + (1.f - z) * n;
        h2bf[((size_t)t * 32 + bglob) * 512 + i] = f2bf(h2);  // cross-kernel
        h2t[i_l][b_l] = h2;
      }
    }
    __syncthreads();
    if (tid < 64) {
      int p = tid >> 3, bl = tid & 7;
      u32 pk = (u32)f2bf(h2t[2*p][bl]) | ((u32)f2bf(h2t[2*p+1][bl]) << 16);
      ast_u((u32*)(hring + (size_t)(257 + t) * 16384)
            + (bg * 8 + bl) * 256 + ig * 8 + p, pk);
    }
    ++ep; grid_bar(flags, bid, 128, ep);
  }
}

// ---------- K5: fcW f32 -> bf16 (one-time) ----------
__global__ __launch_bounds__(256)
void k_cvt(const float* __restrict__ in, u16* __restrict__ out)
{
  size_t i = ((size_t)blockIdx.x * 256 + threadIdx.x) * 8;
  float4 a = *(const float4*)(in + i);
  float4 b = *(const float4*)(in + i + 4);
  union { uint4 v; u16 s[8]; } u;
  u.s[0]=f2bf(a.x); u.s[1]=f2bf(a.y); u.s[2]=f2bf(a.z); u.s[3]=f2bf(a.w);
  u.s[4]=f2bf(b.x); u.s[5]=f2bf(b.y); u.s[6]=f2bf(b.z); u.s[7]=f2bf(b.w);
  *(uint4*)(out + i) = u.v;
}

// ---------- K6: logits via bf16 MFMA (proven) ----------
__global__ __launch_bounds__(256)
void k_logits_mfma(const u16* __restrict__ A, const u16* __restrict__ Wb,
                   const float* __restrict__ bias, float* __restrict__ out)
{
  __shared__ u16 Al[64 * 512];
  const int tid = threadIdx.x;
  const int r0 = blockIdx.x * 64;
  const int v0 = blockIdx.y * 64;
  {
    const uint4* src = (const uint4*)(A + (size_t)r0 * 512);
    uint4* dst = (uint4*)Al;
    #pragma unroll
    for (int j = 0; j < 16; ++j) {
      int idx = j * 256 + tid;
      int row = idx >> 6, g = idx & 63;
      dst[(row << 6) | (g ^ (row & 7))] = src[idx];
    }
  }
  const int w  = tid >> 6, l = tid & 63;
  const int lr = l & 15,  qk = l >> 4;
  const int v  = v0 + w * 16 + lr;
  frag bfr[16];
  {
    const u16* wrow = Wb + (size_t)v * 512 + qk * 8;
    #pragma unroll
    for (int ks = 0; ks < 16; ++ks)
      bfr[ks] = *(const frag*)(wrow + ks * 32);
  }
  const float bv = bias[v];
  __syncthreads();
  f32x4v acc[4];
  #pragma unroll
  for (int mt = 0; mt < 4; ++mt) acc[mt] = (f32x4v){0.f, 0.f, 0.f, 0.f};
  #pragma unroll
  for (int ks = 0; ks < 16; ++ks) {
    #pragma unroll
    for (int mt = 0; mt < 4; ++mt) {
      const int row = mt * 16 + lr;
      const int gr  = ks * 4 + qk;
      frag a = *(const frag*)&Al[(row << 9) | ((gr ^ (row & 7)) << 3)];
      acc[mt] = __builtin_amdgcn_mfma_f32_16x16x32_bf16(a, bfr[ks], acc[mt], 0, 0, 0);
    }
  }
  #pragma unroll
  for (int mt = 0; mt < 4; ++mt)
    #pragma unroll
    for (int reg = 0; reg < 4; ++reg) {
      const int r = r0 + mt * 16 + qk * 4 + reg;
      out[(size_t)(r & 31) * 64 * VV + (size_t)(r >> 5) * VV + v] = acc[mt][reg] + bv;
    }
}

// ---------- launch ----------
extern "C" void kernel_launch(void* const* d_in, const int* in_sizes, int n_in,
                              void* d_out, int out_size, void* d_ws, size_t ws_size,
                              hipStream_t stream) {
  (void)in_sizes; (void)n_in; (void)out_size; (void)ws_size;
  const int*   src  = (const int*)d_in[0];
  const int*   tgt  = (const int*)d_in[1];
  const float* eemb = (const float*)d_in[2];
  const float* eWih = (const float*)d_in[3];
  const float* eWhh = (const float*)d_in[4];
  const float* ebih = (const float*)d_in[5];
  const float* ebhh = (const float*)d_in[6];
  const float* demb = (const float*)d_in[7];
  const float* aW1  = (const float*)d_in[8];
  const float* ab1  = (const float*)d_in[9];
  const float* aW2  = (const float*)d_in[10];
  const float* ab2  = (const float*)d_in[11];
  const float* av   = (const float*)d_in[12];
  const float* dWih = (const float*)d_in[13];
  const float* dWhh = (const float*)d_in[14];
  const float* dbih = (const float*)d_in[15];
  const float* dbhh = (const float*)d_in[16];
  const float* fcW  = (const float*)d_in[17];
  const float* fcb  = (const float*)d_in[18];
  float* out = (float*)d_out;

  // workspace carve (~71 MiB)
  float* aring   = (float*)d_ws;                 // 64x16384 f32 (4 MiB)
  float* sringP  = aring + 1048576;              // 64x128 f32 (32 KiB)
  u32*   flags   = (u32*)(sringP + 8192);        // 2x128x32 u32 (32 KiB)
  u16*  ctxP     = (u16*)(flags + 8192);         // 64x128x512 u16 (8 MiB)
  u16*  hring    = ctxP + 4194304;               // 321x16384 u16 (10.5 MiB)
  u16*  h2bf     = hring + 5259264;              // 1,048,576 u16
  u16*  gi_enc   = h2bf + 1048576;               // 12,582,912 u16
  u16*  gi_dec   = gi_enc + 12582912;            //  3,145,728 u16
  u16*  enc_outs = gi_dec + 3145728;             //  4,194,304 u16
  u16*  enc_proj = enc_outs + 4194304;           //  4,194,304 u16
  u16*  wbf      = gi_enc;  // fcW bf16 alias (dead after k_dec_scan)

  hipMemsetAsync(hring, 0, 16384 * sizeof(u16), stream);   // h0 slot (zeros)
  hipMemsetAsync(flags, 0, 8192 * sizeof(u32), stream);    // barrier flags

  k_embed_gemm<<<dim3(6, 512), 256, 0, stream>>>(src, SS, eemb, eWih, EE,  ebih, gi_enc);
  k_embed_gemm<<<dim3(6, 128), 256, 0, stream>>>(tgt, TT, demb, dWih, 768, dbih, gi_dec);

  k_enc_scan<<<128, 256, 0, stream>>>(gi_enc, eWhh, ebhh, hring, enc_outs, flags);

  k_proj<<<dim3(2, 512), 256, 0, stream>>>(enc_outs, aW2, ab2, enc_proj);

  k_dec_scan<<<128, 256, 0, stream>>>(gi_dec, hring, aW1, ab1, av,
                                      enc_proj, enc_outs, dWhh, dWih, dbhh,
                                      aring, ctxP, sringP, h2bf, flags + 4096);

  k_cvt<<<8000, 256, 0, stream>>>(fcW, wbf);

  k_logits_mfma<<<dim3(32, 500), 256, 0, stream>>>(h2bf, wbf, fcb, out);
}

// Round 18
// 4948.064 us; speedup vs baseline: 1.7132x; 1.0827x over previous
//
#include <hip/hip_runtime.h>
#include <hip/hip_bf16.h>
#include <stdint.h>

#define DEV __device__ __forceinline__
typedef unsigned short u16;
typedef unsigned int   u32;
typedef unsigned long long u64;

static constexpr int SS = 256;   // src len
static constexpr int TT = 64;    // tgt len
static constexpr int EE = 256;   // embed dim
static constexpr int HH = 512;   // hidden
static constexpr int G3 = 1536;  // 3*H
static constexpr int VV = 32000; // vocab
static constexpr int HP  = 516;  // padded f32 LDS row (h tiles)
static constexpr int WPE = 516;  // padded f32 weight row (encoder)
static constexpr int WPD = 520;  // padded u16 weight row (decoder)
static constexpr int CP8 = 520;  // padded u16 ctx row (decoder)

using frag   = __attribute__((ext_vector_type(8))) short;  // 8 bf16
using f32x4v = __attribute__((ext_vector_type(4))) float;  // MFMA acc

// ---------- helpers ----------
DEV float blo(u32 u){ union{u32 i; float f;} x; x.i = u << 16;         return x.f; }
DEV float bhi(u32 u){ union{u32 i; float f;} x; x.i = u & 0xffff0000u; return x.f; }
DEV float bf2f(u16 u){ union{u32 i; float f;} x; x.i = ((u32)u) << 16; return x.f; }
DEV u16 f2bf(float f){ union{float f; u32 u;} v; v.f = f;
  u32 r = v.u + 0x7fffu + ((v.u >> 16) & 1u); return (u16)(r >> 16); }
DEV float sigf (float x){ return 1.0f / (1.0f + __expf(-x)); }
DEV float tanh_(float x){ return 1.0f - 2.0f / (1.0f + __expf(2.0f * x)); }
DEV void unp8(float* d, uint4 u){
  d[0]=blo(u.x); d[1]=bhi(u.x); d[2]=blo(u.y); d[3]=bhi(u.y);
  d[4]=blo(u.z); d[5]=bhi(u.z); d[6]=blo(u.w); d[7]=bhi(u.w);
}
DEV float4 unp4(u64 v){
  return make_float4(bf2f((u16)v), bf2f((u16)(v >> 16)),
                     bf2f((u16)(v >> 32)), bf2f((u16)(v >> 48)));
}
DEV float dot4(float acc, float4 w, float4 x){
  acc = fmaf(w.x,x.x,acc); acc = fmaf(w.y,x.y,acc);
  acc = fmaf(w.z,x.z,acc); acc = fmaf(w.w,x.w,acc);
  return acc;
}
DEV float fma44(float acc, float4 w0, float4 w1, float4 h0, float4 h1){
  return dot4(dot4(acc, w0, h0), w1, h1);
}
DEV float fma8(float acc, const float* w, float4 a, float4 b){
  acc = fmaf(w[0],a.x,acc); acc = fmaf(w[1],a.y,acc);
  acc = fmaf(w[2],a.z,acc); acc = fmaf(w[3],a.w,acc);
  acc = fmaf(w[4],b.x,acc); acc = fmaf(w[5],b.y,acc);
  acc = fmaf(w[6],b.z,acc); acc = fmaf(w[7],b.w,acc);
  return acc;
}
DEV float fma8p(float acc, const float* w, const float* x){
  #pragma unroll
  for (int e = 0; e < 8; ++e) acc = fmaf(w[e], x[e], acc);
  return acc;
}

// ---- agent-scope atomics (r9/r13-proven coherence rule) ----
DEV void  ast_f(float* p, float v){ __hip_atomic_store(p, v, __ATOMIC_RELAXED, __HIP_MEMORY_SCOPE_AGENT); }
DEV void  ast_u(u32* p, u32 v)    { __hip_atomic_store(p, v, __ATOMIC_RELAXED, __HIP_MEMORY_SCOPE_AGENT); }
DEV float ald_f(const float* p)   { return __hip_atomic_load((float*)p, __ATOMIC_RELAXED, __HIP_MEMORY_SCOPE_AGENT); }
DEV u64   ald_u8(const u64* p)    { return __hip_atomic_load((u64*)p,   __ATOMIC_RELAXED, __HIP_MEMORY_SCOPE_AGENT); }
DEV u32   ald_u (const u32* p)    { return __hip_atomic_load((u32*)p,   __ATOMIC_RELAXED, __HIP_MEMORY_SCOPE_AGENT); }

// Distributed grid barrier (r17-proven): block publishes its epoch to its own
// 128B-spaced flag; threads j<nb poll block j's flag. No contended RMW.
DEV void grid_bar(u32* flags, int bid, int nb, u32 epoch){
  __syncthreads();
  if (threadIdx.x == 0) ast_u(&flags[bid * 32], epoch);
  if (threadIdx.x < (u32)nb) {
    while (ald_u(&flags[threadIdx.x * 32]) < epoch)
      __builtin_amdgcn_s_sleep(1);
  }
  __syncthreads();
}

// ---------- K1: gi = gather(emb, tok) @ W[:, :256]^T + bih  (bf16 out) ----
__global__ __launch_bounds__(256)
void k_embed_gemm(const int* __restrict__ tok, int Tlen,
                  const float* __restrict__ emb,
                  const float* __restrict__ W, int wstride,
                  const float* __restrict__ bias,
                  u16* __restrict__ gi)
{
  __shared__ float es[16][EE];
  const int tid = threadIdx.x;
  const int r0 = blockIdx.y * 16;
  #pragma unroll
  for (int rr = 0; rr < 16; ++rr) {
    int r = r0 + rr;
    int token = tok[(r & 31) * Tlen + (r >> 5)];
    es[rr][tid] = emb[(size_t)token * EE + tid];
  }
  __syncthreads();
  const int jl = tid & 63;
  const int rg = (tid >> 6) << 2;
  const int jbase = blockIdx.x * 256 + jl;
  float acc[4][4];
  #pragma unroll
  for (int jj = 0; jj < 4; ++jj) {
    float bv = bias[jbase + jj * 64];
    #pragma unroll
    for (int rr = 0; rr < 4; ++rr) acc[jj][rr] = bv;
  }
  const float4* w0 = (const float4*)(W + (size_t)(jbase      ) * wstride);
  const float4* w1 = (const float4*)(W + (size_t)(jbase +  64) * wstride);
  const float4* w2 = (const float4*)(W + (size_t)(jbase + 128) * wstride);
  const float4* w3 = (const float4*)(W + (size_t)(jbase + 192) * wstride);
  for (int k4 = 0; k4 < EE / 4; ++k4) {
    float4 wv0 = w0[k4], wv1 = w1[k4], wv2 = w2[k4], wv3 = w3[k4];
    #pragma unroll
    for (int rr = 0; rr < 4; ++rr) {
      float4 e = *(const float4*)&es[rg + rr][k4 * 4];
      acc[0][rr] = dot4(acc[0][rr], wv0, e);
      acc[1][rr] = dot4(acc[1][rr], wv1, e);
      acc[2][rr] = dot4(acc[2][rr], wv2, e);
      acc[3][rr] = dot4(acc[3][rr], wv3, e);
    }
  }
  #pragma unroll
  for (int rr = 0; rr < 4; ++rr)
    #pragma unroll
    for (int jj = 0; jj < 4; ++jj)
      gi[(size_t)(r0 + rg + rr) * G3 + jbase + jj * 64] = f2bf(acc[jj][rr]);
}

// ---------- K2: encoder GRU scan — 256 blocks = (b-half x 128 i-groups) --
// Block (bh, ig): b in [bh*16, +16), i in [ig*4, +4). Thread: i_l[4] x
// b_l[16] x kq[4] (k-quarter). Staging halved (16 b's), gemv halved.
__global__ __launch_bounds__(256)
void k_enc_scan(const u16* __restrict__ gi, const float* __restrict__ Whh,
                const float* __restrict__ bhh, u16* __restrict__ hring,
                u16* __restrict__ enc_outs, u32* __restrict__ flags)
{
  __shared__ float hs16[16 * HP];   // 33.0 KB (16 b's)
  __shared__ float wsl[12 * WPE];   // 24.8 KB f32
  __shared__ float h2t[4][16];
  const int tid = threadIdx.x;
  const int bid = blockIdx.x;
  const int bh = bid >> 7, ig = bid & 127;
  const int i0 = ig * 4, b0 = bh * 16;
  #pragma unroll
  for (int j = 0; j < 6; ++j) {     // stage 12 rows x 512 f32
    int f = (j * 256 + tid) * 4;
    int rowl = f >> 9, k = f & 511;
    int g = rowl >> 2, ri = rowl & 3;
    *(float4*)&wsl[rowl * WPE + k] =
      *(const float4*)(Whh + (size_t)(g * 512 + i0 + ri) * 512 + k);
  }
  const int i_l = tid >> 6, lane = tid & 63, b_l = lane >> 2, kq = lane & 3;
  const int i = i0 + i_l;
  const float* w0 = wsl + (0 * 4 + i_l) * WPE + kq * 128;
  const float* w1 = wsl + (1 * 4 + i_l) * WPE + kq * 128;
  const float* w2 = wsl + (2 * 4 + i_l) * WPE + kq * 128;
  const float bR = bhh[i], bZ = bhh[i + 512], bN = bhh[i + 1024];
  for (int t = 0; t < SS; ++t) {
    // stage h for OUR 16 b's: 2048 u64 = 8/thread
    const u64* hsrc = (const u64*)(hring + (size_t)t * 16384);
    #pragma unroll
    for (int j = 0; j < 8; ++j) {
      int idx = j * 256 + tid;
      int lb = idx >> 7, gu = idx & 127;
      u64 v = ald_u8(hsrc + (size_t)(b0 + lb) * 128 + gu);
      *(float4*)&hs16[lb * HP + gu * 4] = unp4(v);
    }
    __syncthreads();
    float aR = 0.f, aZ = 0.f, aN = 0.f;
    const float* hb = hs16 + b_l * HP + kq * 128;
    for (int k8 = 0; k8 < 16; ++k8) {
      float4 h0 = *(const float4*)&hb[k8*8], h1 = *(const float4*)&hb[k8*8+4];
      aR = fma44(aR, *(const float4*)&w0[k8*8], *(const float4*)&w0[k8*8+4], h0, h1);
      aZ = fma44(aZ, *(const float4*)&w1[k8*8], *(const float4*)&w1[k8*8+4], h0, h1);
      aN = fma44(aN, *(const float4*)&w2[k8*8], *(const float4*)&w2[k8*8+4], h0, h1);
    }
    aR += __shfl_xor(aR, 1); aR += __shfl_xor(aR, 2);
    aZ += __shfl_xor(aZ, 1); aZ += __shfl_xor(aZ, 2);
    aN += __shfl_xor(aN, 1); aN += __shfl_xor(aN, 2);
    if (kq == 0) {
      const int bg = b0 + b_l;
      const size_t g = ((size_t)t * 32 + bg) * G3;
      float r = sigf (bf2f(gi[g +        i]) + aR + bR);
      float z = sigf (bf2f(gi[g +  512 + i]) + aZ + bZ);
      float n = tanh_(bf2f(gi[g + 1024 + i]) + r * (aN + bN));
      float h2 = z * hs16[b_l * HP + i] + (1.f - z) * n;
      enc_outs[((size_t)bg * 256 + t) * 512 + i] = f2bf(h2);
      h2t[i_l][b_l] = h2;
    }
    __syncthreads();
    if (tid < 32) {    // 32 packed u32: 2 i-pairs x 16 b
      int p = tid >> 4, bl = tid & 15;
      u32 pk = (u32)f2bf(h2t[2*p][bl]) | ((u32)f2bf(h2t[2*p+1][bl]) << 16);
      ast_u((u32*)(hring + (size_t)(t + 1) * 16384)
            + (b0 + bl) * 256 + (i0 >> 1) + p, pk);
    }
    grid_bar(flags, bid, 256, (u32)(t + 1));
  }
}

// ---------- K3: enc_proj = enc_outs @ attn_W2^T + b2 ----------
__global__ __launch_bounds__(256)
void k_proj(const u16* __restrict__ A, const float* __restrict__ W,
            const float* __restrict__ bias, u16* __restrict__ Out)
{
  __shared__ float es[16][HH];
  const int tid = threadIdx.x;
  const int r0 = blockIdx.y * 16;
  #pragma unroll
  for (int j = 0; j < 4; ++j) {
    int u = j * 256 + tid;
    int row = u >> 6, k = (u & 63) * 8;
    float d[8]; unp8(d, *(const uint4*)(A + (size_t)(r0 + row) * HH + k));
    *(float4*)&es[row][k]     = make_float4(d[0],d[1],d[2],d[3]);
    *(float4*)&es[row][k + 4] = make_float4(d[4],d[5],d[6],d[7]);
  }
  __syncthreads();
  const int jl = tid & 63;
  const int rg = (tid >> 6) << 2;
  const int jbase = blockIdx.x * 256 + jl;
  float acc[4][4];
  #pragma unroll
  for (int jj = 0; jj < 4; ++jj) {
    float bv = bias[jbase + jj * 64];
    #pragma unroll
    for (int rr = 0; rr < 4; ++rr) acc[jj][rr] = bv;
  }
  const float4* w0 = (const float4*)(W + (size_t)(jbase      ) * HH);
  const float4* w1 = (const float4*)(W + (size_t)(jbase +  64) * HH);
  const float4* w2 = (const float4*)(W + (size_t)(jbase + 128) * HH);
  const float4* w3 = (const float4*)(W + (size_t)(jbase + 192) * HH);
  for (int k4 = 0; k4 < HH / 4; ++k4) {
    float4 wv0 = w0[k4], wv1 = w1[k4], wv2 = w2[k4], wv3 = w3[k4];
    #pragma unroll
    for (int rr = 0; rr < 4; ++rr) {
      float4 e = *(const float4*)&es[rg + rr][k4 * 4];
      acc[0][rr] = dot4(acc[0][rr], wv0, e);
      acc[1][rr] = dot4(acc[1][rr], wv1, e);
      acc[2][rr] = dot4(acc[2][rr], wv2, e);
      acc[3][rr] = dot4(acc[3][rr], wv3, e);
    }
  }
  #pragma unroll
  for (int rr = 0; rr < 4; ++rr)
    #pragma unroll
    for (int jj = 0; jj < 4; ++jj)
      Out[(size_t)(r0 + rg + rr) * HH + jbase + jj * 64] = f2bf(acc[jj][rr]);
}

// ---------- K4: decoder scan — b-partitioned P1/P3 (r16/r17-proven) ------
__global__ __launch_bounds__(256)
void k_dec_scan(const u16* __restrict__ gi, u16* __restrict__ hring,
                const float* __restrict__ W1, const float* __restrict__ b1,
                const float* __restrict__ av,
                const u16* __restrict__ enc_proj, const u16* __restrict__ enc_outs,
                const float* __restrict__ Whh, const float* __restrict__ Wih,
                const float* __restrict__ bhh,
                float* __restrict__ aring, u16* __restrict__ ctxP,
                float* __restrict__ sringP, u16* __restrict__ h2bf,
                u32* __restrict__ flags)
{
  __shared__ float hs8[8 * HP];      // 16.5 KB
  __shared__ u16  csb8[8 * CP8];     //  8.3 KB
  __shared__ u16  wlds[112 * WPD];   // 113.8 KB
  __shared__ float as_[512], vs_[512];
  __shared__ float scq[4][64], wts[64];
  __shared__ float rs[8];
  __shared__ float h2t[16][8];
  const int tid = threadIdx.x;
  const int bid = blockIdx.x;
  const int bg = bid >> 5, ig = bid & 31;
  const int b_l = tid >> 5, i_l = (tid >> 1) & 15, kh = tid & 1;
  const int i = ig * 16 + i_l;
  const int bglob = bg * 8 + b_l;
  const int pb = bid >> 2, sq = bid & 3;
  vs_[tid] = av[tid]; vs_[tid + 256] = av[tid + 256];
  for (int j = 0; j < 56; ++j) {
    int idx = j * 256 + tid;
    int row = idx >> 7, k4 = idx & 127;
    const float* src;
    if (row < 16)      src = W1  + (size_t)(ig * 16 + row) * 512 + k4 * 4;
    else if (row < 64) { int rr = row - 16; int g = rr >> 4, ii = rr & 15;
                         src = Whh + (size_t)(g * 512 + ig * 16 + ii) * 512 + k4 * 4; }
    else               { int rr = row - 64; int g = rr >> 4, ii = rr & 15;
                         src = Wih + (size_t)(g * 512 + ig * 16 + ii) * 768 + 256 + k4 * 4; }
    float4 w = *(const float4*)src;
    int f = row * WPD + k4 * 4;
    wlds[f] = f2bf(w.x); wlds[f+1] = f2bf(w.y); wlds[f+2] = f2bf(w.z); wlds[f+3] = f2bf(w.w);
  }
  const u16* w1r = wlds + (      i_l) * WPD + kh * 256;
  const u16* whr = wlds + (16  + i_l) * WPD + kh * 256;
  const u16* whz = wlds + (32  + i_l) * WPD + kh * 256;
  const u16* whn = wlds + (48  + i_l) * WPD + kh * 256;
  const u16* wir = wlds + (64  + i_l) * WPD + kh * 256;
  const u16* wiz = wlds + (80  + i_l) * WPD + kh * 256;
  const u16* win = wlds + (96  + i_l) * WPD + kh * 256;
  const float bR = bhh[i], bZ = bhh[i + 512], bN = bhh[i + 1024];
  const float b1i = b1[i];
  u32 ep = 0;
  for (int t = 0; t < TT; ++t) {
    const u64* hsrc = (const u64*)(hring + (size_t)(256 + t) * 16384);
    #pragma unroll
    for (int j = 0; j < 4; ++j) {
      int idx = j * 256 + tid;
      int lb = idx >> 7, gu = idx & 127;
      u64 v = ald_u8(hsrc + (size_t)(bg * 8 + lb) * 128 + gu);
      *(float4*)&hs8[lb * HP + gu * 4] = unp4(v);
    }
    __syncthreads();
    // ---- P1 ----
    {
      const float* hb = hs8 + b_l * HP + kh * 256;
      float acc = 0.f;
      for (int k8 = 0; k8 < 32; ++k8) {
        float wf[8]; unp8(wf, *(const uint4*)(w1r + k8 * 8));
        acc = fma8(acc, wf, *(const float4*)&hb[k8*8], *(const float4*)&hb[k8*8+4]);
      }
      acc += __shfl_xor(acc, 1);
      if (kh == 0) ast_f(&aring[(size_t)t * 16384 + bglob * 512 + i], acc + b1i);
    }
    ++ep; grid_bar(flags, bid, 128, ep);
    // ---- P2 (pb,sq): scores -> exp -> partial ctx/S ----
    {
      u64 v = ald_u8((const u64*)(aring + (size_t)t * 16384 + pb * 512) + tid);
      union { u64 q; float f[2]; } cv; cv.q = v;
      as_[2 * tid] = cv.f[0]; as_[2 * tid + 1] = cv.f[1];
    }
    __syncthreads();
    {
      const int kp = tid >> 6, s_l = tid & 63;
      const int s = sq * 64 + s_l;
      const u16* pr = enc_proj + ((size_t)pb * 256 + s) * 512 + kp * 128;
      const float* ak = as_ + kp * 128;
      const float* vk = vs_ + kp * 128;
      float acc = 0.f;
      for (int k8 = 0; k8 < 16; ++k8) {
        float d[8]; unp8(d, *(const uint4*)(pr + k8 * 8));
        #pragma unroll
        for (int e = 0; e < 8; ++e)
          acc += vk[k8 * 8 + e] * tanh_(d[e] + ak[k8 * 8 + e]);
      }
      scq[kp][s_l] = acc;
    }
    __syncthreads();
    if (tid < 64) {
      float sc = (scq[0][tid] + scq[1][tid]) + (scq[2][tid] + scq[3][tid]);
      float e = __expf(sc);          // bounded scores: no max-shift (proven r7)
      wts[tid] = e;
      float su = e;
      #pragma unroll
      for (int d = 1; d < 64; d <<= 1) su += __shfl_xor(su, d);
      if (tid == 0) ast_f(&sringP[t * 128 + sq * 32 + pb], su);
    }
    __syncthreads();
    {
      const int k0 = tid * 2;
      float c0 = 0.f, c1 = 0.f;
      const u16* eo = enc_outs + ((size_t)pb * 256 + sq * 64) * 512 + k0;
      for (int s = 0; s < 64; ++s) {
        float w = wts[s];
        u32 pair = *(const u32*)(eo + (size_t)s * 512);
        c0 = fmaf(w, blo(pair), c0);
        c1 = fmaf(w, bhi(pair), c1);
      }
      u32 pk = (u32)f2bf(c0) | ((u32)f2bf(c1) << 16);
      ast_u((u32*)(ctxP + (size_t)t * 65536 + (sq * 32 + pb) * 512 + k0), pk);
    }
    ++ep; grid_bar(flags, bid, 128, ep);
    // ---- P3: combine partials for OUR 8 b's, GRU ----
    if (tid < 8) {
      const float* sp = sringP + t * 128;
      int bq = bg * 8 + tid;
      rs[tid] = 1.f / ((ald_f(sp + bq) + ald_f(sp + 32 + bq)) +
                       (ald_f(sp + 64 + bq) + ald_f(sp + 96 + bq)));
    }
    __syncthreads();
    #pragma unroll
    for (int j = 0; j < 4; ++j) {
      int idx = j * 256 + tid;
      int lb = idx >> 7, gu = idx & 127;
      const u64* bp = (const u64*)(ctxP + (size_t)t * 65536);
      float c[4] = {0,0,0,0};
      #pragma unroll
      for (int q = 0; q < 4; ++q) {
        float4 d = unp4(ald_u8(bp + (size_t)(q * 32 + bg * 8 + lb) * 128 + gu));
        c[0] += d.x; c[1] += d.y; c[2] += d.z; c[3] += d.w;
      }
      float r = rs[lb];
      int m = gu * 4;
      *(u32*)&csb8[lb * CP8 + m]     = (u32)f2bf(c[0]*r) | ((u32)f2bf(c[1]*r) << 16);
      *(u32*)&csb8[lb * CP8 + m + 2] = (u32)f2bf(c[2]*r) | ((u32)f2bf(c[3]*r) << 16);
    }
    __syncthreads();
    {
      const float* hb = hs8 + b_l * HP + kh * 256;
      const u16*   cb = csb8 + b_l * CP8 + kh * 256;
      float hR=0.f,hZ=0.f,hN=0.f,cR=0.f,cZ=0.f,cN=0.f;
      for (int k8 = 0; k8 < 32; ++k8) {
        float4 h0 = *(const float4*)&hb[k8*8], h1 = *(const float4*)&hb[k8*8+4];
        float cf[8]; unp8(cf, *(const uint4*)(cb + k8 * 8));
        float wf[8];
        unp8(wf, *(const uint4*)(whr + k8 * 8)); hR = fma8(hR, wf, h0, h1);
        unp8(wf, *(const uint4*)(whz + k8 * 8)); hZ = fma8(hZ, wf, h0, h1);
        unp8(wf, *(const uint4*)(whn + k8 * 8)); hN = fma8(hN, wf, h0, h1);
        unp8(wf, *(const uint4*)(wir + k8 * 8)); cR = fma8p(cR, wf, cf);
        unp8(wf, *(const uint4*)(wiz + k8 * 8)); cZ = fma8p(cZ, wf, cf);
        unp8(wf, *(const uint4*)(win + k8 * 8)); cN = fma8p(cN, wf, cf);
      }
      hR += __shfl_xor(hR, 1); hZ += __shfl_xor(hZ, 1); hN += __shfl_xor(hN, 1);
      cR += __shfl_xor(cR, 1); cZ += __shfl_xor(cZ, 1); cN += __shfl_xor(cN, 1);
      if (kh == 0) {
        const size_t g = ((size_t)t * 32 + bglob) * G3;
        float r = sigf (bf2f(gi[g +        i]) + cR + hR + bR);
        float z = sigf (bf2f(gi[g +  512 + i]) + cZ + hZ + bZ);
        float n = tanh_(bf2f(gi[g + 1024 + i]) + cN + r * (hN + bN));
        float h2 = z * hs8[b_l * HP + i] + (1.f - z) * n;
        h2bf[((size_t)t * 32 + bglob) * 512 + i] = f2bf(h2);  // cross-kernel
        h2t[i_l][b_l] = h2;
      }
    }
    __syncthreads();
    if (tid < 64) {
      int p = tid >> 3, bl = tid & 7;
      u32 pk = (u32)f2bf(h2t[2*p][bl]) | ((u32)f2bf(h2t[2*p+1][bl]) << 16);
      ast_u((u32*)(hring + (size_t)(257 + t) * 16384)
            + (bg * 8 + bl) * 256 + ig * 8 + p, pk);
    }
    ++ep; grid_bar(flags, bid, 128, ep);
  }
}

// ---------- K5: fcW f32 -> bf16 (one-time) ----------
__global__ __launch_bounds__(256)
void k_cvt(const float* __restrict__ in, u16* __restrict__ out)
{
  size_t i = ((size_t)blockIdx.x * 256 + threadIdx.x) * 8;
  float4 a = *(const float4*)(in + i);
  float4 b = *(const float4*)(in + i + 4);
  union { uint4 v; u16 s[8]; } u;
  u.s[0]=f2bf(a.x); u.s[1]=f2bf(a.y); u.s[2]=f2bf(a.z); u.s[3]=f2bf(a.w);
  u.s[4]=f2bf(b.x); u.s[5]=f2bf(b.y); u.s[6]=f2bf(b.z); u.s[7]=f2bf(b.w);
  *(uint4*)(out + i) = u.v;
}

// ---------- K6: logits via bf16 MFMA (proven) ----------
__global__ __launch_bounds__(256)
void k_logits_mfma(const u16* __restrict__ A, const u16* __restrict__ Wb,
                   const float* __restrict__ bias, float* __restrict__ out)
{
  __shared__ u16 Al[64 * 512];
  const int tid = threadIdx.x;
  const int r0 = blockIdx.x * 64;
  const int v0 = blockIdx.y * 64;
  {
    const uint4* src = (const uint4*)(A + (size_t)r0 * 512);
    uint4* dst = (uint4*)Al;
    #pragma unroll
    for (int j = 0; j < 16; ++j) {
      int idx = j * 256 + tid;
      int row = idx >> 6, g = idx & 63;
      dst[(row << 6) | (g ^ (row & 7))] = src[idx];
    }
  }
  const int w  = tid >> 6, l = tid & 63;
  const int lr = l & 15,  qk = l >> 4;
  const int v  = v0 + w * 16 + lr;
  frag bfr[16];
  {
    const u16* wrow = Wb + (size_t)v * 512 + qk * 8;
    #pragma unroll
    for (int ks = 0; ks < 16; ++ks)
      bfr[ks] = *(const frag*)(wrow + ks * 32);
  }
  const float bv = bias[v];
  __syncthreads();
  f32x4v acc[4];
  #pragma unroll
  for (int mt = 0; mt < 4; ++mt) acc[mt] = (f32x4v){0.f, 0.f, 0.f, 0.f};
  #pragma unroll
  for (int ks = 0; ks < 16; ++ks) {
    #pragma unroll
    for (int mt = 0; mt < 4; ++mt) {
      const int row = mt * 16 + lr;
      const int gr  = ks * 4 + qk;
      frag a = *(const frag*)&Al[(row << 9) | ((gr ^ (row & 7)) << 3)];
      acc[mt] = __builtin_amdgcn_mfma_f32_16x16x32_bf16(a, bfr[ks], acc[mt], 0, 0, 0);
    }
  }
  #pragma unroll
  for (int mt = 0; mt < 4; ++mt)
    #pragma unroll
    for (int reg = 0; reg < 4; ++reg) {
      const int r = r0 + mt * 16 + qk * 4 + reg;
      out[(size_t)(r & 31) * 64 * VV + (size_t)(r >> 5) * VV + v] = acc[mt][reg] + bv;
    }
}

// ---------- launch ----------
extern "C" void kernel_launch(void* const* d_in, const int* in_sizes, int n_in,
                              void* d_out, int out_size, void* d_ws, size_t ws_size,
                              hipStream_t stream) {
  (void)in_sizes; (void)n_in; (void)out_size; (void)ws_size;
  const int*   src  = (const int*)d_in[0];
  const int*   tgt  = (const int*)d_in[1];
  const float* eemb = (const float*)d_in[2];
  const float* eWih = (const float*)d_in[3];
  const float* eWhh = (const float*)d_in[4];
  const float* ebih = (const float*)d_in[5];
  const float* ebhh = (const float*)d_in[6];
  const float* demb = (const float*)d_in[7];
  const float* aW1  = (const float*)d_in[8];
  const float* ab1  = (const float*)d_in[9];
  const float* aW2  = (const float*)d_in[10];
  const float* ab2  = (const float*)d_in[11];
  const float* av   = (const float*)d_in[12];
  const float* dWih = (const float*)d_in[13];
  const float* dWhh = (const float*)d_in[14];
  const float* dbih = (const float*)d_in[15];
  const float* dbhh = (const float*)d_in[16];
  const float* fcW  = (const float*)d_in[17];
  const float* fcb  = (const float*)d_in[18];
  float* out = (float*)d_out;

  // workspace carve (~71 MiB)
  float* aring   = (float*)d_ws;                 // 64x16384 f32 (4 MiB)
  float* sringP  = aring + 1048576;              // 64x128 f32 (32 KiB)
  u32*   flags   = (u32*)(sringP + 8192);        // 256x32 + 128x32 u32 (48 KiB)
  u16*  ctxP     = (u16*)(flags + 12288);        // 64x128x512 u16 (8 MiB)
  u16*  hring    = ctxP + 4194304;               // 321x16384 u16 (10.5 MiB)
  u16*  h2bf     = hring + 5259264;              // 1,048,576 u16
  u16*  gi_enc   = h2bf + 1048576;               // 12,582,912 u16
  u16*  gi_dec   = gi_enc + 12582912;            //  3,145,728 u16
  u16*  enc_outs = gi_dec + 3145728;             //  4,194,304 u16
  u16*  enc_proj = enc_outs + 4194304;           //  4,194,304 u16
  u16*  wbf      = gi_enc;  // fcW bf16 alias (dead after k_dec_scan)

  hipMemsetAsync(hring, 0, 16384 * sizeof(u16), stream);   // h0 slot (zeros)
  hipMemsetAsync(flags, 0, 12288 * sizeof(u32), stream);   // barrier flags

  k_embed_gemm<<<dim3(6, 512), 256, 0, stream>>>(src, SS, eemb, eWih, EE,  ebih, gi_enc);
  k_embed_gemm<<<dim3(6, 128), 256, 0, stream>>>(tgt, TT, demb, dWih, 768, dbih, gi_dec);

  k_enc_scan<<<256, 256, 0, stream>>>(gi_enc, eWhh, ebhh, hring, enc_outs, flags);

  k_proj<<<dim3(2, 512), 256, 0, stream>>>(enc_outs, aW2, ab2, enc_proj);

  k_dec_scan<<<128, 256, 0, stream>>>(gi_dec, hring, aW1, ab1, av,
                                      enc_proj, enc_outs, dWhh, dWih, dbhh,
                                      aring, ctxP, sringP, h2bf, flags + 8192);

  k_cvt<<<8000, 256, 0, stream>>>(fcW, wbf);

  k_logits_mfma<<<dim3(32, 500), 256, 0, stream>>>(h2bf, wbf, fcb, out);
}

// Round 21
// 4942.913 us; speedup vs baseline: 1.7149x; 1.0010x over previous
//
#include <hip/hip_runtime.h>
#include <hip/hip_bf16.h>
#include <stdint.h>

#define DEV __device__ __forceinline__
typedef unsigned short u16;
typedef unsigned int   u32;
typedef unsigned long long u64;

static constexpr int SS = 256;   // src len
static constexpr int TT = 64;    // tgt len
static constexpr int EE = 256;   // embed dim
static constexpr int HH = 512;   // hidden
static constexpr int G3 = 1536;  // 3*H
static constexpr int VV = 32000; // vocab
static constexpr int HP  = 516;  // padded f32 LDS row (h tiles)
static constexpr int WPE = 516;  // padded f32 weight row (encoder)
static constexpr int WPD = 520;  // padded u16 weight row (decoder)
static constexpr int CP8 = 520;  // padded u16 ctx row (decoder)

using frag   = __attribute__((ext_vector_type(8))) short;  // 8 bf16
using f32x4v = __attribute__((ext_vector_type(4))) float;  // MFMA acc

// ---------- helpers ----------
DEV float blo(u32 u){ union{u32 i; float f;} x; x.i = u << 16;         return x.f; }
DEV float bhi(u32 u){ union{u32 i; float f;} x; x.i = u & 0xffff0000u; return x.f; }
DEV float bf2f(u16 u){ union{u32 i; float f;} x; x.i = ((u32)u) << 16; return x.f; }
DEV u16 f2bf(float f){ union{float f; u32 u;} v; v.f = f;
  u32 r = v.u + 0x7fffu + ((v.u >> 16) & 1u); return (u16)(r >> 16); }
DEV float sigf (float x){ return 1.0f / (1.0f + __expf(-x)); }
DEV float tanh_(float x){ return 1.0f - 2.0f / (1.0f + __expf(2.0f * x)); }
DEV void unp8(float* d, uint4 u){
  d[0]=blo(u.x); d[1]=bhi(u.x); d[2]=blo(u.y); d[3]=bhi(u.y);
  d[4]=blo(u.z); d[5]=bhi(u.z); d[6]=blo(u.w); d[7]=bhi(u.w);
}
DEV float4 unp4(u64 v){
  return make_float4(bf2f((u16)v), bf2f((u16)(v >> 16)),
                     bf2f((u16)(v >> 32)), bf2f((u16)(v >> 48)));
}
DEV float dot4(float acc, float4 w, float4 x){
  acc = fmaf(w.x,x.x,acc); acc = fmaf(w.y,x.y,acc);
  acc = fmaf(w.z,x.z,acc); acc = fmaf(w.w,x.w,acc);
  return acc;
}
DEV float fma44(float acc, float4 w0, float4 w1, float4 h0, float4 h1){
  return dot4(dot4(acc, w0, h0), w1, h1);
}
DEV float fma8(float acc, const float* w, float4 a, float4 b){
  acc = fmaf(w[0],a.x,acc); acc = fmaf(w[1],a.y,acc);
  acc = fmaf(w[2],a.z,acc); acc = fmaf(w[3],a.w,acc);
  acc = fmaf(w[4],b.x,acc); acc = fmaf(w[5],b.y,acc);
  acc = fmaf(w[6],b.z,acc); acc = fmaf(w[7],b.w,acc);
  return acc;
}
DEV float fma8p(float acc, const float* w, const float* x){
  #pragma unroll
  for (int e = 0; e < 8; ++e) acc = fmaf(w[e], x[e], acc);
  return acc;
}

// ---- agent-scope atomics (r9/r13-proven coherence rule) ----
DEV void  ast_f(float* p, float v){ __hip_atomic_store(p, v, __ATOMIC_RELAXED, __HIP_MEMORY_SCOPE_AGENT); }
DEV void  ast_u(u32* p, u32 v)    { __hip_atomic_store(p, v, __ATOMIC_RELAXED, __HIP_MEMORY_SCOPE_AGENT); }
DEV float ald_f(const float* p)   { return __hip_atomic_load((float*)p, __ATOMIC_RELAXED, __HIP_MEMORY_SCOPE_AGENT); }
DEV u64   ald_u8(const u64* p)    { return __hip_atomic_load((u64*)p,   __ATOMIC_RELAXED, __HIP_MEMORY_SCOPE_AGENT); }
DEV u32   ald_u (const u32* p)    { return __hip_atomic_load((u32*)p,   __ATOMIC_RELAXED, __HIP_MEMORY_SCOPE_AGENT); }

// Distributed grid barrier (r17/r18-proven).
DEV void grid_bar(u32* flags, int bid, int nb, u32 epoch){
  __syncthreads();
  if (threadIdx.x == 0) ast_u(&flags[bid * 32], epoch);
  if (threadIdx.x < (u32)nb) {
    while (ald_u(&flags[threadIdx.x * 32]) < epoch)
      __builtin_amdgcn_s_sleep(1);
  }
  __syncthreads();
}

// ---------- K1: gi = gather(emb, tok) @ W[:, :256]^T + bih  (bf16 out) ----
__global__ __launch_bounds__(256)
void k_embed_gemm(const int* __restrict__ tok, int Tlen,
                  const float* __restrict__ emb,
                  const float* __restrict__ W, int wstride,
                  const float* __restrict__ bias,
                  u16* __restrict__ gi)
{
  __shared__ float es[16][EE];
  const int tid = threadIdx.x;
  const int r0 = blockIdx.y * 16;
  #pragma unroll
  for (int rr = 0; rr < 16; ++rr) {
    int r = r0 + rr;
    int token = tok[(r & 31) * Tlen + (r >> 5)];
    es[rr][tid] = emb[(size_t)token * EE + tid];
  }
  __syncthreads();
  const int jl = tid & 63;
  const int rg = (tid >> 6) << 2;
  const int jbase = blockIdx.x * 256 + jl;
  float acc[4][4];
  #pragma unroll
  for (int jj = 0; jj < 4; ++jj) {
    float bv = bias[jbase + jj * 64];
    #pragma unroll
    for (int rr = 0; rr < 4; ++rr) acc[jj][rr] = bv;
  }
  const float4* w0 = (const float4*)(W + (size_t)(jbase      ) * wstride);
  const float4* w1 = (const float4*)(W + (size_t)(jbase +  64) * wstride);
  const float4* w2 = (const float4*)(W + (size_t)(jbase + 128) * wstride);
  const float4* w3 = (const float4*)(W + (size_t)(jbase + 192) * wstride);
  for (int k4 = 0; k4 < EE / 4; ++k4) {
    float4 wv0 = w0[k4], wv1 = w1[k4], wv2 = w2[k4], wv3 = w3[k4];
    #pragma unroll
    for (int rr = 0; rr < 4; ++rr) {
      float4 e = *(const float4*)&es[rg + rr][k4 * 4];
      acc[0][rr] = dot4(acc[0][rr], wv0, e);
      acc[1][rr] = dot4(acc[1][rr], wv1, e);
      acc[2][rr] = dot4(acc[2][rr], wv2, e);
      acc[3][rr] = dot4(acc[3][rr], wv3, e);
    }
  }
  #pragma unroll
  for (int rr = 0; rr < 4; ++rr)
    #pragma unroll
    for (int jj = 0; jj < 4; ++jj)
      gi[(size_t)(r0 + rg + rr) * G3 + jbase + jj * 64] = f2bf(acc[jj][rr]);
}

// ---------- K2: encoder GRU scan — 256 blocks = (b-half x 128 i-groups) --
// Block (bh, ig): b in [bh*16, +16), i in [ig*4, +4). Thread: i_l[4] x
// b_l[16] x kq[4] (k-quarter). Staging halved (16 b's), gemv halved.
__global__ __launch_bounds__(256)
void k_enc_scan(const u16* __restrict__ gi, const float* __restrict__ Whh,
                const float* __restrict__ bhh, u16* __restrict__ hring,
                u16* __restrict__ enc_outs, u32* __restrict__ flags)
{
  __shared__ float hs16[16 * HP];   // 33.0 KB (16 b's)
  __shared__ float wsl[12 * WPE];   // 24.8 KB f32
  __shared__ float h2t[4][16];
  const int tid = threadIdx.x;
  const int bid = blockIdx.x;
  const int bh = bid >> 7, ig = bid & 127;
  const int i0 = ig * 4, b0 = bh * 16;
  #pragma unroll
  for (int j = 0; j < 6; ++j) {     // stage 12 rows x 512 f32
    int f = (j * 256 + tid) * 4;
    int rowl = f >> 9, k = f & 511;
    int g = rowl >> 2, ri = rowl & 3;
    *(float4*)&wsl[rowl * WPE + k] =
      *(const float4*)(Whh + (size_t)(g * 512 + i0 + ri) * 512 + k);
  }
  const int i_l = tid >> 6, lane = tid & 63, b_l = lane >> 2, kq = lane & 3;
  const int i = i0 + i_l;
  const float* w0 = wsl + (0 * 4 + i_l) * WPE + kq * 128;
  const float* w1 = wsl + (1 * 4 + i_l) * WPE + kq * 128;
  const float* w2 = wsl + (2 * 4 + i_l) * WPE + kq * 128;
  const float bR = bhh[i], bZ = bhh[i + 512], bN = bhh[i + 1024];
  for (int t = 0; t < SS; ++t) {
    // stage h for OUR 16 b's: 2048 u64 = 8/thread
    const u64* hsrc = (const u64*)(hring + (size_t)t * 16384);
    #pragma unroll
    for (int j = 0; j < 8; ++j) {
      int idx = j * 256 + tid;
      int lb = idx >> 7, gu = idx & 127;
      u64 v = ald_u8(hsrc + (size_t)(b0 + lb) * 128 + gu);
      *(float4*)&hs16[lb * HP + gu * 4] = unp4(v);
    }
    __syncthreads();
    float aR = 0.f, aZ = 0.f, aN = 0.f;
    const float* hb = hs16 + b_l * HP + kq * 128;
    for (int k8 = 0; k8 < 16; ++k8) {
      float4 h0 = *(const float4*)&hb[k8*8], h1 = *(const float4*)&hb[k8*8+4];
      aR = fma44(aR, *(const float4*)&w0[k8*8], *(const float4*)&w0[k8*8+4], h0, h1);
      aZ = fma44(aZ, *(const float4*)&w1[k8*8], *(const float4*)&w1[k8*8+4], h0, h1);
      aN = fma44(aN, *(const float4*)&w2[k8*8], *(const float4*)&w2[k8*8+4], h0, h1);
    }
    aR += __shfl_xor(aR, 1); aR += __shfl_xor(aR, 2);
    aZ += __shfl_xor(aZ, 1); aZ += __shfl_xor(aZ, 2);
    aN += __shfl_xor(aN, 1); aN += __shfl_xor(aN, 2);
    if (kq == 0) {
      const int bg = b0 + b_l;
      const size_t g = ((size_t)t * 32 + bg) * G3;
      float r = sigf (bf2f(gi[g +        i]) + aR + bR);
      float z = sigf (bf2f(gi[g +  512 + i]) + aZ + bZ);
      float n = tanh_(bf2f(gi[g + 1024 + i]) + r * (aN + bN));
      float h2 = z * hs16[b_l * HP + i] + (1.f - z) * n;
      enc_outs[((size_t)bg * 256 + t) * 512 + i] = f2bf(h2);
      h2t[i_l][b_l] = h2;
    }
    __syncthreads();
    if (tid < 32) {    // 32 packed u32: 2 i-pairs x 16 b
      int p = tid >> 4, bl = tid & 15;
      u32 pk = (u32)f2bf(h2t[2*p][bl]) | ((u32)f2bf(h2t[2*p+1][bl]) << 16);
      ast_u((u32*)(hring + (size_t)(t + 1) * 16384)
            + (b0 + bl) * 256 + (i0 >> 1) + p, pk);
    }
    grid_bar(flags, bid, 256, (u32)(t + 1));
  }
}

// ---------- K3: enc_proj = enc_outs @ attn_W2^T + b2 ----------
__global__ __launch_bounds__(256)
void k_proj(const u16* __restrict__ A, const float* __restrict__ W,
            const float* __restrict__ bias, u16* __restrict__ Out)
{
  __shared__ float es[16][HH];
  const int tid = threadIdx.x;
  const int r0 = blockIdx.y * 16;
  #pragma unroll
  for (int j = 0; j < 4; ++j) {
    int u = j * 256 + tid;
    int row = u >> 6, k = (u & 63) * 8;
    float d[8]; unp8(d, *(const uint4*)(A + (size_t)(r0 + row) * HH + k));
    *(float4*)&es[row][k]     = make_float4(d[0],d[1],d[2],d[3]);
    *(float4*)&es[row][k + 4] = make_float4(d[4],d[5],d[6],d[7]);
  }
  __syncthreads();
  const int jl = tid & 63;
  const int rg = (tid >> 6) << 2;
  const int jbase = blockIdx.x * 256 + jl;
  float acc[4][4];
  #pragma unroll
  for (int jj = 0; jj < 4; ++jj) {
    float bv = bias[jbase + jj * 64];
    #pragma unroll
    for (int rr = 0; rr < 4; ++rr) acc[jj][rr] = bv;
  }
  const float4* w0 = (const float4*)(W + (size_t)(jbase      ) * HH);
  const float4* w1 = (const float4*)(W + (size_t)(jbase +  64) * HH);
  const float4* w2 = (const float4*)(W + (size_t)(jbase + 128) * HH);
  const float4* w3 = (const float4*)(W + (size_t)(jbase + 192) * HH);
  for (int k4 = 0; k4 < HH / 4; ++k4) {
    float4 wv0 = w0[k4], wv1 = w1[k4], wv2 = w2[k4], wv3 = w3[k4];
    #pragma unroll
    for (int rr = 0; rr < 4; ++rr) {
      float4 e = *(const float4*)&es[rg + rr][k4 * 4];
      acc[0][rr] = dot4(acc[0][rr], wv0, e);
      acc[1][rr] = dot4(acc[1][rr], wv1, e);
      acc[2][rr] = dot4(acc[2][rr], wv2, e);
      acc[3][rr] = dot4(acc[3][rr], wv3, e);
    }
  }
  #pragma unroll
  for (int rr = 0; rr < 4; ++rr)
    #pragma unroll
    for (int jj = 0; jj < 4; ++jj)
      Out[(size_t)(r0 + rg + rr) * HH + jbase + jj * 64] = f2bf(acc[jj][rr]);
}

// ---------- K4: decoder scan — b-partitioned P1/P3 (r16/r17/r18-proven) --
__global__ __launch_bounds__(256)
void k_dec_scan(const u16* __restrict__ gi, u16* __restrict__ hring,
                const float* __restrict__ W1, const float* __restrict__ b1,
                const float* __restrict__ av,
                const u16* __restrict__ enc_proj, const u16* __restrict__ enc_outs,
                const float* __restrict__ Whh, const float* __restrict__ Wih,
                const float* __restrict__ bhh,
                float* __restrict__ aring, u16* __restrict__ ctxP,
                float* __restrict__ sringP, u16* __restrict__ h2bf,
                u32* __restrict__ flags)
{
  __shared__ float hs8[8 * HP];      // 16.5 KB
  __shared__ u16  csb8[8 * CP8];     //  8.3 KB
  __shared__ u16  wlds[112 * WPD];   // 113.8 KB
  __shared__ float as_[512], vs_[512];
  __shared__ float scq[4][64], wts[64];
  __shared__ float rs[8];
  __shared__ float h2t[16][8];
  const int tid = threadIdx.x;
  const int bid = blockIdx.x;
  const int bg = bid >> 5, ig = bid & 31;
  const int b_l = tid >> 5, i_l = (tid >> 1) & 15, kh = tid & 1;
  const int i = ig * 16 + i_l;
  const int bglob = bg * 8 + b_l;
  const int pb = bid >> 2, sq = bid & 3;
  vs_[tid] = av[tid]; vs_[tid + 256] = av[tid + 256];
  for (int j = 0; j < 56; ++j) {
    int idx = j * 256 + tid;
    int row = idx >> 7, k4 = idx & 127;
    const float* src;
    if (row < 16)      src = W1  + (size_t)(ig * 16 + row) * 512 + k4 * 4;
    else if (row < 64) { int rr = row - 16; int g = rr >> 4, ii = rr & 15;
                         src = Whh + (size_t)(g * 512 + ig * 16 + ii) * 512 + k4 * 4; }
    else               { int rr = row - 64; int g = rr >> 4, ii = rr & 15;
                         src = Wih + (size_t)(g * 512 + ig * 16 + ii) * 768 + 256 + k4 * 4; }
    float4 w = *(const float4*)src;
    int f = row * WPD + k4 * 4;
    wlds[f] = f2bf(w.x); wlds[f+1] = f2bf(w.y); wlds[f+2] = f2bf(w.z); wlds[f+3] = f2bf(w.w);
  }
  const u16* w1r = wlds + (      i_l) * WPD + kh * 256;
  const u16* whr = wlds + (16  + i_l) * WPD + kh * 256;
  const u16* whz = wlds + (32  + i_l) * WPD + kh * 256;
  const u16* whn = wlds + (48  + i_l) * WPD + kh * 256;
  const u16* wir = wlds + (64  + i_l) * WPD + kh * 256;
  const u16* wiz = wlds + (80  + i_l) * WPD + kh * 256;
  const u16* win = wlds + (96  + i_l) * WPD + kh * 256;
  const float bR = bhh[i], bZ = bhh[i + 512], bN = bhh[i + 1024];
  const float b1i = b1[i];
  u32 ep = 0;
  for (int t = 0; t < TT; ++t) {
    const u64* hsrc = (const u64*)(hring + (size_t)(256 + t) * 16384);
    #pragma unroll
    for (int j = 0; j < 4; ++j) {
      int idx = j * 256 + tid;
      int lb = idx >> 7, gu = idx & 127;
      u64 v = ald_u8(hsrc + (size_t)(bg * 8 + lb) * 128 + gu);
      *(float4*)&hs8[lb * HP + gu * 4] = unp4(v);
    }
    __syncthreads();
    // ---- P1 ----
    {
      const float* hb = hs8 + b_l * HP + kh * 256;
      float acc = 0.f;
      for (int k8 = 0; k8 < 32; ++k8) {
        float wf[8]; unp8(wf, *(const uint4*)(w1r + k8 * 8));
        acc = fma8(acc, wf, *(const float4*)&hb[k8*8], *(const float4*)&hb[k8*8+4]);
      }
      acc += __shfl_xor(acc, 1);
      if (kh == 0) ast_f(&aring[(size_t)t * 16384 + bglob * 512 + i], acc + b1i);
    }
    ++ep; grid_bar(flags, bid, 128, ep);
    // ---- P2 (pb,sq): scores -> exp -> partial ctx/S ----
    {
      u64 v = ald_u8((const u64*)(aring + (size_t)t * 16384 + pb * 512) + tid);
      union { u64 q; float f[2]; } cv; cv.q = v;
      as_[2 * tid] = cv.f[0]; as_[2 * tid + 1] = cv.f[1];
    }
    __syncthreads();
    {
      const int kp = tid >> 6, s_l = tid & 63;
      const int s = sq * 64 + s_l;
      const u16* pr = enc_proj + ((size_t)pb * 256 + s) * 512 + kp * 128;
      const float* ak = as_ + kp * 128;
      const float* vk = vs_ + kp * 128;
      float acc = 0.f;
      for (int k8 = 0; k8 < 16; ++k8) {
        float d[8]; unp8(d, *(const uint4*)(pr + k8 * 8));
        #pragma unroll
        for (int e = 0; e < 8; ++e)
          acc += vk[k8 * 8 + e] * tanh_(d[e] + ak[k8 * 8 + e]);
      }
      scq[kp][s_l] = acc;
    }
    __syncthreads();
    if (tid < 64) {
      float sc = (scq[0][tid] + scq[1][tid]) + (scq[2][tid] + scq[3][tid]);
      float e = __expf(sc);          // bounded scores: no max-shift (proven r7)
      wts[tid] = e;
      float su = e;
      #pragma unroll
      for (int d = 1; d < 64; d <<= 1) su += __shfl_xor(su, d);
      if (tid == 0) ast_f(&sringP[t * 128 + sq * 32 + pb], su);
    }
    __syncthreads();
    {
      const int k0 = tid * 2;
      float c0 = 0.f, c1 = 0.f;
      const u16* eo = enc_outs + ((size_t)pb * 256 + sq * 64) * 512 + k0;
      for (int s = 0; s < 64; ++s) {
        float w = wts[s];
        u32 pair = *(const u32*)(eo + (size_t)s * 512);
        c0 = fmaf(w, blo(pair), c0);
        c1 = fmaf(w, bhi(pair), c1);
      }
      u32 pk = (u32)f2bf(c0) | ((u32)f2bf(c1) << 16);
      ast_u((u32*)(ctxP + (size_t)t * 65536 + (sq * 32 + pb) * 512 + k0), pk);
    }
    ++ep; grid_bar(flags, bid, 128, ep);
    // ---- P3: combine partials for OUR 8 b's, GRU ----
    if (tid < 8) {
      const float* sp = sringP + t * 128;
      int bq = bg * 8 + tid;
      rs[tid] = 1.f / ((ald_f(sp + bq) + ald_f(sp + 32 + bq)) +
                       (ald_f(sp + 64 + bq) + ald_f(sp + 96 + bq)));
    }
    __syncthreads();
    #pragma unroll
    for (int j = 0; j < 4; ++j) {
      int idx = j * 256 + tid;
      int lb = idx >> 7, gu = idx & 127;
      const u64* bp = (const u64*)(ctxP + (size_t)t * 65536);
      float c[4] = {0,0,0,0};
      #pragma unroll
      for (int q = 0; q < 4; ++q) {
        float4 d = unp4(ald_u8(bp + (size_t)(q * 32 + bg * 8 + lb) * 128 + gu));
        c[0] += d.x; c[1] += d.y; c[2] += d.z; c[3] += d.w;
      }
      float r = rs[lb];
      int m = gu * 4;
      *(u32*)&csb8[lb * CP8 + m]     = (u32)f2bf(c[0]*r) | ((u32)f2bf(c[1]*r) << 16);
      *(u32*)&csb8[lb * CP8 + m + 2] = (u32)f2bf(c[2]*r) | ((u32)f2bf(c[3]*r) << 16);
    }
    __syncthreads();
    {
      const float* hb = hs8 + b_l * HP + kh * 256;
      const u16*   cb = csb8 + b_l * CP8 + kh * 256;
      float hR=0.f,hZ=0.f,hN=0.f,cR=0.f,cZ=0.f,cN=0.f;
      for (int k8 = 0; k8 < 32; ++k8) {
        float4 h0 = *(const float4*)&hb[k8*8], h1 = *(const float4*)&hb[k8*8+4];
        float cf[8]; unp8(cf, *(const uint4*)(cb + k8 * 8));
        float wf[8];
        unp8(wf, *(const uint4*)(whr + k8 * 8)); hR = fma8(hR, wf, h0, h1);
        unp8(wf, *(const uint4*)(whz + k8 * 8)); hZ = fma8(hZ, wf, h0, h1);
        unp8(wf, *(const uint4*)(whn + k8 * 8)); hN = fma8(hN, wf, h0, h1);
        unp8(wf, *(const uint4*)(wir + k8 * 8)); cR = fma8p(cR, wf, cf);
        unp8(wf, *(const uint4*)(wiz + k8 * 8)); cZ = fma8p(cZ, wf, cf);
        unp8(wf, *(const uint4*)(win + k8 * 8)); cN = fma8p(cN, wf, cf);
      }
      hR += __shfl_xor(hR, 1); hZ += __shfl_xor(hZ, 1); hN += __shfl_xor(hN, 1);
      cR += __shfl_xor(cR, 1); cZ += __shfl_xor(cZ, 1); cN += __shfl_xor(cN, 1);
      if (kh == 0) {
        const size_t g = ((size_t)t * 32 + bglob) * G3;
        float r = sigf (bf2f(gi[g +        i]) + cR + hR + bR);
        float z = sigf (bf2f(gi[g +  512 + i]) + cZ + hZ + bZ);
        float n = tanh_(bf2f(gi[g + 1024 + i]) + cN + r * (hN + bN));
        float h2 = z * hs8[b_l * HP + i] + (1.f - z) * n;
        h2bf[((size_t)t * 32 + bglob) * 512 + i] = f2bf(h2);  // cross-kernel
        h2t[i_l][b_l] = h2;
      }
    }
    __syncthreads();
    if (tid < 64) {
      int p = tid >> 3, bl = tid & 7;
      u32 pk = (u32)f2bf(h2t[2*p][bl]) | ((u32)f2bf(h2t[2*p+1][bl]) << 16);
      ast_u((u32*)(hring + (size_t)(257 + t) * 16384)
            + (bg * 8 + bl) * 256 + ig * 8 + p, pk);
    }
    ++ep; grid_bar(flags, bid, 128, ep);
  }
}

// ---------- K5: fcW f32 -> bf16 (one-time) ----------
__global__ __launch_bounds__(256)
void k_cvt(const float* __restrict__ in, u16* __restrict__ out)
{
  size_t i = ((size_t)blockIdx.x * 256 + threadIdx.x) * 8;
  float4 a = *(const float4*)(in + i);
  float4 b = *(const float4*)(in + i + 4);
  union { uint4 v; u16 s[8]; } u;
  u.s[0]=f2bf(a.x); u.s[1]=f2bf(a.y); u.s[2]=f2bf(a.z); u.s[3]=f2bf(a.w);
  u.s[4]=f2bf(b.x); u.s[5]=f2bf(b.y); u.s[6]=f2bf(b.z); u.s[7]=f2bf(b.w);
  *(uint4*)(out + i) = u.v;
}

// ---------- K6: logits via bf16 MFMA (proven) ----------
__global__ __launch_bounds__(256)
void k_logits_mfma(const u16* __restrict__ A, const u16* __restrict__ Wb,
                   const float* __restrict__ bias, float* __restrict__ out)
{
  __shared__ u16 Al[64 * 512];
  const int tid = threadIdx.x;
  const int r0 = blockIdx.x * 64;
  const int v0 = blockIdx.y * 64;
  {
    const uint4* src = (const uint4*)(A + (size_t)r0 * 512);
    uint4* dst = (uint4*)Al;
    #pragma unroll
    for (int j = 0; j < 16; ++j) {
      int idx = j * 256 + tid;
      int row = idx >> 6, g = idx & 63;
      dst[(row << 6) | (g ^ (row & 7))] = src[idx];
    }
  }
  const int w  = tid >> 6, l = tid & 63;
  const int lr = l & 15,  qk = l >> 4;
  const int v  = v0 + w * 16 + lr;
  frag bfr[16];
  {
    const u16* wrow = Wb + (size_t)v * 512 + qk * 8;
    #pragma unroll
    for (int ks = 0; ks < 16; ++ks)
      bfr[ks] = *(const frag*)(wrow + ks * 32);
  }
  const float bv = bias[v];
  __syncthreads();
  f32x4v acc[4];
  #pragma unroll
  for (int mt = 0; mt < 4; ++mt) acc[mt] = (f32x4v){0.f, 0.f, 0.f, 0.f};
  #pragma unroll
  for (int ks = 0; ks < 16; ++ks) {
    #pragma unroll
    for (int mt = 0; mt < 4; ++mt) {
      const int row = mt * 16 + lr;
      const int gr  = ks * 4 + qk;
      frag a = *(const frag*)&Al[(row << 9) | ((gr ^ (row & 7)) << 3)];
      acc[mt] = __builtin_amdgcn_mfma_f32_16x16x32_bf16(a, bfr[ks], acc[mt], 0, 0, 0);
    }
  }
  #pragma unroll
  for (int mt = 0; mt < 4; ++mt)
    #pragma unroll
    for (int reg = 0; reg < 4; ++reg) {
      const int r = r0 + mt * 16 + qk * 4 + reg;
      out[(size_t)(r & 31) * 64 * VV + (size_t)(r >> 5) * VV + v] = acc[mt][reg] + bv;
    }
}

// ---------- launch ----------
extern "C" void kernel_launch(void* const* d_in, const int* in_sizes, int n_in,
                              void* d_out, int out_size, void* d_ws, size_t ws_size,
                              hipStream_t stream) {
  (void)in_sizes; (void)n_in; (void)out_size; (void)ws_size;
  const int*   src  = (const int*)d_in[0];
  const int*   tgt  = (const int*)d_in[1];
  const float* eemb = (const float*)d_in[2];
  const float* eWih = (const float*)d_in[3];
  const float* eWhh = (const float*)d_in[4];
  const float* ebih = (const float*)d_in[5];
  const float* ebhh = (const float*)d_in[6];
  const float* demb = (const float*)d_in[7];
  const float* aW1  = (const float*)d_in[8];
  const float* ab1  = (const float*)d_in[9];
  const float* aW2  = (const float*)d_in[10];
  const float* ab2  = (const float*)d_in[11];
  const float* av   = (const float*)d_in[12];
  const float* dWih = (const float*)d_in[13];
  const float* dWhh = (const float*)d_in[14];
  const float* dbih = (const float*)d_in[15];
  const float* dbhh = (const float*)d_in[16];
  const float* fcW  = (const float*)d_in[17];
  const float* fcb  = (const float*)d_in[18];
  float* out = (float*)d_out;

  // workspace carve (~71 MiB)
  float* aring   = (float*)d_ws;                 // 64x16384 f32 (4 MiB)
  float* sringP  = aring + 1048576;              // 64x128 f32 (32 KiB)
  u32*   flags   = (u32*)(sringP + 8192);        // 256x32 + 128x32 u32 (48 KiB)
  u16*  ctxP     = (u16*)(flags + 12288);        // 64x128x512 u16 (8 MiB)
  u16*  hring    = ctxP + 4194304;               // 321x16384 u16 (10.5 MiB)
  u16*  h2bf     = hring + 5259264;              // 1,048,576 u16
  u16*  gi_enc   = h2bf + 1048576;               // 12,582,912 u16
  u16*  gi_dec   = gi_enc + 12582912;            //  3,145,728 u16
  u16*  enc_outs = gi_dec + 3145728;             //  4,194,304 u16
  u16*  enc_proj = enc_outs + 4194304;           //  4,194,304 u16
  u16*  wbf      = gi_enc;  // fcW bf16 alias (dead after k_dec_scan)

  hipMemsetAsync(hring, 0, 16384 * sizeof(u16), stream);   // h0 slot (zeros)
  hipMemsetAsync(flags, 0, 12288 * sizeof(u32), stream);   // barrier flags

  k_embed_gemm<<<dim3(6, 512), 256, 0, stream>>>(src, SS, eemb, eWih, EE,  ebih, gi_enc);
  k_embed_gemm<<<dim3(6, 128), 256, 0, stream>>>(tgt, TT, demb, dWih, 768, dbih, gi_dec);

  k_enc_scan<<<256, 256, 0, stream>>>(gi_enc, eWhh, ebhh, hring, enc_outs, flags);

  k_proj<<<dim3(2, 512), 256, 0, stream>>>(enc_outs, aW2, ab2, enc_proj);

  k_dec_scan<<<128, 256, 0, stream>>>(gi_dec, hring, aW1, ab1, av,
                                      enc_proj, enc_outs, dWhh, dWih, dbhh,
                                      aring, ctxP, sringP, h2bf, flags + 8192);

  k_cvt<<<8000, 256, 0, stream>>>(fcW, wbf);

  k_logits_mfma<<<dim3(32, 500), 256, 0, stream>>>(h2bf, wbf, fcb, out);
}